// Round 7
// baseline (308.244 us; speedup 1.0000x reference)
//
#include <hip/hip_runtime.h>

// ---------------------------------------------------------------------------
// QueryConditionedTransportScorerV3 on MI355X (gfx950)
// Q=64 W=16 A=64 D=H=512.
//   fused@rw1 = Ya[w,a] + Yq[q] + [a*q ; |a-q|+c] @ (rg*rw1)[1024:2048] (MFMA)
//   h = rstd*(sum - mu*S1) + (rb1 + rb@rw1); gelu; @rw2; softmax+entropy fused
// Round 7: main kernel producer/consumer wave split — waves 0-7 MFMA (64 cols,
//   acc[4][4]), waves 8-15 build (native bf16 cvt, per-fr stats). Double-buf
//   2x32KB, 1 barrier/chunk, setprio(1) around MFMA. Pre-path = round 6.
// ---------------------------------------------------------------------------

#define DEV static __device__ __forceinline__

typedef __attribute__((ext_vector_type(8))) __bf16 bf16x8;
typedef __attribute__((ext_vector_type(4))) float f32x4;
typedef unsigned short ushort_t;

DEV ushort_t f2bf(float f) {
  unsigned u = __builtin_bit_cast(unsigned, f);
  u = (u + 0x7fffu + ((u >> 16) & 1u)) >> 16;
  return (ushort_t)u;
}

// branch-free erf (Abramowitz-Stegun 7.1.26, |err| <= 1.5e-7)
DEV float gelu_fast(float x) {
  const float y = x * 0.70710678118654752f;
  const float z = fabsf(y);
  const float t = __fdividef(1.0f, 1.0f + 0.3275911f * z);
  float p = 1.061405429f;
  p = p * t - 1.453152027f;
  p = p * t + 1.421413741f;
  p = p * t - 0.284496736f;
  p = p * t + 0.254829592f;
  const float e = 1.0f - p * t * __expf(-z * z);
  const float erfv = copysignf(e, y);
  return 0.5f * x * (1.0f + erfv);
}

// ---- ws layout (float offsets) --------------------------------------------
#define OFF_XQB    0          // bf16 64x512    (aliased by QHS after P1)
#define OFF_XAB    16384      // bf16 1024x512  (aliased by AHHS after P1)
#define OFF_XCB    278528     // bf16 16x1024   (aliased by CHH f32 after P1)
#define OFF_HAB    286720     // bf16 1024x512
#define OFF_HQB    548864     // bf16 64x512
#define OFF_HCB    565248     // bf16 16x512
#define OFF_AHH    569344     // f32 1024x512
#define OFF_QH     1093632    // f32 64x512
#define OFF_S1     1126400    // f32 512
#define OFF_B1     1126912    // f32 512
#define OFF_WT2    1127424    // bf16 k-tiled hi rw1 (rg-scaled), 524288 el
#define OFF_RW1LOT 1389568    // bf16 [512n][512k] rw1[0:512]
#define OFF_RW1MIT 1520640    // bf16 [512n][512k] rw1[512:1024]
#define OFF_AW1T   1651712    // bf16 [512][512]   ┐
#define OFF_QW1T   1782784    // bf16 [512][512]   ├ dead after P1 -> YA
#define OFF_CW1T   1913856    // bf16 [512][1024]  ┘
#define OFF_AW2T   2176000    // bf16 [512][512]   ┐ dead after P2 -> YQ
#define OFF_QW2T   2307072    // bf16 [512][512]   ┘
#define OFF_CW2T   2438144    // bf16 [512][512]   (end: 2569216 fl)
#define OFF_YA     OFF_AW1T   // f32 1024x512
#define OFF_YQ     OFF_AW2T   // f32 64x512
#define OFF_CHH    OFF_XCB    // f32 16x512
#define OFF_AHHS   OFF_XAB    // bf16 1024x512 (ahh*rg_lo)
#define OFF_QHS    OFF_XQB    // bf16 64x512   (qh*rg_mid)

// WT2 k-tiled layout: element (n, k2) at (k2>>5)*16384 + n*32 + (k2&31).

// ======================== P0: wide prep kernel ==============================
DEV void transpose_tile(const float* __restrict__ src, int koff, int kt, int ct,
                        ushort_t* __restrict__ dst, int ldk, float* sh, int tid) {
  float (*t)[65] = (float(*)[65])sh;
  for (int idx = tid; idx < 4096; idx += 512) {
    const int r = idx >> 6, c = idx & 63;
    t[r][c] = src[(koff + kt + r) * 512 + ct + c];
  }
  __syncthreads();
  for (int idx = tid; idx < 4096; idx += 512) {
    const int c = idx >> 6, r = idx & 63;
    dst[(ct + c) * ldk + kt + r] = f2bf(t[r][c]);
  }
}

// roles: [0,128) WT2 | [128,192) rw1loT | [192,256) rw1midT | [256,320) aw1T
// [320,384) qw1T | [384,512) cw1T | [512,576) aw2T | [576,640) qw2T
// [640,704) cw2T | [704,720) S1/B1 | [720,784) q pool+LN | [784,912) a LN
// [912,928) c concat+LN
__global__ __launch_bounds__(512) void pre0_kernel(
    const float* __restrict__ qa, const float* __restrict__ qm,
    const float* __restrict__ ca, const float* __restrict__ csum,
    const float* __restrict__ ectx,
    const float* __restrict__ qg, const float* __restrict__ qb,
    const float* __restrict__ ag, const float* __restrict__ ab,
    const float* __restrict__ cg, const float* __restrict__ cb,
    const float* __restrict__ rw1, const float* __restrict__ rg,
    const float* __restrict__ rb,
    const float* __restrict__ aw1, const float* __restrict__ qw1,
    const float* __restrict__ cw1, const float* __restrict__ aw2,
    const float* __restrict__ qw2, const float* __restrict__ cw2,
    float* __restrict__ ws) {
  __shared__ float sh[4160];
  const int b = blockIdx.x, tid = threadIdx.x, l = tid & 63, wv = tid >> 6;

  if (b < 128) {
    ushort_t* WT = (ushort_t*)(ws + OFF_WT2);
    float (*t)[65] = (float(*)[65])sh;
    const int kt = (b >> 3) << 6;
    const int ct = (b & 7) << 6;
    for (int idx = tid; idx < 4096; idx += 512) {
      const int r = idx >> 6, c = idx & 63;
      t[r][c] = rg[1024 + kt + r] * rw1[(1024 + kt + r) * 512 + ct + c];
    }
    __syncthreads();
    for (int idx = tid; idx < 4096; idx += 512) {
      const int c = idx >> 6, r = idx & 63;
      const int n = ct + c, k2 = kt + r;
      WT[((k2 >> 5) << 14) + (n << 5) + (k2 & 31)] = f2bf(t[r][c]);
    }
  } else if (b < 192) {
    const int bb = b - 128;
    transpose_tile(rw1, 0, (bb >> 3) << 6, (bb & 7) << 6,
                   (ushort_t*)(ws + OFF_RW1LOT), 512, sh, tid);
  } else if (b < 256) {
    const int bb = b - 192;
    transpose_tile(rw1, 512, (bb >> 3) << 6, (bb & 7) << 6,
                   (ushort_t*)(ws + OFF_RW1MIT), 512, sh, tid);
  } else if (b < 320) {
    const int bb = b - 256;
    transpose_tile(aw1, 0, (bb >> 3) << 6, (bb & 7) << 6,
                   (ushort_t*)(ws + OFF_AW1T), 512, sh, tid);
  } else if (b < 384) {
    const int bb = b - 320;
    transpose_tile(qw1, 0, (bb >> 3) << 6, (bb & 7) << 6,
                   (ushort_t*)(ws + OFF_QW1T), 512, sh, tid);
  } else if (b < 512) {
    const int bb = b - 384;
    transpose_tile(cw1, 0, (bb >> 3) << 6, (bb & 7) << 6,
                   (ushort_t*)(ws + OFF_CW1T), 1024, sh, tid);
  } else if (b < 576) {
    const int bb = b - 512;
    transpose_tile(aw2, 0, (bb >> 3) << 6, (bb & 7) << 6,
                   (ushort_t*)(ws + OFF_AW2T), 512, sh, tid);
  } else if (b < 640) {
    const int bb = b - 576;
    transpose_tile(qw2, 0, (bb >> 3) << 6, (bb & 7) << 6,
                   (ushort_t*)(ws + OFF_QW2T), 512, sh, tid);
  } else if (b < 704) {
    const int bb = b - 640;
    transpose_tile(cw2, 0, (bb >> 3) << 6, (bb & 7) << 6,
                   (ushort_t*)(ws + OFF_CW2T), 512, sh, tid);
  } else if (b < 720) {
    const int kc = (b - 704) << 7;
    float s0 = 0.f, s1 = 0.f, b0 = 0.f, b1v = 0.f;
    for (int k = kc; k < kc + 128; k += 2) {
      const float wa = rw1[(k << 9) + tid];
      const float wb = rw1[((k + 1) << 9) + tid];
      s0 += rg[k] * wa; b0 += rb[k] * wa;
      s1 += rg[k + 1] * wb; b1v += rb[k + 1] * wb;
    }
    atomicAdd(ws + OFF_S1 + tid, s0 + s1);
    atomicAdd(ws + OFF_B1 + tid, b0 + b1v);
  } else if (b < 784) {
    const int q = b - 720;
    if (wv == 0) {
      float m = fmaxf(qm[(q << 6) + l], 0.f);
      sh[l] = m;
      float s = m;
#pragma unroll
      for (int off = 1; off < 64; off <<= 1) s += __shfl_xor(s, off);
      if (l == 0) sh[64] = 1.0f / fmaxf(s, 1e-8f);
    }
    __syncthreads();
    const float sinv = sh[64];
    const float* qaq = qa + (q << 15) + tid;
    float v0 = 0.f, v1 = 0.f, v2 = 0.f, v3 = 0.f;
#pragma unroll 4
    for (int a = 0; a < 64; a += 4) {
      v0 += sh[a] * qaq[a << 9];
      v1 += sh[a + 1] * qaq[(a + 1) << 9];
      v2 += sh[a + 2] * qaq[(a + 2) << 9];
      v3 += sh[a + 3] * qaq[(a + 3) << 9];
    }
    const float v = (v0 + v1 + v2 + v3) * sinv;
    float s = v, ss = v * v;
#pragma unroll
    for (int off = 1; off < 64; off <<= 1) {
      s += __shfl_xor(s, off); ss += __shfl_xor(ss, off);
    }
    if (l == 0) { sh[128 + wv] = s; sh[136 + wv] = ss; }
    __syncthreads();
    float st = 0.f, sst = 0.f;
#pragma unroll
    for (int i = 0; i < 8; ++i) { st += sh[128 + i]; sst += sh[136 + i]; }
    const float mu = st * (1.0f / 512.0f);
    const float rstd = rsqrtf(sst * (1.0f / 512.0f) - mu * mu + 1e-5f);
    ((ushort_t*)(ws + OFF_XQB))[(q << 9) + tid] =
        f2bf((v - mu) * rstd * qg[tid] + qb[tid]);
  } else if (b < 912) {
    const int row = ((b - 784) << 3) + wv;
    const float* crow = ca + (row << 9);
    float x[8];
    float s = 0.f, ss = 0.f;
#pragma unroll
    for (int i = 0; i < 8; ++i) {
      x[i] = crow[l + (i << 6)];
      s += x[i]; ss += x[i] * x[i];
    }
#pragma unroll
    for (int off = 1; off < 64; off <<= 1) {
      s += __shfl_xor(s, off); ss += __shfl_xor(ss, off);
    }
    const float mu = s * (1.0f / 512.0f);
    const float rstd = rsqrtf(ss * (1.0f / 512.0f) - mu * mu + 1e-5f);
    ushort_t* xab = (ushort_t*)(ws + OFF_XAB);
#pragma unroll
    for (int i = 0; i < 8; ++i) {
      const int k = l + (i << 6);
      xab[(row << 9) + k] = f2bf((x[i] - mu) * rstd * ag[k] + ab[k]);
    }
  } else {
    const int w = b - 912;
    const float v0 = csum[(w << 9) + tid];
    const float v1 = ectx[(w << 9) + tid];
    float s = v0 + v1, ss = v0 * v0 + v1 * v1;
#pragma unroll
    for (int off = 1; off < 64; off <<= 1) {
      s += __shfl_xor(s, off); ss += __shfl_xor(ss, off);
    }
    if (l == 0) { sh[wv] = s; sh[8 + wv] = ss; }
    __syncthreads();
    float st = 0.f, sst = 0.f;
#pragma unroll
    for (int i = 0; i < 8; ++i) { st += sh[i]; sst += sh[8 + i]; }
    const float mu = st * (1.0f / 1024.0f);
    const float rstd = rsqrtf(sst * (1.0f / 1024.0f) - mu * mu + 1e-5f);
    ushort_t* xcb = (ushort_t*)(ws + OFF_XCB);
    xcb[(w << 10) + tid] = f2bf((v0 - mu) * rstd * cg[tid] + cb[tid]);
    xcb[(w << 10) + 512 + tid] =
        f2bf((v1 - mu) * rstd * cg[512 + tid] + cb[512 + tid]);
  }
}

// ======================== MFMA GEMM phases ==================================
template <int PHASE>
__global__ __launch_bounds__(256) void gemm_kernel(
    float* __restrict__ ws, const float* __restrict__ ba,
    const float* __restrict__ bq, const float* __restrict__ bc,
    const float* __restrict__ rg) {
  const int b = blockIdx.x, tid = threadIdx.x;
  const int l = tid & 63, wv = tid >> 6;

  const ushort_t* A; const ushort_t* BT;
  float* outF = nullptr; ushort_t* outB = nullptr; ushort_t* outS = nullptr;
  const float* bias = nullptr; const float* scl = nullptr;
  int M, K, rb, cb;

  if (PHASE == 1) {
    if (b < 32) {
      A = (const ushort_t*)(ws + OFF_XAB); BT = (const ushort_t*)(ws + OFF_AW1T);
      M = 1024; K = 512; rb = (b >> 1) << 6; cb = (b & 1) << 8;
      outB = (ushort_t*)(ws + OFF_HAB); bias = ba;
    } else if (b < 34) {
      A = (const ushort_t*)(ws + OFF_XQB); BT = (const ushort_t*)(ws + OFF_QW1T);
      M = 64; K = 512; rb = 0; cb = (b - 32) << 8;
      outB = (ushort_t*)(ws + OFF_HQB); bias = bq;
    } else {
      A = (const ushort_t*)(ws + OFF_XCB); BT = (const ushort_t*)(ws + OFF_CW1T);
      M = 16; K = 1024; rb = 0; cb = (b - 34) << 8;
      outB = (ushort_t*)(ws + OFF_HCB); bias = bc;
    }
  } else if (PHASE == 2) {
    if (b < 32) {
      A = (const ushort_t*)(ws + OFF_HAB); BT = (const ushort_t*)(ws + OFF_AW2T);
      M = 1024; K = 512; rb = (b >> 1) << 6; cb = (b & 1) << 8;
      outF = ws + OFF_AHH; outS = (ushort_t*)(ws + OFF_AHHS); bias = ba; scl = rg;
    } else if (b < 34) {
      A = (const ushort_t*)(ws + OFF_HQB); BT = (const ushort_t*)(ws + OFF_QW2T);
      M = 64; K = 512; rb = 0; cb = (b - 32) << 8;
      outF = ws + OFF_QH; outS = (ushort_t*)(ws + OFF_QHS); bias = bq; scl = rg + 512;
    } else {
      A = (const ushort_t*)(ws + OFF_HCB); BT = (const ushort_t*)(ws + OFF_CW2T);
      M = 16; K = 512; rb = 0; cb = (b - 34) << 8;
      outF = ws + OFF_CHH; bias = bc;
    }
  } else {
    if (b < 32) {
      A = (const ushort_t*)(ws + OFF_AHHS); BT = (const ushort_t*)(ws + OFF_RW1LOT);
      M = 1024; K = 512; rb = (b >> 1) << 6; cb = (b & 1) << 8;
      outF = ws + OFF_YA;
    } else {
      A = (const ushort_t*)(ws + OFF_QHS); BT = (const ushort_t*)(ws + OFF_RW1MIT);
      M = 64; K = 512; rb = 0; cb = (b - 32) << 8;
      outF = ws + OFF_YQ;
    }
  }

  const int colw = cb + (wv << 6);
  const int kh = (l >> 4) << 3;
  const ushort_t* ap[4];
  const ushort_t* bp[4];
#pragma unroll
  for (int fr = 0; fr < 4; ++fr) {
    int r = rb + (fr << 4) + (l & 15);
    if (r > M - 1) r = M - 1;
    ap[fr] = A + r * K + kh;
  }
#pragma unroll
  for (int cf = 0; cf < 4; ++cf) {
    const int ccol = colw + (cf << 4) + (l & 15);
    bp[cf] = BT + ccol * K + kh;
  }

  f32x4 acc[4][4] = {};
  const int nst = K >> 5;
#pragma unroll 4
  for (int ks = 0; ks < nst; ++ks) {
    bf16x8 afr[4], bfr[4];
#pragma unroll
    for (int fr = 0; fr < 4; ++fr)
      afr[fr] = __builtin_bit_cast(bf16x8, *(const uint4*)(ap[fr] + (ks << 5)));
#pragma unroll
    for (int cf = 0; cf < 4; ++cf)
      bfr[cf] = __builtin_bit_cast(bf16x8, *(const uint4*)(bp[cf] + (ks << 5)));
#pragma unroll
    for (int fr = 0; fr < 4; ++fr)
#pragma unroll
      for (int cf = 0; cf < 4; ++cf)
        acc[fr][cf] = __builtin_amdgcn_mfma_f32_16x16x32_bf16(
            afr[fr], bfr[cf], acc[fr][cf], 0, 0, 0);
  }

  const int rsub = (l >> 4) << 2, cl = l & 15;
#pragma unroll
  for (int fr = 0; fr < 4; ++fr) {
#pragma unroll
    for (int cf = 0; cf < 4; ++cf) {
      const int col = colw + (cf << 4) + cl;
#pragma unroll
      for (int j = 0; j < 4; ++j) {
        const int row = rb + (fr << 4) + rsub + j;
        if (row < M) {
          float v = acc[fr][cf][j];
          if (PHASE == 1) {
            outB[(row << 9) + col] = f2bf(gelu_fast(v + bias[col]));
          } else if (PHASE == 2) {
            v += bias[col];
            outF[(row << 9) + col] = v;
            if (outS) outS[(row << 9) + col] = f2bf(v * scl[col]);
          } else {
            outF[(row << 9) + col] = v;
          }
        }
      }
    }
  }
}

// ---------------------------- main fused kernel -----------------------------
// 1 block per (q,w), 1024 threads = 16 waves.
// Waves 0-7 (consumers): MFMA 64 rows x 64 cols each, acc[4][4].
// Waves 8-15 (producers): build pair matrix chunks (K=256) + LN stats.
// Double-buffered 2x32KB LDS; 1 barrier per chunk; setprio(1) around MFMA.
__global__ __launch_bounds__(1024, 4) void main_kernel(
    const float* __restrict__ AH, const float* __restrict__ QH,
    const float* __restrict__ CH, const ushort_t* __restrict__ WT2,
    const float* __restrict__ Ya, const float* __restrict__ Yq,
    const float* __restrict__ S1, const float* __restrict__ B1,
    const float* __restrict__ rb1, const float* __restrict__ rw2,
    const float* __restrict__ rb2, const float* __restrict__ cmass,
    float* __restrict__ out) {
  extern __shared__ char smem_raw[];
  float* qs = (float*)smem_raw;          // 512
  float* cs = qs + 512;                  // 512
  float* s1_s = cs + 512;                // 64
  float* s2_s = s1_s + 64;               // 64
  float* rel_s = s2_s + 64;              // 64
  float* misc = rel_s + 64;              // 2 (+pad to 5120 B)
  uint4* apv = (uint4*)(smem_raw + 5120);  // 2 x 32KB: [buf][ksl(8)][fr(4)][l]

  const int tid = threadIdx.x;
  const int l = tid & 63;
  const int wv = tid >> 6;               // 0..15
  const int q = blockIdx.x >> 4;
  const int w = blockIdx.x & 15;

  if (tid < 512) qs[tid] = QH[(q << 9) + tid];
  else cs[tid - 512] = CH[(w << 9) + (tid - 512)];
  if (tid < 64) { s1_s[tid] = 0.f; s2_s[tid] = 0.f; rel_s[tid] = 0.f; }
  __syncthreads();

  const int kh = (l >> 4) << 3;          // 0,8,16,24
  const int pw = wv - 8;                 // producer slot 0..7
  const float* abase = AH + ((w << 6) + (l & 15)) * 512;  // +fr*16 rows later
  float s1a[4] = {0.f, 0.f, 0.f, 0.f};
  float s2a[4] = {0.f, 0.f, 0.f, 0.f};

  // producer: build chunk C (ks = C*8 + pw) into buffer B
#define BUILD(C, B) do { \
    const int ks_ = ((C) << 3) + pw; \
    const int ka_ = ((ks_ << 5) + kh) & 511; \
    const float4 q0_ = *(const float4*)(qs + ka_); \
    const float4 q1_ = *(const float4*)(qs + ka_ + 4); \
    const float qv_[8] = {q0_.x, q0_.y, q0_.z, q0_.w, q1_.x, q1_.y, q1_.z, q1_.w}; \
    float cv_[8]; \
    if ((C) >= 2) { \
      const float4 c0_ = *(const float4*)(cs + ka_); \
      const float4 c1_ = *(const float4*)(cs + ka_ + 4); \
      cv_[0]=c0_.x; cv_[1]=c0_.y; cv_[2]=c0_.z; cv_[3]=c0_.w; \
      cv_[4]=c1_.x; cv_[5]=c1_.y; cv_[6]=c1_.z; cv_[7]=c1_.w; \
    } \
    _Pragma("unroll") for (int fr_ = 0; fr_ < 4; ++fr_) { \
      const float* ar_ = abase + (fr_ << 13) + ka_; \
      const float4 a0_ = *(const float4*)(ar_); \
      const float4 a1_ = *(const float4*)(ar_ + 4); \
      const float av_[8] = {a0_.x, a0_.y, a0_.z, a0_.w, a1_.x, a1_.y, a1_.z, a1_.w}; \
      float vv_[8]; \
      if ((C) < 2) { \
        _Pragma("unroll") for (int j_ = 0; j_ < 8; ++j_) { \
          const float aq_ = av_[j_] * qv_[j_]; \
          vv_[j_] = aq_; \
          s1a[fr_] += av_[j_] + aq_; \
          s2a[fr_] += av_[j_] * av_[j_] + aq_ * aq_; \
        } \
      } else { \
        _Pragma("unroll") for (int j_ = 0; j_ < 8; ++j_) { \
          const float dd_ = fabsf(av_[j_] - qv_[j_]) + cv_[j_]; \
          vv_[j_] = dd_; \
          s1a[fr_] += dd_; \
          s2a[fr_] += dd_ * dd_; \
        } \
      } \
      union { __bf16 bv[8]; uint4 u4; } pk_; \
      _Pragma("unroll") for (int j_ = 0; j_ < 8; ++j_) pk_.bv[j_] = (__bf16)vv_[j_]; \
      apv[((B) << 11) + (pw << 8) + (fr_ << 6) + l] = pk_.u4; \
    } } while (0)

  // ---- prologue: producers build chunk 0; wave 8 also does q-segment stats
  if (wv >= 8) {
    BUILD(0, 0);
    if (wv == 8) {
      float sq = 0.f, sqq = 0.f;
#pragma unroll
      for (int it = 0; it < 8; ++it) {
        const float vq = qs[l + (it << 6)];
        sq += vq; sqq += vq * vq;
      }
#pragma unroll
      for (int off = 1; off < 64; off <<= 1) {
        sq += __shfl_xor(sq, off); sqq += __shfl_xor(sqq, off);
      }
      if (l == 0) { misc[0] = sq; misc[1] = sqq; }
    }
  }
  __syncthreads();

  // ---- chunk loop: consumers MFMA chunk c; producers build chunk c+1 ------
  f32x4 acc[4][4] = {};
  const int ncb = (wv << 6) + (l & 15);  // consumer col base (wv<8)
#pragma unroll
  for (int c = 0; c < 4; ++c) {
    if (wv < 8) {
      const uint4* cbuf = apv + ((c & 1) << 11);
      __builtin_amdgcn_s_setprio(1);
#pragma unroll
      for (int ksl = 0; ksl < 8; ++ksl) {
        const int ks = (c << 3) + ksl;
        bf16x8 bfr[4], afr[4];
#pragma unroll
        for (int cf = 0; cf < 4; ++cf)
          bfr[cf] = __builtin_bit_cast(bf16x8,
              *(const uint4*)(WT2 + (ks << 14) + ((ncb + (cf << 4)) << 5) + kh));
#pragma unroll
        for (int fr = 0; fr < 4; ++fr)
          afr[fr] = __builtin_bit_cast(bf16x8, cbuf[(ksl << 8) + (fr << 6) + l]);
#pragma unroll
        for (int fr = 0; fr < 4; ++fr)
#pragma unroll
          for (int cf = 0; cf < 4; ++cf)
            acc[fr][cf] = __builtin_amdgcn_mfma_f32_16x16x32_bf16(
                afr[fr], bfr[cf], acc[fr][cf], 0, 0, 0);
      }
      __builtin_amdgcn_s_setprio(0);
    } else {
      if (c == 0) BUILD(1, 1);
      if (c == 1) BUILD(2, 0);
      if (c == 2) BUILD(3, 1);
      if (c == 3) {
        // fold per-fr stats into per-row LDS totals
#pragma unroll
        for (int fr = 0; fr < 4; ++fr) {
          float s1v = s1a[fr], s2v = s2a[fr];
          s1v += __shfl_xor(s1v, 16); s1v += __shfl_xor(s1v, 32);
          s2v += __shfl_xor(s2v, 16); s2v += __shfl_xor(s2v, 32);
          if ((l >> 4) == 0) {
            atomicAdd(&s1_s[(fr << 4) + l], s1v);
            atomicAdd(&s2_s[(fr << 4) + l], s2v);
          }
        }
      }
    }
    __syncthreads();
  }
#undef BUILD

  // ---- epilogue (consumers): LN-fold + gelu + dot(rw2) -> relevance -------
  if (wv < 8) {
    const float sqt = misc[0], sqqt = misc[1];
    float yqv[4], s1c[4], b1c[4], w2c[4];
#pragma unroll
    for (int cf = 0; cf < 4; ++cf) {
      const int n = ncb + (cf << 4);
      yqv[cf] = Yq[(q << 9) + n];
      s1c[cf] = S1[n];
      b1c[cf] = B1[n] + rb1[n];
      w2c[cf] = rw2[n];
    }
    const float* yab = Ya + (w << 15) + ncb;
    const int rsub = (l >> 4) << 2;
#pragma unroll
    for (int fr = 0; fr < 4; ++fr) {
#pragma unroll
      for (int j = 0; j < 4; ++j) {
        const int r = (fr << 4) + rsub + j;
        const float s1r = s1_s[r] + sqt;
        const float s2r = s2_s[r] + sqqt;
        const float mu = s1r * (1.0f / 2048.0f);
        const float rs = rsqrtf(s2r * (1.0f / 2048.0f) - mu * mu + 1e-5f);
        float rp = 0.f;
#pragma unroll
        for (int cf = 0; cf < 4; ++cf) {
          const float ya = yab[(r << 9) + (cf << 4)];
          const float hp = rs * (acc[fr][cf][j] + ya + yqv[cf] - mu * s1c[cf]) + b1c[cf];
          rp += gelu_fast(hp) * w2c[cf];
        }
        rp += __shfl_xor(rp, 1); rp += __shfl_xor(rp, 2);
        rp += __shfl_xor(rp, 4); rp += __shfl_xor(rp, 8);
        if ((l & 15) == 0) atomicAdd(&rel_s[r], rp);
      }
    }
  }
  __syncthreads();

  // ---- softmax over atoms + entropy (wave 0)
  if (tid < 64) {
    const float relv = rel_s[tid] + rb2[0];
    const float x = logf(fmaxf(cmass[(w << 6) + tid], 1e-8f)) + relv;
    float m = x;
#pragma unroll
    for (int off = 1; off < 64; off <<= 1) m = fmaxf(m, __shfl_xor(m, off));
    const float p = expf(x - m);
    float s = p;
#pragma unroll
    for (int off = 1; off < 64; off <<= 1) s += __shfl_xor(s, off);
    float mix = p / fmaxf(s, 1e-8f);
    float s2 = mix;
#pragma unroll
    for (int off = 1; off < 64; off <<= 1) s2 += __shfl_xor(s2, off);
    mix = mix / fmaxf(s2, 1e-8f);
    const float et = -mix * logf(fmaxf(mix, 1e-8f));
    float ent = et;
#pragma unroll
    for (int off = 1; off < 64; off <<= 1) ent += __shfl_xor(ent, off);
    out[(blockIdx.x << 6) + tid] = mix;                 // mixed[q][w][a]
    if (tid == 0) out[65536 + blockIdx.x] = ent;        // entropy[q][w]
  }
}

// ---------------------------------------------------------------------------
extern "C" void kernel_launch(void* const* d_in, const int* in_sizes, int n_in,
                              void* d_out, int out_size, void* d_ws, size_t ws_size,
                              hipStream_t stream) {
  (void)in_sizes; (void)n_in; (void)out_size; (void)ws_size;
  const float* q_atoms = (const float*)d_in[0];
  const float* q_mass  = (const float*)d_in[1];
  const float* c_atoms = (const float*)d_in[2];
  const float* c_mass  = (const float*)d_in[3];
  const float* c_sum   = (const float*)d_in[4];
  const float* e_ctx   = (const float*)d_in[5];
  const float* qg  = (const float*)d_in[6];  const float* qb  = (const float*)d_in[7];
  const float* qw1 = (const float*)d_in[8];  const float* qb1 = (const float*)d_in[9];
  const float* qw2 = (const float*)d_in[10]; const float* qb2 = (const float*)d_in[11];
  const float* ag  = (const float*)d_in[12]; const float* ab  = (const float*)d_in[13];
  const float* aw1 = (const float*)d_in[14]; const float* ab1 = (const float*)d_in[15];
  const float* aw2 = (const float*)d_in[16]; const float* ab2 = (const float*)d_in[17];
  const float* cg  = (const float*)d_in[18]; const float* cb  = (const float*)d_in[19];
  const float* cw1 = (const float*)d_in[20]; const float* cb1 = (const float*)d_in[21];
  const float* cw2 = (const float*)d_in[22]; const float* cb2 = (const float*)d_in[23];
  const float* rg  = (const float*)d_in[24]; const float* rb  = (const float*)d_in[25];
  const float* rw1 = (const float*)d_in[26]; const float* rb1 = (const float*)d_in[27];
  const float* rw2 = (const float*)d_in[28]; const float* rb2 = (const float*)d_in[29];

  float* ws = (float*)d_ws;
  float* out = (float*)d_out;

  hipMemsetAsync(ws + OFF_S1, 0, 1024 * sizeof(float), stream);  // S1+B1
  pre0_kernel<<<928, 512, 0, stream>>>(q_atoms, q_mass, c_atoms, c_sum, e_ctx,
                                       qg, qb, ag, ab, cg, cb, rw1, rg, rb,
                                       aw1, qw1, cw1, aw2, qw2, cw2, ws);
  gemm_kernel<1><<<36, 256, 0, stream>>>(ws, ab1, qb1, cb1, rg);
  gemm_kernel<2><<<36, 256, 0, stream>>>(ws, ab2, qb2, cb2, rg);
  gemm_kernel<3><<<34, 256, 0, stream>>>(ws, nullptr, nullptr, nullptr, rg);

  static const size_t MAIN_SMEM = 5120 + 65536;  // 70656 B
  hipFuncSetAttribute((const void*)main_kernel,
                      hipFuncAttributeMaxDynamicSharedMemorySize, (int)MAIN_SMEM);
  main_kernel<<<1024, 1024, MAIN_SMEM, stream>>>(
      ws + OFF_AHH, ws + OFF_QH, ws + OFF_CHH,
      (const ushort_t*)(ws + OFF_WT2), ws + OFF_YA, ws + OFF_YQ,
      ws + OFF_S1, ws + OFF_B1, rb1, rw2, rb2, c_mass, out);
}

// Round 8
// 198.732 us; speedup vs baseline: 1.5511x; 1.5511x over previous
//
#include <hip/hip_runtime.h>

// ---------------------------------------------------------------------------
// QueryConditionedTransportScorerV3 on MI355X (gfx950)
// Q=64 W=16 A=64 D=H=512.
//   fused@rw1 = Ya[w,a] + Yq[q] + [a*q ; |a-q|+c] @ (rg*rw1)[1024:2048] (MFMA)
//   h = rstd*(sum - mu*S1) + (rb1 + rb@rw1); gelu; @rw2; softmax+entropy fused
// Round 8: revert main to round-6 lockstep pipeline (r7 producer/consumer
//   spilled); add depth-2 static B-prefetch + native v_cvt_pk bf16 in build.
//   Pre GEMMs retiled to 32x32/wave (acc[2][2]), grids 140/140/136.
// ---------------------------------------------------------------------------

#define DEV static __device__ __forceinline__

typedef __attribute__((ext_vector_type(8))) __bf16 bf16x8;
typedef __attribute__((ext_vector_type(4))) float f32x4;
typedef unsigned short ushort_t;

DEV ushort_t f2bf(float f) {
  unsigned u = __builtin_bit_cast(unsigned, f);
  u = (u + 0x7fffu + ((u >> 16) & 1u)) >> 16;
  return (ushort_t)u;
}

// branch-free erf (Abramowitz-Stegun 7.1.26, |err| <= 1.5e-7)
DEV float gelu_fast(float x) {
  const float y = x * 0.70710678118654752f;
  const float z = fabsf(y);
  const float t = __fdividef(1.0f, 1.0f + 0.3275911f * z);
  float p = 1.061405429f;
  p = p * t - 1.453152027f;
  p = p * t + 1.421413741f;
  p = p * t - 0.284496736f;
  p = p * t + 0.254829592f;
  const float e = 1.0f - p * t * __expf(-z * z);
  const float erfv = copysignf(e, y);
  return 0.5f * x * (1.0f + erfv);
}

// ---- ws layout (float offsets) --------------------------------------------
#define OFF_XQB    0          // bf16 64x512    (aliased by QHS after P1)
#define OFF_XAB    16384      // bf16 1024x512  (aliased by AHHS after P1)
#define OFF_XCB    278528     // bf16 16x1024   (aliased by CHH f32 after P1)
#define OFF_HAB    286720     // bf16 1024x512
#define OFF_HQB    548864     // bf16 64x512
#define OFF_HCB    565248     // bf16 16x512
#define OFF_AHH    569344     // f32 1024x512
#define OFF_QH     1093632    // f32 64x512
#define OFF_S1     1126400    // f32 512
#define OFF_B1     1126912    // f32 512
#define OFF_WT2    1127424    // bf16 k-tiled hi rw1 (rg-scaled), 524288 el
#define OFF_RW1LOT 1389568    // bf16 [512n][512k] rw1[0:512]
#define OFF_RW1MIT 1520640    // bf16 [512n][512k] rw1[512:1024]
#define OFF_AW1T   1651712    // bf16 [512][512]   ┐
#define OFF_QW1T   1782784    // bf16 [512][512]   ├ dead after P1 -> YA
#define OFF_CW1T   1913856    // bf16 [512][1024]  ┘
#define OFF_AW2T   2176000    // bf16 [512][512]   ┐ dead after P2 -> YQ
#define OFF_QW2T   2307072    // bf16 [512][512]   ┘
#define OFF_CW2T   2438144    // bf16 [512][512]   (end: 2569216 fl)
#define OFF_YA     OFF_AW1T   // f32 1024x512
#define OFF_YQ     OFF_AW2T   // f32 64x512
#define OFF_CHH    OFF_XCB    // f32 16x512
#define OFF_AHHS   OFF_XAB    // bf16 1024x512 (ahh*rg_lo)
#define OFF_QHS    OFF_XQB    // bf16 64x512   (qh*rg_mid)

// WT2 k-tiled layout: element (n, k2) at (k2>>5)*16384 + n*32 + (k2&31).

// ======================== P0: wide prep kernel ==============================
DEV void transpose_tile(const float* __restrict__ src, int koff, int kt, int ct,
                        ushort_t* __restrict__ dst, int ldk, float* sh, int tid) {
  float (*t)[65] = (float(*)[65])sh;
  for (int idx = tid; idx < 4096; idx += 512) {
    const int r = idx >> 6, c = idx & 63;
    t[r][c] = src[(koff + kt + r) * 512 + ct + c];
  }
  __syncthreads();
  for (int idx = tid; idx < 4096; idx += 512) {
    const int c = idx >> 6, r = idx & 63;
    dst[(ct + c) * ldk + kt + r] = f2bf(t[r][c]);
  }
}

// roles: [0,128) WT2 | [128,192) rw1loT | [192,256) rw1midT | [256,320) aw1T
// [320,384) qw1T | [384,512) cw1T | [512,576) aw2T | [576,640) qw2T
// [640,704) cw2T | [704,720) S1/B1 | [720,784) q pool+LN | [784,912) a LN
// [912,928) c concat+LN
__global__ __launch_bounds__(512) void pre0_kernel(
    const float* __restrict__ qa, const float* __restrict__ qm,
    const float* __restrict__ ca, const float* __restrict__ csum,
    const float* __restrict__ ectx,
    const float* __restrict__ qg, const float* __restrict__ qb,
    const float* __restrict__ ag, const float* __restrict__ ab,
    const float* __restrict__ cg, const float* __restrict__ cb,
    const float* __restrict__ rw1, const float* __restrict__ rg,
    const float* __restrict__ rb,
    const float* __restrict__ aw1, const float* __restrict__ qw1,
    const float* __restrict__ cw1, const float* __restrict__ aw2,
    const float* __restrict__ qw2, const float* __restrict__ cw2,
    float* __restrict__ ws) {
  __shared__ float sh[4160];
  const int b = blockIdx.x, tid = threadIdx.x, l = tid & 63, wv = tid >> 6;

  if (b < 128) {
    ushort_t* WT = (ushort_t*)(ws + OFF_WT2);
    float (*t)[65] = (float(*)[65])sh;
    const int kt = (b >> 3) << 6;
    const int ct = (b & 7) << 6;
    for (int idx = tid; idx < 4096; idx += 512) {
      const int r = idx >> 6, c = idx & 63;
      t[r][c] = rg[1024 + kt + r] * rw1[(1024 + kt + r) * 512 + ct + c];
    }
    __syncthreads();
    for (int idx = tid; idx < 4096; idx += 512) {
      const int c = idx >> 6, r = idx & 63;
      const int n = ct + c, k2 = kt + r;
      WT[((k2 >> 5) << 14) + (n << 5) + (k2 & 31)] = f2bf(t[r][c]);
    }
  } else if (b < 192) {
    const int bb = b - 128;
    transpose_tile(rw1, 0, (bb >> 3) << 6, (bb & 7) << 6,
                   (ushort_t*)(ws + OFF_RW1LOT), 512, sh, tid);
  } else if (b < 256) {
    const int bb = b - 192;
    transpose_tile(rw1, 512, (bb >> 3) << 6, (bb & 7) << 6,
                   (ushort_t*)(ws + OFF_RW1MIT), 512, sh, tid);
  } else if (b < 320) {
    const int bb = b - 256;
    transpose_tile(aw1, 0, (bb >> 3) << 6, (bb & 7) << 6,
                   (ushort_t*)(ws + OFF_AW1T), 512, sh, tid);
  } else if (b < 384) {
    const int bb = b - 320;
    transpose_tile(qw1, 0, (bb >> 3) << 6, (bb & 7) << 6,
                   (ushort_t*)(ws + OFF_QW1T), 512, sh, tid);
  } else if (b < 512) {
    const int bb = b - 384;
    transpose_tile(cw1, 0, (bb >> 3) << 6, (bb & 7) << 6,
                   (ushort_t*)(ws + OFF_CW1T), 1024, sh, tid);
  } else if (b < 576) {
    const int bb = b - 512;
    transpose_tile(aw2, 0, (bb >> 3) << 6, (bb & 7) << 6,
                   (ushort_t*)(ws + OFF_AW2T), 512, sh, tid);
  } else if (b < 640) {
    const int bb = b - 576;
    transpose_tile(qw2, 0, (bb >> 3) << 6, (bb & 7) << 6,
                   (ushort_t*)(ws + OFF_QW2T), 512, sh, tid);
  } else if (b < 704) {
    const int bb = b - 640;
    transpose_tile(cw2, 0, (bb >> 3) << 6, (bb & 7) << 6,
                   (ushort_t*)(ws + OFF_CW2T), 512, sh, tid);
  } else if (b < 720) {
    const int kc = (b - 704) << 7;
    float s0 = 0.f, s1 = 0.f, b0 = 0.f, b1v = 0.f;
    for (int k = kc; k < kc + 128; k += 2) {
      const float wa = rw1[(k << 9) + tid];
      const float wb = rw1[((k + 1) << 9) + tid];
      s0 += rg[k] * wa; b0 += rb[k] * wa;
      s1 += rg[k + 1] * wb; b1v += rb[k + 1] * wb;
    }
    atomicAdd(ws + OFF_S1 + tid, s0 + s1);
    atomicAdd(ws + OFF_B1 + tid, b0 + b1v);
  } else if (b < 784) {
    const int q = b - 720;
    if (wv == 0) {
      float m = fmaxf(qm[(q << 6) + l], 0.f);
      sh[l] = m;
      float s = m;
#pragma unroll
      for (int off = 1; off < 64; off <<= 1) s += __shfl_xor(s, off);
      if (l == 0) sh[64] = 1.0f / fmaxf(s, 1e-8f);
    }
    __syncthreads();
    const float sinv = sh[64];
    const float* qaq = qa + (q << 15) + tid;
    float v0 = 0.f, v1 = 0.f, v2 = 0.f, v3 = 0.f;
#pragma unroll 4
    for (int a = 0; a < 64; a += 4) {
      v0 += sh[a] * qaq[a << 9];
      v1 += sh[a + 1] * qaq[(a + 1) << 9];
      v2 += sh[a + 2] * qaq[(a + 2) << 9];
      v3 += sh[a + 3] * qaq[(a + 3) << 9];
    }
    const float v = (v0 + v1 + v2 + v3) * sinv;
    float s = v, ss = v * v;
#pragma unroll
    for (int off = 1; off < 64; off <<= 1) {
      s += __shfl_xor(s, off); ss += __shfl_xor(ss, off);
    }
    if (l == 0) { sh[128 + wv] = s; sh[136 + wv] = ss; }
    __syncthreads();
    float st = 0.f, sst = 0.f;
#pragma unroll
    for (int i = 0; i < 8; ++i) { st += sh[128 + i]; sst += sh[136 + i]; }
    const float mu = st * (1.0f / 512.0f);
    const float rstd = rsqrtf(sst * (1.0f / 512.0f) - mu * mu + 1e-5f);
    ((ushort_t*)(ws + OFF_XQB))[(q << 9) + tid] =
        f2bf((v - mu) * rstd * qg[tid] + qb[tid]);
  } else if (b < 912) {
    const int row = ((b - 784) << 3) + wv;
    const float* crow = ca + (row << 9);
    float x[8];
    float s = 0.f, ss = 0.f;
#pragma unroll
    for (int i = 0; i < 8; ++i) {
      x[i] = crow[l + (i << 6)];
      s += x[i]; ss += x[i] * x[i];
    }
#pragma unroll
    for (int off = 1; off < 64; off <<= 1) {
      s += __shfl_xor(s, off); ss += __shfl_xor(ss, off);
    }
    const float mu = s * (1.0f / 512.0f);
    const float rstd = rsqrtf(ss * (1.0f / 512.0f) - mu * mu + 1e-5f);
    ushort_t* xab = (ushort_t*)(ws + OFF_XAB);
#pragma unroll
    for (int i = 0; i < 8; ++i) {
      const int k = l + (i << 6);
      xab[(row << 9) + k] = f2bf((x[i] - mu) * rstd * ag[k] + ab[k]);
    }
  } else {
    const int w = b - 912;
    const float v0 = csum[(w << 9) + tid];
    const float v1 = ectx[(w << 9) + tid];
    float s = v0 + v1, ss = v0 * v0 + v1 * v1;
#pragma unroll
    for (int off = 1; off < 64; off <<= 1) {
      s += __shfl_xor(s, off); ss += __shfl_xor(ss, off);
    }
    if (l == 0) { sh[wv] = s; sh[8 + wv] = ss; }
    __syncthreads();
    float st = 0.f, sst = 0.f;
#pragma unroll
    for (int i = 0; i < 8; ++i) { st += sh[i]; sst += sh[8 + i]; }
    const float mu = st * (1.0f / 1024.0f);
    const float rstd = rsqrtf(sst * (1.0f / 1024.0f) - mu * mu + 1e-5f);
    ushort_t* xcb = (ushort_t*)(ws + OFF_XCB);
    xcb[(w << 10) + tid] = f2bf((v0 - mu) * rstd * cg[tid] + cb[tid]);
    xcb[(w << 10) + 512 + tid] =
        f2bf((v1 - mu) * rstd * cg[512 + tid] + cb[512 + tid]);
  }
}

// ======================== MFMA GEMM phases (32x32 tiles/wave) ===============
// Each wave computes a 32x32 tile: acc[2][2]=16 regs. Tile t: rt=t>>4, ct=t&15.
// PHASE 1: H = gelu(X@W1 + b1) -> bf16.  PHASE 2: L2 = H@W2 + b2 -> f32
// (+ scaled bf16 copy).  PHASE 3: Y = S @ rw1T -> f32 (no bias).
template <int PHASE>
__global__ __launch_bounds__(256) void gemm_kernel(
    float* __restrict__ ws, const float* __restrict__ ba,
    const float* __restrict__ bq, const float* __restrict__ bc,
    const float* __restrict__ rg) {
  const int b = blockIdx.x, tid = threadIdx.x;
  const int l = tid & 63, wv = tid >> 6;

  const ushort_t* A; const ushort_t* BT;
  float* outF = nullptr; ushort_t* outB = nullptr; ushort_t* outS = nullptr;
  const float* bias = nullptr; const float* scl = nullptr;
  int M, K, t;

  if (PHASE == 1) {
    if (b < 128) {
      A = (const ushort_t*)(ws + OFF_XAB); BT = (const ushort_t*)(ws + OFF_AW1T);
      M = 1024; K = 512; outB = (ushort_t*)(ws + OFF_HAB); bias = ba;
      t = (b << 2) + wv;
    } else if (b < 136) {
      A = (const ushort_t*)(ws + OFF_XQB); BT = (const ushort_t*)(ws + OFF_QW1T);
      M = 64; K = 512; outB = (ushort_t*)(ws + OFF_HQB); bias = bq;
      t = ((b - 128) << 2) + wv;
    } else {
      A = (const ushort_t*)(ws + OFF_XCB); BT = (const ushort_t*)(ws + OFF_CW1T);
      M = 16; K = 1024; outB = (ushort_t*)(ws + OFF_HCB); bias = bc;
      t = ((b - 136) << 2) + wv;
    }
  } else if (PHASE == 2) {
    if (b < 128) {
      A = (const ushort_t*)(ws + OFF_HAB); BT = (const ushort_t*)(ws + OFF_AW2T);
      M = 1024; K = 512; outF = ws + OFF_AHH;
      outS = (ushort_t*)(ws + OFF_AHHS); bias = ba; scl = rg;
      t = (b << 2) + wv;
    } else if (b < 136) {
      A = (const ushort_t*)(ws + OFF_HQB); BT = (const ushort_t*)(ws + OFF_QW2T);
      M = 64; K = 512; outF = ws + OFF_QH;
      outS = (ushort_t*)(ws + OFF_QHS); bias = bq; scl = rg + 512;
      t = ((b - 128) << 2) + wv;
    } else {
      A = (const ushort_t*)(ws + OFF_HCB); BT = (const ushort_t*)(ws + OFF_CW2T);
      M = 16; K = 512; outF = ws + OFF_CHH; bias = bc;
      t = ((b - 136) << 2) + wv;
    }
  } else {
    if (b < 128) {
      A = (const ushort_t*)(ws + OFF_AHHS); BT = (const ushort_t*)(ws + OFF_RW1LOT);
      M = 1024; K = 512; outF = ws + OFF_YA;
      t = (b << 2) + wv;
    } else {
      A = (const ushort_t*)(ws + OFF_QHS); BT = (const ushort_t*)(ws + OFF_RW1MIT);
      M = 64; K = 512; outF = ws + OFF_YQ;
      t = ((b - 128) << 2) + wv;
    }
  }

  const int rt = t >> 4, ct = t & 15;
  const int r0 = rt << 5, c0 = ct << 5;
  const int kh = (l >> 4) << 3;
  const ushort_t* ap[2];
  const ushort_t* bp[2];
#pragma unroll
  for (int fr = 0; fr < 2; ++fr) {
    int r = r0 + (fr << 4) + (l & 15);
    if (r > M - 1) r = M - 1;          // row clamp for small-M tiles
    ap[fr] = A + r * K + kh;
  }
#pragma unroll
  for (int cf = 0; cf < 2; ++cf)
    bp[cf] = BT + (c0 + (cf << 4) + (l & 15)) * K + kh;

  f32x4 acc[2][2] = {};
  const int nst = K >> 5;
#pragma unroll 4
  for (int ks = 0; ks < nst; ++ks) {
    bf16x8 afr[2], bfr[2];
#pragma unroll
    for (int fr = 0; fr < 2; ++fr)
      afr[fr] = __builtin_bit_cast(bf16x8, *(const uint4*)(ap[fr] + (ks << 5)));
#pragma unroll
    for (int cf = 0; cf < 2; ++cf)
      bfr[cf] = __builtin_bit_cast(bf16x8, *(const uint4*)(bp[cf] + (ks << 5)));
#pragma unroll
    for (int fr = 0; fr < 2; ++fr)
#pragma unroll
      for (int cf = 0; cf < 2; ++cf)
        acc[fr][cf] = __builtin_amdgcn_mfma_f32_16x16x32_bf16(
            afr[fr], bfr[cf], acc[fr][cf], 0, 0, 0);
  }

  // epilogue (C layout: col = l&15 (+16cf), row = (l>>4)*4 + j (+16fr))
  const int rsub = (l >> 4) << 2, cl = l & 15;
#pragma unroll
  for (int fr = 0; fr < 2; ++fr) {
#pragma unroll
    for (int cf = 0; cf < 2; ++cf) {
      const int col = c0 + (cf << 4) + cl;
#pragma unroll
      for (int j = 0; j < 4; ++j) {
        const int row = r0 + (fr << 4) + rsub + j;
        if (row < M) {
          float v = acc[fr][cf][j];
          if (PHASE == 1) {
            outB[(row << 9) + col] = f2bf(gelu_fast(v + bias[col]));
          } else if (PHASE == 2) {
            v += bias[col];
            outF[(row << 9) + col] = v;
            if (outS) outS[(row << 9) + col] = f2bf(v * scl[col]);
          } else {
            outF[(row << 9) + col] = v;
          }
        }
      }
    }
  }
}

// ---------------------------- main fused kernel -----------------------------
// 1 block per (q,w), 1024 threads = 16 waves, wave -> 64 rows x 32 cols.
// 4 K-chunks of 256, double-buffered 32KB LDS; per chunk: issue next chunk's
// global A loads -> MFMA current (depth-2 B prefetch) -> build next -> barrier.
__global__ __launch_bounds__(1024, 4) void main_kernel(
    const float* __restrict__ AH, const float* __restrict__ QH,
    const float* __restrict__ CH, const ushort_t* __restrict__ WT2,
    const float* __restrict__ Ya, const float* __restrict__ Yq,
    const float* __restrict__ S1, const float* __restrict__ B1,
    const float* __restrict__ rb1, const float* __restrict__ rw2,
    const float* __restrict__ rb2, const float* __restrict__ cmass,
    float* __restrict__ out) {
  extern __shared__ char smem_raw[];
  float* qs = (float*)smem_raw;          // 512
  float* cs = qs + 512;                  // 512
  float* s1_s = cs + 512;                // 64
  float* s2_s = s1_s + 64;               // 64
  float* rel_s = s2_s + 64;              // 64
  float* misc = rel_s + 64;              // 2 (+pad to 5120 B)
  uint4* apv = (uint4*)(smem_raw + 5120);  // 2 x 32KB

  const int tid = threadIdx.x;
  const int l = tid & 63;
  const int wv = tid >> 6;               // 0..15
  const int q = blockIdx.x >> 4;
  const int w = blockIdx.x & 15;

  if (tid < 512) qs[tid] = QH[(q << 9) + tid];
  else cs[tid - 512] = CH[(w << 9) + (tid - 512)];
  if (tid < 64) { s1_s[tid] = 0.f; s2_s[tid] = 0.f; rel_s[tid] = 0.f; }
  __syncthreads();

  const int rloc = ((wv & 3) << 4) + (l & 15);
  const float* arow = AH + (((w << 6) + rloc) << 9);
  const int kh = (l >> 4) << 3;          // 0,8,16,24
  const int par = wv >> 2;               // 0..3
  float s1a = 0.f, s2a = 0.f;
  float4 pav[2][2];

#define BUILD_LOAD(C) do { \
    _Pragma("unroll") for (int i_ = 0; i_ < 2; ++i_) { \
      const int ks_ = ((C) << 3) + par + (i_ << 2); \
      const int ka_ = ((ks_ << 5) + kh) & 511; \
      pav[i_][0] = *(const float4*)(arow + ka_); \
      pav[i_][1] = *(const float4*)(arow + ka_ + 4); \
    } } while (0)

#define BUILD_STORE(C, B) do { \
    _Pragma("unroll") for (int i_ = 0; i_ < 2; ++i_) { \
      const int ksl_ = par + (i_ << 2); \
      const int ka_ = (((((C) << 3) + ksl_) << 5) + kh) & 511; \
      const float av_[8] = {pav[i_][0].x, pav[i_][0].y, pav[i_][0].z, pav[i_][0].w, \
                            pav[i_][1].x, pav[i_][1].y, pav[i_][1].z, pav[i_][1].w}; \
      const float4 q0_ = *(const float4*)(qs + ka_); \
      const float4 q1_ = *(const float4*)(qs + ka_ + 4); \
      const float qv_[8] = {q0_.x, q0_.y, q0_.z, q0_.w, q1_.x, q1_.y, q1_.z, q1_.w}; \
      float vv_[8]; \
      if ((C) < 2) { \
        _Pragma("unroll") for (int j_ = 0; j_ < 8; ++j_) { \
          const float aq_ = av_[j_] * qv_[j_]; \
          vv_[j_] = aq_; \
          s1a += av_[j_] + aq_; \
          s2a += av_[j_] * av_[j_] + aq_ * aq_; \
        } \
      } else { \
        const float4 c0_ = *(const float4*)(cs + ka_); \
        const float4 c1_ = *(const float4*)(cs + ka_ + 4); \
        const float cv_[8] = {c0_.x, c0_.y, c0_.z, c0_.w, c1_.x, c1_.y, c1_.z, c1_.w}; \
        _Pragma("unroll") for (int j_ = 0; j_ < 8; ++j_) { \
          const float dd_ = fabsf(av_[j_] - qv_[j_]) + cv_[j_]; \
          vv_[j_] = dd_; \
          s1a += dd_; \
          s2a += dd_ * dd_; \
        } \
      } \
      union { __bf16 bv[8]; uint4 u4; } pk_; \
      _Pragma("unroll") for (int j_ = 0; j_ < 8; ++j_) pk_.bv[j_] = (__bf16)vv_[j_]; \
      apv[((B) << 11) + (ksl_ << 8) + ((wv & 3) << 6) + l] = pk_.u4; \
    } } while (0)

  // ---- prologue: build chunk 0 into buf 0 + q-segment stats
  BUILD_LOAD(0);
  BUILD_STORE(0, 0);
  if (wv == 0) {
    float sq = 0.f, sqq = 0.f;
#pragma unroll
    for (int it = 0; it < 8; ++it) {
      const float vq = qs[l + (it << 6)];
      sq += vq; sqq += vq * vq;
    }
#pragma unroll
    for (int off = 1; off < 64; off <<= 1) {
      sq += __shfl_xor(sq, off); sqq += __shfl_xor(sqq, off);
    }
    if (l == 0) { misc[0] = sq; misc[1] = sqq; }
  }
  __syncthreads();

  // ---- pipelined chunk loop: wave wv owns cols [wv*32, wv*32+32) ----------
  f32x4 acc[4][2] = {};
  const int ncb = (wv << 5) + (l & 15);
#pragma unroll
  for (int c = 0; c < 4; ++c) {
    if (c < 3) BUILD_LOAD(c + 1);        // next-chunk A loads in flight
    const uint4* cbuf = apv + ((c & 1) << 11);
    // B pointers for this chunk (k-tiled WT2: ksl stride = 1<<14 elements)
    const ushort_t* wc0 = WT2 + ((c << 3) << 14) + (ncb << 5) + kh;
    const ushort_t* wc1 = wc0 + (16 << 5);
    // depth-2 static B prefetch
    uint4 bA0 = *(const uint4*)(wc0);
    uint4 bB0 = *(const uint4*)(wc1);
    uint4 bA1 = *(const uint4*)(wc0 + (1 << 14));
    uint4 bB1 = *(const uint4*)(wc1 + (1 << 14));
#pragma unroll
    for (int ksl = 0; ksl < 8; ++ksl) {
      const bf16x8 bf0 =
          __builtin_bit_cast(bf16x8, (ksl & 1) ? bA1 : bA0);
      const bf16x8 bf1 =
          __builtin_bit_cast(bf16x8, (ksl & 1) ? bB1 : bB0);
      if (ksl < 6) {
        if (ksl & 1) {
          bA1 = *(const uint4*)(wc0 + ((ksl + 2) << 14));
          bB1 = *(const uint4*)(wc1 + ((ksl + 2) << 14));
        } else {
          bA0 = *(const uint4*)(wc0 + ((ksl + 2) << 14));
          bB0 = *(const uint4*)(wc1 + ((ksl + 2) << 14));
        }
      }
      bf16x8 afr[4];
#pragma unroll
      for (int fr = 0; fr < 4; ++fr)
        afr[fr] = __builtin_bit_cast(bf16x8, cbuf[(ksl << 8) + (fr << 6) + l]);
#pragma unroll
      for (int fr = 0; fr < 4; ++fr) {
        acc[fr][0] = __builtin_amdgcn_mfma_f32_16x16x32_bf16(
            afr[fr], bf0, acc[fr][0], 0, 0, 0);
        acc[fr][1] = __builtin_amdgcn_mfma_f32_16x16x32_bf16(
            afr[fr], bf1, acc[fr][1], 0, 0, 0);
      }
    }
    if (c == 0) BUILD_STORE(1, 1);
    if (c == 1) BUILD_STORE(2, 0);
    if (c == 2) {
      BUILD_STORE(3, 1);
      s1a += __shfl_xor(s1a, 16); s1a += __shfl_xor(s1a, 32);
      s2a += __shfl_xor(s2a, 16); s2a += __shfl_xor(s2a, 32);
      if ((l >> 4) == 0) {
        atomicAdd(&s1_s[rloc], s1a);
        atomicAdd(&s2_s[rloc], s2a);
      }
    }
    __syncthreads();
  }
#undef BUILD_LOAD
#undef BUILD_STORE

  // ---- epilogue: LN-fold + gelu + dot(rw2) -> per-row relevance -----------
  {
    const float sqt = misc[0], sqqt = misc[1];
    float yqv[2], s1c[2], b1c[2], w2c[2];
#pragma unroll
    for (int cf = 0; cf < 2; ++cf) {
      const int n = ncb + (cf << 4);
      yqv[cf] = Yq[(q << 9) + n];
      s1c[cf] = S1[n];
      b1c[cf] = B1[n] + rb1[n];
      w2c[cf] = rw2[n];
    }
    const float* yab = Ya + (w << 15) + ncb;
    const int rsub = (l >> 4) << 2;
#pragma unroll
    for (int fr = 0; fr < 4; ++fr) {
#pragma unroll
      for (int j = 0; j < 4; ++j) {
        const int r = (fr << 4) + rsub + j;
        const float s1r = s1_s[r] + sqt;
        const float s2r = s2_s[r] + sqqt;
        const float mu = s1r * (1.0f / 2048.0f);
        const float rs = rsqrtf(s2r * (1.0f / 2048.0f) - mu * mu + 1e-5f);
        float rp = 0.f;
#pragma unroll
        for (int cf = 0; cf < 2; ++cf) {
          const float ya = yab[(r << 9) + (cf << 4)];
          const float hp = rs * (acc[fr][cf][j] + ya + yqv[cf] - mu * s1c[cf]) + b1c[cf];
          rp += gelu_fast(hp) * w2c[cf];
        }
        rp += __shfl_xor(rp, 1); rp += __shfl_xor(rp, 2);
        rp += __shfl_xor(rp, 4); rp += __shfl_xor(rp, 8);
        if ((l & 15) == 0) atomicAdd(&rel_s[r], rp);
      }
    }
  }
  __syncthreads();

  // ---- softmax over atoms + entropy (wave 0)
  if (tid < 64) {
    const float relv = rel_s[tid] + rb2[0];
    const float x = logf(fmaxf(cmass[(w << 6) + tid], 1e-8f)) + relv;
    float m = x;
#pragma unroll
    for (int off = 1; off < 64; off <<= 1) m = fmaxf(m, __shfl_xor(m, off));
    const float p = expf(x - m);
    float s = p;
#pragma unroll
    for (int off = 1; off < 64; off <<= 1) s += __shfl_xor(s, off);
    float mix = p / fmaxf(s, 1e-8f);
    float s2 = mix;
#pragma unroll
    for (int off = 1; off < 64; off <<= 1) s2 += __shfl_xor(s2, off);
    mix = mix / fmaxf(s2, 1e-8f);
    const float et = -mix * logf(fmaxf(mix, 1e-8f));
    float ent = et;
#pragma unroll
    for (int off = 1; off < 64; off <<= 1) ent += __shfl_xor(ent, off);
    out[(blockIdx.x << 6) + tid] = mix;                 // mixed[q][w][a]
    if (tid == 0) out[65536 + blockIdx.x] = ent;        // entropy[q][w]
  }
}

// ---------------------------------------------------------------------------
extern "C" void kernel_launch(void* const* d_in, const int* in_sizes, int n_in,
                              void* d_out, int out_size, void* d_ws, size_t ws_size,
                              hipStream_t stream) {
  (void)in_sizes; (void)n_in; (void)out_size; (void)ws_size;
  const float* q_atoms = (const float*)d_in[0];
  const float* q_mass  = (const float*)d_in[1];
  const float* c_atoms = (const float*)d_in[2];
  const float* c_mass  = (const float*)d_in[3];
  const float* c_sum   = (const float*)d_in[4];
  const float* e_ctx   = (const float*)d_in[5];
  const float* qg  = (const float*)d_in[6];  const float* qb  = (const float*)d_in[7];
  const float* qw1 = (const float*)d_in[8];  const float* qb1 = (const float*)d_in[9];
  const float* qw2 = (const float*)d_in[10]; const float* qb2 = (const float*)d_in[11];
  const float* ag  = (const float*)d_in[12]; const float* ab  = (const float*)d_in[13];
  const float* aw1 = (const float*)d_in[14]; const float* ab1 = (const float*)d_in[15];
  const float* aw2 = (const float*)d_in[16]; const float* ab2 = (const float*)d_in[17];
  const float* cg  = (const float*)d_in[18]; const float* cb  = (const float*)d_in[19];
  const float* cw1 = (const float*)d_in[20]; const float* cb1 = (const float*)d_in[21];
  const float* cw2 = (const float*)d_in[22]; const float* cb2 = (const float*)d_in[23];
  const float* rg  = (const float*)d_in[24]; const float* rb  = (const float*)d_in[25];
  const float* rw1 = (const float*)d_in[26]; const float* rb1 = (const float*)d_in[27];
  const float* rw2 = (const float*)d_in[28]; const float* rb2 = (const float*)d_in[29];

  float* ws = (float*)d_ws;
  float* out = (float*)d_out;

  hipMemsetAsync(ws + OFF_S1, 0, 1024 * sizeof(float), stream);  // S1+B1
  pre0_kernel<<<928, 512, 0, stream>>>(q_atoms, q_mass, c_atoms, c_sum, e_ctx,
                                       qg, qb, ag, ab, cg, cb, rw1, rg, rb,
                                       aw1, qw1, cw1, aw2, qw2, cw2, ws);
  gemm_kernel<1><<<140, 256, 0, stream>>>(ws, ab1, qb1, cb1, rg);
  gemm_kernel<2><<<140, 256, 0, stream>>>(ws, ab2, qb2, cb2, rg);
  gemm_kernel<3><<<136, 256, 0, stream>>>(ws, nullptr, nullptr, nullptr, rg);

  static const size_t MAIN_SMEM = 5120 + 65536;  // 70656 B
  hipFuncSetAttribute((const void*)main_kernel,
                      hipFuncAttributeMaxDynamicSharedMemorySize, (int)MAIN_SMEM);
  main_kernel<<<1024, 1024, MAIN_SMEM, stream>>>(
      ws + OFF_AHH, ws + OFF_QH, ws + OFF_CHH,
      (const ushort_t*)(ws + OFF_WT2), ws + OFF_YA, ws + OFF_YQ,
      ws + OFF_S1, ws + OFF_B1, rb1, rw2, rb2, c_mass, out);
}

// Round 9
// 194.989 us; speedup vs baseline: 1.5808x; 1.0192x over previous
//
#include <hip/hip_runtime.h>

// ---------------------------------------------------------------------------
// QueryConditionedTransportScorerV3 on MI355X (gfx950)
// Q=64 W=16 A=64 D=H=512.
//   fused@rw1 = Ya[w,a] + Yq[q] + [a*q ; |a-q|+c] @ (rg*rw1)[1024:2048] (MFMA)
//   h = rstd*(sum - mu*S1) + (rb1 + rb@rw1); gelu; @rw2; softmax+entropy fused
// Round 9: main kernel batches 2 q per block (same w) -> B/WT2 L2 traffic and
//   Ya loads halved, half the blocks. K-chunk 128, 8 chunks, 4x16KB dbuf,
//   acc0+acc1 = 64 regs (no pav-through-MFMA to stay under the 128 cap).
// ---------------------------------------------------------------------------

#define DEV static __device__ __forceinline__

typedef __attribute__((ext_vector_type(8))) __bf16 bf16x8;
typedef __attribute__((ext_vector_type(4))) float f32x4;
typedef unsigned short ushort_t;

DEV ushort_t f2bf(float f) {
  unsigned u = __builtin_bit_cast(unsigned, f);
  u = (u + 0x7fffu + ((u >> 16) & 1u)) >> 16;
  return (ushort_t)u;
}

// branch-free erf (Abramowitz-Stegun 7.1.26, |err| <= 1.5e-7)
DEV float gelu_fast(float x) {
  const float y = x * 0.70710678118654752f;
  const float z = fabsf(y);
  const float t = __fdividef(1.0f, 1.0f + 0.3275911f * z);
  float p = 1.061405429f;
  p = p * t - 1.453152027f;
  p = p * t + 1.421413741f;
  p = p * t - 0.284496736f;
  p = p * t + 0.254829592f;
  const float e = 1.0f - p * t * __expf(-z * z);
  const float erfv = copysignf(e, y);
  return 0.5f * x * (1.0f + erfv);
}

// ---- ws layout (float offsets) --------------------------------------------
#define OFF_XQB    0          // bf16 64x512    (aliased by QHS after P1)
#define OFF_XAB    16384      // bf16 1024x512  (aliased by AHHS after P1)
#define OFF_XCB    278528     // bf16 16x1024   (aliased by CHH f32 after P1)
#define OFF_HAB    286720     // bf16 1024x512
#define OFF_HQB    548864     // bf16 64x512
#define OFF_HCB    565248     // bf16 16x512
#define OFF_AHH    569344     // f32 1024x512
#define OFF_QH     1093632    // f32 64x512
#define OFF_S1     1126400    // f32 512
#define OFF_B1     1126912    // f32 512
#define OFF_WT2    1127424    // bf16 k-tiled hi rw1 (rg-scaled), 524288 el
#define OFF_RW1LOT 1389568    // bf16 [512n][512k] rw1[0:512]
#define OFF_RW1MIT 1520640    // bf16 [512n][512k] rw1[512:1024]
#define OFF_AW1T   1651712    // bf16 [512][512]   ┐
#define OFF_QW1T   1782784    // bf16 [512][512]   ├ dead after P1 -> YA
#define OFF_CW1T   1913856    // bf16 [512][1024]  ┘
#define OFF_AW2T   2176000    // bf16 [512][512]   ┐ dead after P2 -> YQ
#define OFF_QW2T   2307072    // bf16 [512][512]   ┘
#define OFF_CW2T   2438144    // bf16 [512][512]   (end: 2569216 fl)
#define OFF_YA     OFF_AW1T   // f32 1024x512
#define OFF_YQ     OFF_AW2T   // f32 64x512
#define OFF_CHH    OFF_XCB    // f32 16x512
#define OFF_AHHS   OFF_XAB    // bf16 1024x512 (ahh*rg_lo)
#define OFF_QHS    OFF_XQB    // bf16 64x512   (qh*rg_mid)

// WT2 k-tiled layout: element (n, k2) at (k2>>5)*16384 + n*32 + (k2&31).

// ======================== P0: wide prep kernel ==============================
DEV void transpose_tile(const float* __restrict__ src, int koff, int kt, int ct,
                        ushort_t* __restrict__ dst, int ldk, float* sh, int tid) {
  float (*t)[65] = (float(*)[65])sh;
  for (int idx = tid; idx < 4096; idx += 512) {
    const int r = idx >> 6, c = idx & 63;
    t[r][c] = src[(koff + kt + r) * 512 + ct + c];
  }
  __syncthreads();
  for (int idx = tid; idx < 4096; idx += 512) {
    const int c = idx >> 6, r = idx & 63;
    dst[(ct + c) * ldk + kt + r] = f2bf(t[r][c]);
  }
}

// roles: [0,128) WT2 | [128,192) rw1loT | [192,256) rw1midT | [256,320) aw1T
// [320,384) qw1T | [384,512) cw1T | [512,576) aw2T | [576,640) qw2T
// [640,704) cw2T | [704,720) S1/B1 | [720,784) q pool+LN | [784,912) a LN
// [912,928) c concat+LN
__global__ __launch_bounds__(512) void pre0_kernel(
    const float* __restrict__ qa, const float* __restrict__ qm,
    const float* __restrict__ ca, const float* __restrict__ csum,
    const float* __restrict__ ectx,
    const float* __restrict__ qg, const float* __restrict__ qb,
    const float* __restrict__ ag, const float* __restrict__ ab,
    const float* __restrict__ cg, const float* __restrict__ cb,
    const float* __restrict__ rw1, const float* __restrict__ rg,
    const float* __restrict__ rb,
    const float* __restrict__ aw1, const float* __restrict__ qw1,
    const float* __restrict__ cw1, const float* __restrict__ aw2,
    const float* __restrict__ qw2, const float* __restrict__ cw2,
    float* __restrict__ ws) {
  __shared__ float sh[4160];
  const int b = blockIdx.x, tid = threadIdx.x, l = tid & 63, wv = tid >> 6;

  if (b < 128) {
    ushort_t* WT = (ushort_t*)(ws + OFF_WT2);
    float (*t)[65] = (float(*)[65])sh;
    const int kt = (b >> 3) << 6;
    const int ct = (b & 7) << 6;
    for (int idx = tid; idx < 4096; idx += 512) {
      const int r = idx >> 6, c = idx & 63;
      t[r][c] = rg[1024 + kt + r] * rw1[(1024 + kt + r) * 512 + ct + c];
    }
    __syncthreads();
    for (int idx = tid; idx < 4096; idx += 512) {
      const int c = idx >> 6, r = idx & 63;
      const int n = ct + c, k2 = kt + r;
      WT[((k2 >> 5) << 14) + (n << 5) + (k2 & 31)] = f2bf(t[r][c]);
    }
  } else if (b < 192) {
    const int bb = b - 128;
    transpose_tile(rw1, 0, (bb >> 3) << 6, (bb & 7) << 6,
                   (ushort_t*)(ws + OFF_RW1LOT), 512, sh, tid);
  } else if (b < 256) {
    const int bb = b - 192;
    transpose_tile(rw1, 512, (bb >> 3) << 6, (bb & 7) << 6,
                   (ushort_t*)(ws + OFF_RW1MIT), 512, sh, tid);
  } else if (b < 320) {
    const int bb = b - 256;
    transpose_tile(aw1, 0, (bb >> 3) << 6, (bb & 7) << 6,
                   (ushort_t*)(ws + OFF_AW1T), 512, sh, tid);
  } else if (b < 384) {
    const int bb = b - 320;
    transpose_tile(qw1, 0, (bb >> 3) << 6, (bb & 7) << 6,
                   (ushort_t*)(ws + OFF_QW1T), 512, sh, tid);
  } else if (b < 512) {
    const int bb = b - 384;
    transpose_tile(cw1, 0, (bb >> 3) << 6, (bb & 7) << 6,
                   (ushort_t*)(ws + OFF_CW1T), 1024, sh, tid);
  } else if (b < 576) {
    const int bb = b - 512;
    transpose_tile(aw2, 0, (bb >> 3) << 6, (bb & 7) << 6,
                   (ushort_t*)(ws + OFF_AW2T), 512, sh, tid);
  } else if (b < 640) {
    const int bb = b - 576;
    transpose_tile(qw2, 0, (bb >> 3) << 6, (bb & 7) << 6,
                   (ushort_t*)(ws + OFF_QW2T), 512, sh, tid);
  } else if (b < 704) {
    const int bb = b - 640;
    transpose_tile(cw2, 0, (bb >> 3) << 6, (bb & 7) << 6,
                   (ushort_t*)(ws + OFF_CW2T), 512, sh, tid);
  } else if (b < 720) {
    const int kc = (b - 704) << 7;
    float s0 = 0.f, s1 = 0.f, b0 = 0.f, b1v = 0.f;
    for (int k = kc; k < kc + 128; k += 2) {
      const float wa = rw1[(k << 9) + tid];
      const float wb = rw1[((k + 1) << 9) + tid];
      s0 += rg[k] * wa; b0 += rb[k] * wa;
      s1 += rg[k + 1] * wb; b1v += rb[k + 1] * wb;
    }
    atomicAdd(ws + OFF_S1 + tid, s0 + s1);
    atomicAdd(ws + OFF_B1 + tid, b0 + b1v);
  } else if (b < 784) {
    const int q = b - 720;
    if (wv == 0) {
      float m = fmaxf(qm[(q << 6) + l], 0.f);
      sh[l] = m;
      float s = m;
#pragma unroll
      for (int off = 1; off < 64; off <<= 1) s += __shfl_xor(s, off);
      if (l == 0) sh[64] = 1.0f / fmaxf(s, 1e-8f);
    }
    __syncthreads();
    const float sinv = sh[64];
    const float* qaq = qa + (q << 15) + tid;
    float v0 = 0.f, v1 = 0.f, v2 = 0.f, v3 = 0.f;
#pragma unroll 4
    for (int a = 0; a < 64; a += 4) {
      v0 += sh[a] * qaq[a << 9];
      v1 += sh[a + 1] * qaq[(a + 1) << 9];
      v2 += sh[a + 2] * qaq[(a + 2) << 9];
      v3 += sh[a + 3] * qaq[(a + 3) << 9];
    }
    const float v = (v0 + v1 + v2 + v3) * sinv;
    float s = v, ss = v * v;
#pragma unroll
    for (int off = 1; off < 64; off <<= 1) {
      s += __shfl_xor(s, off); ss += __shfl_xor(ss, off);
    }
    if (l == 0) { sh[128 + wv] = s; sh[136 + wv] = ss; }
    __syncthreads();
    float st = 0.f, sst = 0.f;
#pragma unroll
    for (int i = 0; i < 8; ++i) { st += sh[128 + i]; sst += sh[136 + i]; }
    const float mu = st * (1.0f / 512.0f);
    const float rstd = rsqrtf(sst * (1.0f / 512.0f) - mu * mu + 1e-5f);
    ((ushort_t*)(ws + OFF_XQB))[(q << 9) + tid] =
        f2bf((v - mu) * rstd * qg[tid] + qb[tid]);
  } else if (b < 912) {
    const int row = ((b - 784) << 3) + wv;
    const float* crow = ca + (row << 9);
    float x[8];
    float s = 0.f, ss = 0.f;
#pragma unroll
    for (int i = 0; i < 8; ++i) {
      x[i] = crow[l + (i << 6)];
      s += x[i]; ss += x[i] * x[i];
    }
#pragma unroll
    for (int off = 1; off < 64; off <<= 1) {
      s += __shfl_xor(s, off); ss += __shfl_xor(ss, off);
    }
    const float mu = s * (1.0f / 512.0f);
    const float rstd = rsqrtf(ss * (1.0f / 512.0f) - mu * mu + 1e-5f);
    ushort_t* xab = (ushort_t*)(ws + OFF_XAB);
#pragma unroll
    for (int i = 0; i < 8; ++i) {
      const int k = l + (i << 6);
      xab[(row << 9) + k] = f2bf((x[i] - mu) * rstd * ag[k] + ab[k]);
    }
  } else {
    const int w = b - 912;
    const float v0 = csum[(w << 9) + tid];
    const float v1 = ectx[(w << 9) + tid];
    float s = v0 + v1, ss = v0 * v0 + v1 * v1;
#pragma unroll
    for (int off = 1; off < 64; off <<= 1) {
      s += __shfl_xor(s, off); ss += __shfl_xor(ss, off);
    }
    if (l == 0) { sh[wv] = s; sh[8 + wv] = ss; }
    __syncthreads();
    float st = 0.f, sst = 0.f;
#pragma unroll
    for (int i = 0; i < 8; ++i) { st += sh[i]; sst += sh[8 + i]; }
    const float mu = st * (1.0f / 1024.0f);
    const float rstd = rsqrtf(sst * (1.0f / 1024.0f) - mu * mu + 1e-5f);
    ushort_t* xcb = (ushort_t*)(ws + OFF_XCB);
    xcb[(w << 10) + tid] = f2bf((v0 - mu) * rstd * cg[tid] + cb[tid]);
    xcb[(w << 10) + 512 + tid] =
        f2bf((v1 - mu) * rstd * cg[512 + tid] + cb[512 + tid]);
  }
}

// ======================== MFMA GEMM phases (32x32 tiles/wave) ===============
template <int PHASE>
__global__ __launch_bounds__(256) void gemm_kernel(
    float* __restrict__ ws, const float* __restrict__ ba,
    const float* __restrict__ bq, const float* __restrict__ bc,
    const float* __restrict__ rg) {
  const int b = blockIdx.x, tid = threadIdx.x;
  const int l = tid & 63, wv = tid >> 6;

  const ushort_t* A; const ushort_t* BT;
  float* outF = nullptr; ushort_t* outB = nullptr; ushort_t* outS = nullptr;
  const float* bias = nullptr; const float* scl = nullptr;
  int M, K, t;

  if (PHASE == 1) {
    if (b < 128) {
      A = (const ushort_t*)(ws + OFF_XAB); BT = (const ushort_t*)(ws + OFF_AW1T);
      M = 1024; K = 512; outB = (ushort_t*)(ws + OFF_HAB); bias = ba;
      t = (b << 2) + wv;
    } else if (b < 136) {
      A = (const ushort_t*)(ws + OFF_XQB); BT = (const ushort_t*)(ws + OFF_QW1T);
      M = 64; K = 512; outB = (ushort_t*)(ws + OFF_HQB); bias = bq;
      t = ((b - 128) << 2) + wv;
    } else {
      A = (const ushort_t*)(ws + OFF_XCB); BT = (const ushort_t*)(ws + OFF_CW1T);
      M = 16; K = 1024; outB = (ushort_t*)(ws + OFF_HCB); bias = bc;
      t = ((b - 136) << 2) + wv;
    }
  } else if (PHASE == 2) {
    if (b < 128) {
      A = (const ushort_t*)(ws + OFF_HAB); BT = (const ushort_t*)(ws + OFF_AW2T);
      M = 1024; K = 512; outF = ws + OFF_AHH;
      outS = (ushort_t*)(ws + OFF_AHHS); bias = ba; scl = rg;
      t = (b << 2) + wv;
    } else if (b < 136) {
      A = (const ushort_t*)(ws + OFF_HQB); BT = (const ushort_t*)(ws + OFF_QW2T);
      M = 64; K = 512; outF = ws + OFF_QH;
      outS = (ushort_t*)(ws + OFF_QHS); bias = bq; scl = rg + 512;
      t = ((b - 128) << 2) + wv;
    } else {
      A = (const ushort_t*)(ws + OFF_HCB); BT = (const ushort_t*)(ws + OFF_CW2T);
      M = 16; K = 512; outF = ws + OFF_CHH; bias = bc;
      t = ((b - 136) << 2) + wv;
    }
  } else {
    if (b < 128) {
      A = (const ushort_t*)(ws + OFF_AHHS); BT = (const ushort_t*)(ws + OFF_RW1LOT);
      M = 1024; K = 512; outF = ws + OFF_YA;
      t = (b << 2) + wv;
    } else {
      A = (const ushort_t*)(ws + OFF_QHS); BT = (const ushort_t*)(ws + OFF_RW1MIT);
      M = 64; K = 512; outF = ws + OFF_YQ;
      t = ((b - 128) << 2) + wv;
    }
  }

  const int rt = t >> 4, ct = t & 15;
  const int r0 = rt << 5, c0 = ct << 5;
  const int kh = (l >> 4) << 3;
  const ushort_t* ap[2];
  const ushort_t* bp[2];
#pragma unroll
  for (int fr = 0; fr < 2; ++fr) {
    int r = r0 + (fr << 4) + (l & 15);
    if (r > M - 1) r = M - 1;          // row clamp for small-M tiles
    ap[fr] = A + r * K + kh;
  }
#pragma unroll
  for (int cf = 0; cf < 2; ++cf)
    bp[cf] = BT + (c0 + (cf << 4) + (l & 15)) * K + kh;

  f32x4 acc[2][2] = {};
  const int nst = K >> 5;
#pragma unroll 4
  for (int ks = 0; ks < nst; ++ks) {
    bf16x8 afr[2], bfr[2];
#pragma unroll
    for (int fr = 0; fr < 2; ++fr)
      afr[fr] = __builtin_bit_cast(bf16x8, *(const uint4*)(ap[fr] + (ks << 5)));
#pragma unroll
    for (int cf = 0; cf < 2; ++cf)
      bfr[cf] = __builtin_bit_cast(bf16x8, *(const uint4*)(bp[cf] + (ks << 5)));
#pragma unroll
    for (int fr = 0; fr < 2; ++fr)
#pragma unroll
      for (int cf = 0; cf < 2; ++cf)
        acc[fr][cf] = __builtin_amdgcn_mfma_f32_16x16x32_bf16(
            afr[fr], bfr[cf], acc[fr][cf], 0, 0, 0);
  }

  const int rsub = (l >> 4) << 2, cl = l & 15;
#pragma unroll
  for (int fr = 0; fr < 2; ++fr) {
#pragma unroll
    for (int cf = 0; cf < 2; ++cf) {
      const int col = c0 + (cf << 4) + cl;
#pragma unroll
      for (int j = 0; j < 4; ++j) {
        const int row = r0 + (fr << 4) + rsub + j;
        if (row < M) {
          float v = acc[fr][cf][j];
          if (PHASE == 1) {
            outB[(row << 9) + col] = f2bf(gelu_fast(v + bias[col]));
          } else if (PHASE == 2) {
            v += bias[col];
            outF[(row << 9) + col] = v;
            if (outS) outS[(row << 9) + col] = f2bf(v * scl[col]);
          } else {
            outF[(row << 9) + col] = v;
          }
        }
      }
    }
  }
}

// ---------------------------- main fused kernel -----------------------------
// 1 block per (q-pair, w): q0 = (blockIdx>>4)*2, q1 = q0+1, w = blockIdx&15.
// 1024 threads = 16 waves; every wave MFMAs BOTH pairs on its 32 cols
// (acc0[4][2] + acc1[4][2]); build waves: pair p = wv>>3, slot s = wv&7.
// K-chunk 128, 8 chunks, double-buffered 2x(2x16KB); B frag loaded once per
// chunk serves both pairs (halves WT2 L2 traffic).
__global__ __launch_bounds__(1024, 4) void main_kernel(
    const float* __restrict__ AH, const float* __restrict__ QH,
    const float* __restrict__ CH, const ushort_t* __restrict__ WT2,
    const float* __restrict__ Ya, const float* __restrict__ Yq,
    const float* __restrict__ S1, const float* __restrict__ B1,
    const float* __restrict__ rb1, const float* __restrict__ rw2,
    const float* __restrict__ rb2, const float* __restrict__ cmass,
    float* __restrict__ out) {
  extern __shared__ char smem_raw[];
  float* qs = (float*)smem_raw;          // 1024 (2 q rows)
  float* cs = qs + 1024;                 // 512
  float* s1_s = cs + 512;                // 128 ([p*64+r])
  float* s2_s = s1_s + 128;              // 128
  float* rel_s = s2_s + 128;             // 128
  float* misc = rel_s + 128;             // 4
  uint4* apv = (uint4*)(smem_raw + 8192);  // 2 buf x 2 pair x 16KB

  const int tid = threadIdx.x;
  const int l = tid & 63;
  const int wv = tid >> 6;               // 0..15
  const int w = blockIdx.x & 15;
  const int q0 = (blockIdx.x >> 4) << 1;

  qs[tid] = QH[(q0 << 9) + tid];         // rows q0, q0+1 contiguous
  if (tid < 512) cs[tid] = CH[(w << 9) + tid];
  if (tid < 128) { s1_s[tid] = 0.f; s2_s[tid] = 0.f; rel_s[tid] = 0.f; }
  __syncthreads();

  const int p = wv >> 3;                 // build pair
  const int s = wv & 7;                  // build slot
  const int rloc = ((s & 3) << 4) + (l & 15);
  const float* arow = AH + (((w << 6) + rloc) << 9);
  const float* qsrc = qs + (p << 9);
  const int kh = (l >> 4) << 3;          // 0,8,16,24
  float s1a = 0.f, s2a = 0.f;

  // build chunk C (k in [C*128,(C+1)*128)) into buffer B; ksl = (s>>2)+2i
#define BUILD(C, B) do { \
    _Pragma("unroll") for (int i_ = 0; i_ < 2; ++i_) { \
      const int ksl_ = (s >> 2) + (i_ << 1); \
      const int kg_ = ((C) << 7) + (ksl_ << 5) + kh; \
      const int ka_ = kg_ & 511; \
      const float4 a0_ = *(const float4*)(arow + ka_); \
      const float4 a1_ = *(const float4*)(arow + ka_ + 4); \
      const float4 q0_ = *(const float4*)(qsrc + ka_); \
      const float4 q1_ = *(const float4*)(qsrc + ka_ + 4); \
      const float av_[8] = {a0_.x, a0_.y, a0_.z, a0_.w, a1_.x, a1_.y, a1_.z, a1_.w}; \
      const float qv_[8] = {q0_.x, q0_.y, q0_.z, q0_.w, q1_.x, q1_.y, q1_.z, q1_.w}; \
      float vv_[8]; \
      if ((C) < 4) { \
        _Pragma("unroll") for (int j_ = 0; j_ < 8; ++j_) { \
          const float aq_ = av_[j_] * qv_[j_]; \
          vv_[j_] = aq_; \
          s1a += av_[j_] + aq_; \
          s2a += av_[j_] * av_[j_] + aq_ * aq_; \
        } \
      } else { \
        const float4 c0_ = *(const float4*)(cs + ka_); \
        const float4 c1_ = *(const float4*)(cs + ka_ + 4); \
        const float cv_[8] = {c0_.x, c0_.y, c0_.z, c0_.w, c1_.x, c1_.y, c1_.z, c1_.w}; \
        _Pragma("unroll") for (int j_ = 0; j_ < 8; ++j_) { \
          const float dd_ = fabsf(av_[j_] - qv_[j_]) + cv_[j_]; \
          vv_[j_] = dd_; \
          s1a += dd_; \
          s2a += dd_ * dd_; \
        } \
      } \
      union { __bf16 bv[8]; uint4 u4; } pk_; \
      _Pragma("unroll") for (int j_ = 0; j_ < 8; ++j_) pk_.bv[j_] = (__bf16)vv_[j_]; \
      apv[((B) << 11) + (p << 10) + (ksl_ << 8) + ((s & 3) << 6) + l] = pk_.u4; \
    } } while (0)

  // ---- prologue: build chunk 0 into buf 0 + per-pair q-segment stats
  BUILD(0, 0);
  if (s == 0 && (l >> 4) == 0) { }       // (no-op, keep structure simple)
  if ((wv & 7) == 0) {                   // wv==0 -> p=0, wv==8 -> p=1
    float sq = 0.f, sqq = 0.f;
#pragma unroll
    for (int it = 0; it < 8; ++it) {
      const float vq = qsrc[l + (it << 6)];
      sq += vq; sqq += vq * vq;
    }
#pragma unroll
    for (int off = 1; off < 64; off <<= 1) {
      sq += __shfl_xor(sq, off); sqq += __shfl_xor(sqq, off);
    }
    if (l == 0) { misc[(p << 1)] = sq; misc[(p << 1) + 1] = sqq; }
  }
  __syncthreads();

  // ---- chunk loop: MFMA both pairs on chunk c, then build chunk c+1 -------
  f32x4 acc0[4][2] = {}, acc1[4][2] = {};
  const int ncb = (wv << 5) + (l & 15);  // wave col base
#pragma unroll
  for (int c = 0; c < 8; ++c) {
    const uint4* cbuf = apv + ((c & 1) << 11);
#pragma unroll
    for (int ksl = 0; ksl < 4; ++ksl) {
      const int ks32 = (c << 2) + ksl;
      const bf16x8 bfr0 = __builtin_bit_cast(bf16x8,
          *(const uint4*)(WT2 + (ks32 << 14) + (ncb << 5) + kh));
      const bf16x8 bfr1 = __builtin_bit_cast(bf16x8,
          *(const uint4*)(WT2 + (ks32 << 14) + ((ncb + 16) << 5) + kh));
      bf16x8 afr[4];
#pragma unroll
      for (int fr = 0; fr < 4; ++fr)
        afr[fr] = __builtin_bit_cast(bf16x8, cbuf[(ksl << 8) + (fr << 6) + l]);
#pragma unroll
      for (int fr = 0; fr < 4; ++fr) {
        acc0[fr][0] = __builtin_amdgcn_mfma_f32_16x16x32_bf16(
            afr[fr], bfr0, acc0[fr][0], 0, 0, 0);
        acc0[fr][1] = __builtin_amdgcn_mfma_f32_16x16x32_bf16(
            afr[fr], bfr1, acc0[fr][1], 0, 0, 0);
      }
#pragma unroll
      for (int fr = 0; fr < 4; ++fr)
        afr[fr] = __builtin_bit_cast(bf16x8,
            cbuf[(1 << 10) + (ksl << 8) + (fr << 6) + l]);
#pragma unroll
      for (int fr = 0; fr < 4; ++fr) {
        acc1[fr][0] = __builtin_amdgcn_mfma_f32_16x16x32_bf16(
            afr[fr], bfr0, acc1[fr][0], 0, 0, 0);
        acc1[fr][1] = __builtin_amdgcn_mfma_f32_16x16x32_bf16(
            afr[fr], bfr1, acc1[fr][1], 0, 0, 0);
      }
    }
    if (c < 7) {
      BUILD(c + 1, (c + 1) & 1);
    } else {
      // fold per-thread stats into per-pair per-row LDS totals
      s1a += __shfl_xor(s1a, 16); s1a += __shfl_xor(s1a, 32);
      s2a += __shfl_xor(s2a, 16); s2a += __shfl_xor(s2a, 32);
      if ((l >> 4) == 0) {
        atomicAdd(&s1_s[(p << 6) + rloc], s1a);
        atomicAdd(&s2_s[(p << 6) + rloc], s2a);
      }
    }
    __syncthreads();
  }
#undef BUILD

  // ---- epilogue: LN-fold + gelu + dot(rw2) -> per-row relevance (2 pairs) --
  {
    float yqv0[2], yqv1[2], s1c[2], b1c[2], w2c[2];
#pragma unroll
    for (int cf = 0; cf < 2; ++cf) {
      const int n = ncb + (cf << 4);
      yqv0[cf] = Yq[(q0 << 9) + n];
      yqv1[cf] = Yq[((q0 + 1) << 9) + n];
      s1c[cf] = S1[n];
      b1c[cf] = B1[n] + rb1[n];
      w2c[cf] = rw2[n];
    }
    const float sq0 = misc[0], sqq0 = misc[1];
    const float sq1 = misc[2], sqq1 = misc[3];
    const float* yab = Ya + (w << 15) + ncb;
    const int rsub = (l >> 4) << 2;
#pragma unroll
    for (int fr = 0; fr < 4; ++fr) {
#pragma unroll
      for (int j = 0; j < 4; ++j) {
        const int r = (fr << 4) + rsub + j;
        const float ya0 = yab[(r << 9)];
        const float ya1 = yab[(r << 9) + 16];
        // pair 0
        {
          const float s1r = s1_s[r] + sq0;
          const float s2r = s2_s[r] + sqq0;
          const float mu = s1r * (1.0f / 2048.0f);
          const float rs = rsqrtf(s2r * (1.0f / 2048.0f) - mu * mu + 1e-5f);
          float rp = gelu_fast(rs * (acc0[fr][0][j] + ya0 + yqv0[0] - mu * s1c[0]) + b1c[0]) * w2c[0]
                   + gelu_fast(rs * (acc0[fr][1][j] + ya1 + yqv0[1] - mu * s1c[1]) + b1c[1]) * w2c[1];
          rp += __shfl_xor(rp, 1); rp += __shfl_xor(rp, 2);
          rp += __shfl_xor(rp, 4); rp += __shfl_xor(rp, 8);
          if ((l & 15) == 0) atomicAdd(&rel_s[r], rp);
        }
        // pair 1
        {
          const float s1r = s1_s[64 + r] + sq1;
          const float s2r = s2_s[64 + r] + sqq1;
          const float mu = s1r * (1.0f / 2048.0f);
          const float rs = rsqrtf(s2r * (1.0f / 2048.0f) - mu * mu + 1e-5f);
          float rp = gelu_fast(rs * (acc1[fr][0][j] + ya0 + yqv1[0] - mu * s1c[0]) + b1c[0]) * w2c[0]
                   + gelu_fast(rs * (acc1[fr][1][j] + ya1 + yqv1[1] - mu * s1c[1]) + b1c[1]) * w2c[1];
          rp += __shfl_xor(rp, 1); rp += __shfl_xor(rp, 2);
          rp += __shfl_xor(rp, 4); rp += __shfl_xor(rp, 8);
          if ((l & 15) == 0) atomicAdd(&rel_s[64 + r], rp);
        }
      }
    }
  }
  __syncthreads();

  // ---- softmax over atoms + entropy (2 pairs: tid<128)
  if (tid < 128) {
    const int pp = tid >> 6, a = tid & 63;
    const int qw = ((q0 + pp) << 4) + w;
    const float relv = rel_s[(pp << 6) + a] + rb2[0];
    const float x = logf(fmaxf(cmass[(w << 6) + a], 1e-8f)) + relv;
    float m = x;
#pragma unroll
    for (int off = 1; off < 64; off <<= 1) m = fmaxf(m, __shfl_xor(m, off));
    const float pv = expf(x - m);
    float sv = pv;
#pragma unroll
    for (int off = 1; off < 64; off <<= 1) sv += __shfl_xor(sv, off);
    float mix = pv / fmaxf(sv, 1e-8f);
    float s2 = mix;
#pragma unroll
    for (int off = 1; off < 64; off <<= 1) s2 += __shfl_xor(s2, off);
    mix = mix / fmaxf(s2, 1e-8f);
    const float et = -mix * logf(fmaxf(mix, 1e-8f));
    float ent = et;
#pragma unroll
    for (int off = 1; off < 64; off <<= 1) ent += __shfl_xor(ent, off);
    out[(qw << 6) + a] = mix;                   // mixed[q][w][a]
    if (a == 0) out[65536 + qw] = ent;          // entropy[q][w]
  }
}

// ---------------------------------------------------------------------------
extern "C" void kernel_launch(void* const* d_in, const int* in_sizes, int n_in,
                              void* d_out, int out_size, void* d_ws, size_t ws_size,
                              hipStream_t stream) {
  (void)in_sizes; (void)n_in; (void)out_size; (void)ws_size;
  const float* q_atoms = (const float*)d_in[0];
  const float* q_mass  = (const float*)d_in[1];
  const float* c_atoms = (const float*)d_in[2];
  const float* c_mass  = (const float*)d_in[3];
  const float* c_sum   = (const float*)d_in[4];
  const float* e_ctx   = (const float*)d_in[5];
  const float* qg  = (const float*)d_in[6];  const float* qb  = (const float*)d_in[7];
  const float* qw1 = (const float*)d_in[8];  const float* qb1 = (const float*)d_in[9];
  const float* qw2 = (const float*)d_in[10]; const float* qb2 = (const float*)d_in[11];
  const float* ag  = (const float*)d_in[12]; const float* ab  = (const float*)d_in[13];
  const float* aw1 = (const float*)d_in[14]; const float* ab1 = (const float*)d_in[15];
  const float* aw2 = (const float*)d_in[16]; const float* ab2 = (const float*)d_in[17];
  const float* cg  = (const float*)d_in[18]; const float* cb  = (const float*)d_in[19];
  const float* cw1 = (const float*)d_in[20]; const float* cb1 = (const float*)d_in[21];
  const float* cw2 = (const float*)d_in[22]; const float* cb2 = (const float*)d_in[23];
  const float* rg  = (const float*)d_in[24]; const float* rb  = (const float*)d_in[25];
  const float* rw1 = (const float*)d_in[26]; const float* rb1 = (const float*)d_in[27];
  const float* rw2 = (const float*)d_in[28]; const float* rb2 = (const float*)d_in[29];

  float* ws = (float*)d_ws;
  float* out = (float*)d_out;

  hipMemsetAsync(ws + OFF_S1, 0, 1024 * sizeof(float), stream);  // S1+B1
  pre0_kernel<<<928, 512, 0, stream>>>(q_atoms, q_mass, c_atoms, c_sum, e_ctx,
                                       qg, qb, ag, ab, cg, cb, rw1, rg, rb,
                                       aw1, qw1, cw1, aw2, qw2, cw2, ws);
  gemm_kernel<1><<<140, 256, 0, stream>>>(ws, ab1, qb1, cb1, rg);
  gemm_kernel<2><<<140, 256, 0, stream>>>(ws, ab2, qb2, cb2, rg);
  gemm_kernel<3><<<136, 256, 0, stream>>>(ws, nullptr, nullptr, nullptr, rg);

  static const size_t MAIN_SMEM = 8192 + 65536;  // 73728 B -> 2 blocks/CU
  hipFuncSetAttribute((const void*)main_kernel,
                      hipFuncAttributeMaxDynamicSharedMemorySize, (int)MAIN_SMEM);
  main_kernel<<<512, 1024, MAIN_SMEM, stream>>>(
      ws + OFF_AHH, ws + OFF_QH, ws + OFF_CHH,
      (const ushort_t*)(ws + OFF_WT2), ws + OFF_YA, ws + OFF_YQ,
      ws + OFF_S1, ws + OFF_B1, rb1, rw2, rb2, c_mass, out);
}

// Round 10
// 184.702 us; speedup vs baseline: 1.6689x; 1.0557x over previous
//
#include <hip/hip_runtime.h>

// ---------------------------------------------------------------------------
// QueryConditionedTransportScorerV3 on MI355X (gfx950)
// Q=64 W=16 A=64 D=H=512.
//   fused@rw1 = Ya[w,a] + Yq[q] + [a*q ; |a-q|+c] @ (rg*rw1)[1024:2048] (MFMA)
//   h = rstd*(sum - mu*S1) + (rb1 + rb@rw1); gelu; @rw2; softmax+entropy fused
// Round 10: r9 q-pair batching kept; register diet (sequential afr reuse,
//   BUILD-before-MFMA ordering) to kill the 90MB scratch spill; LN mu/rs
//   precomputed once into LDS instead of per-lane in the epilogue.
// ---------------------------------------------------------------------------

#define DEV static __device__ __forceinline__

typedef __attribute__((ext_vector_type(8))) __bf16 bf16x8;
typedef __attribute__((ext_vector_type(4))) float f32x4;
typedef unsigned short ushort_t;

DEV ushort_t f2bf(float f) {
  unsigned u = __builtin_bit_cast(unsigned, f);
  u = (u + 0x7fffu + ((u >> 16) & 1u)) >> 16;
  return (ushort_t)u;
}

// branch-free erf (Abramowitz-Stegun 7.1.26, |err| <= 1.5e-7)
DEV float gelu_fast(float x) {
  const float y = x * 0.70710678118654752f;
  const float z = fabsf(y);
  const float t = __fdividef(1.0f, 1.0f + 0.3275911f * z);
  float p = 1.061405429f;
  p = p * t - 1.453152027f;
  p = p * t + 1.421413741f;
  p = p * t - 0.284496736f;
  p = p * t + 0.254829592f;
  const float e = 1.0f - p * t * __expf(-z * z);
  const float erfv = copysignf(e, y);
  return 0.5f * x * (1.0f + erfv);
}

// ---- ws layout (float offsets) --------------------------------------------
#define OFF_XQB    0          // bf16 64x512    (aliased by QHS after P1)
#define OFF_XAB    16384      // bf16 1024x512  (aliased by AHHS after P1)
#define OFF_XCB    278528     // bf16 16x1024   (aliased by CHH f32 after P1)
#define OFF_HAB    286720     // bf16 1024x512
#define OFF_HQB    548864     // bf16 64x512
#define OFF_HCB    565248     // bf16 16x512
#define OFF_AHH    569344     // f32 1024x512
#define OFF_QH     1093632    // f32 64x512
#define OFF_S1     1126400    // f32 512
#define OFF_B1     1126912    // f32 512
#define OFF_WT2    1127424    // bf16 k-tiled hi rw1 (rg-scaled), 524288 el
#define OFF_RW1LOT 1389568    // bf16 [512n][512k] rw1[0:512]
#define OFF_RW1MIT 1520640    // bf16 [512n][512k] rw1[512:1024]
#define OFF_AW1T   1651712    // bf16 [512][512]   ┐
#define OFF_QW1T   1782784    // bf16 [512][512]   ├ dead after P1 -> YA
#define OFF_CW1T   1913856    // bf16 [512][1024]  ┘
#define OFF_AW2T   2176000    // bf16 [512][512]   ┐ dead after P2 -> YQ
#define OFF_QW2T   2307072    // bf16 [512][512]   ┘
#define OFF_CW2T   2438144    // bf16 [512][512]   (end: 2569216 fl)
#define OFF_YA     OFF_AW1T   // f32 1024x512
#define OFF_YQ     OFF_AW2T   // f32 64x512
#define OFF_CHH    OFF_XCB    // f32 16x512
#define OFF_AHHS   OFF_XAB    // bf16 1024x512 (ahh*rg_lo)
#define OFF_QHS    OFF_XQB    // bf16 64x512   (qh*rg_mid)

// WT2 k-tiled layout: element (n, k2) at (k2>>5)*16384 + n*32 + (k2&31).

// ======================== P0: wide prep kernel ==============================
DEV void transpose_tile(const float* __restrict__ src, int koff, int kt, int ct,
                        ushort_t* __restrict__ dst, int ldk, float* sh, int tid) {
  float (*t)[65] = (float(*)[65])sh;
  for (int idx = tid; idx < 4096; idx += 512) {
    const int r = idx >> 6, c = idx & 63;
    t[r][c] = src[(koff + kt + r) * 512 + ct + c];
  }
  __syncthreads();
  for (int idx = tid; idx < 4096; idx += 512) {
    const int c = idx >> 6, r = idx & 63;
    dst[(ct + c) * ldk + kt + r] = f2bf(t[r][c]);
  }
}

// roles: [0,128) WT2 | [128,192) rw1loT | [192,256) rw1midT | [256,320) aw1T
// [320,384) qw1T | [384,512) cw1T | [512,576) aw2T | [576,640) qw2T
// [640,704) cw2T | [704,720) S1/B1 | [720,784) q pool+LN | [784,912) a LN
// [912,928) c concat+LN
__global__ __launch_bounds__(512) void pre0_kernel(
    const float* __restrict__ qa, const float* __restrict__ qm,
    const float* __restrict__ ca, const float* __restrict__ csum,
    const float* __restrict__ ectx,
    const float* __restrict__ qg, const float* __restrict__ qb,
    const float* __restrict__ ag, const float* __restrict__ ab,
    const float* __restrict__ cg, const float* __restrict__ cb,
    const float* __restrict__ rw1, const float* __restrict__ rg,
    const float* __restrict__ rb,
    const float* __restrict__ aw1, const float* __restrict__ qw1,
    const float* __restrict__ cw1, const float* __restrict__ aw2,
    const float* __restrict__ qw2, const float* __restrict__ cw2,
    float* __restrict__ ws) {
  __shared__ float sh[4160];
  const int b = blockIdx.x, tid = threadIdx.x, l = tid & 63, wv = tid >> 6;

  if (b < 128) {
    ushort_t* WT = (ushort_t*)(ws + OFF_WT2);
    float (*t)[65] = (float(*)[65])sh;
    const int kt = (b >> 3) << 6;
    const int ct = (b & 7) << 6;
    for (int idx = tid; idx < 4096; idx += 512) {
      const int r = idx >> 6, c = idx & 63;
      t[r][c] = rg[1024 + kt + r] * rw1[(1024 + kt + r) * 512 + ct + c];
    }
    __syncthreads();
    for (int idx = tid; idx < 4096; idx += 512) {
      const int c = idx >> 6, r = idx & 63;
      const int n = ct + c, k2 = kt + r;
      WT[((k2 >> 5) << 14) + (n << 5) + (k2 & 31)] = f2bf(t[r][c]);
    }
  } else if (b < 192) {
    const int bb = b - 128;
    transpose_tile(rw1, 0, (bb >> 3) << 6, (bb & 7) << 6,
                   (ushort_t*)(ws + OFF_RW1LOT), 512, sh, tid);
  } else if (b < 256) {
    const int bb = b - 192;
    transpose_tile(rw1, 512, (bb >> 3) << 6, (bb & 7) << 6,
                   (ushort_t*)(ws + OFF_RW1MIT), 512, sh, tid);
  } else if (b < 320) {
    const int bb = b - 256;
    transpose_tile(aw1, 0, (bb >> 3) << 6, (bb & 7) << 6,
                   (ushort_t*)(ws + OFF_AW1T), 512, sh, tid);
  } else if (b < 384) {
    const int bb = b - 320;
    transpose_tile(qw1, 0, (bb >> 3) << 6, (bb & 7) << 6,
                   (ushort_t*)(ws + OFF_QW1T), 512, sh, tid);
  } else if (b < 512) {
    const int bb = b - 384;
    transpose_tile(cw1, 0, (bb >> 3) << 6, (bb & 7) << 6,
                   (ushort_t*)(ws + OFF_CW1T), 1024, sh, tid);
  } else if (b < 576) {
    const int bb = b - 512;
    transpose_tile(aw2, 0, (bb >> 3) << 6, (bb & 7) << 6,
                   (ushort_t*)(ws + OFF_AW2T), 512, sh, tid);
  } else if (b < 640) {
    const int bb = b - 576;
    transpose_tile(qw2, 0, (bb >> 3) << 6, (bb & 7) << 6,
                   (ushort_t*)(ws + OFF_QW2T), 512, sh, tid);
  } else if (b < 704) {
    const int bb = b - 640;
    transpose_tile(cw2, 0, (bb >> 3) << 6, (bb & 7) << 6,
                   (ushort_t*)(ws + OFF_CW2T), 512, sh, tid);
  } else if (b < 720) {
    const int kc = (b - 704) << 7;
    float s0 = 0.f, s1 = 0.f, b0 = 0.f, b1v = 0.f;
    for (int k = kc; k < kc + 128; k += 2) {
      const float wa = rw1[(k << 9) + tid];
      const float wb = rw1[((k + 1) << 9) + tid];
      s0 += rg[k] * wa; b0 += rb[k] * wa;
      s1 += rg[k + 1] * wb; b1v += rb[k + 1] * wb;
    }
    atomicAdd(ws + OFF_S1 + tid, s0 + s1);
    atomicAdd(ws + OFF_B1 + tid, b0 + b1v);
  } else if (b < 784) {
    const int q = b - 720;
    if (wv == 0) {
      float m = fmaxf(qm[(q << 6) + l], 0.f);
      sh[l] = m;
      float s = m;
#pragma unroll
      for (int off = 1; off < 64; off <<= 1) s += __shfl_xor(s, off);
      if (l == 0) sh[64] = 1.0f / fmaxf(s, 1e-8f);
    }
    __syncthreads();
    const float sinv = sh[64];
    const float* qaq = qa + (q << 15) + tid;
    float v0 = 0.f, v1 = 0.f, v2 = 0.f, v3 = 0.f;
#pragma unroll 4
    for (int a = 0; a < 64; a += 4) {
      v0 += sh[a] * qaq[a << 9];
      v1 += sh[a + 1] * qaq[(a + 1) << 9];
      v2 += sh[a + 2] * qaq[(a + 2) << 9];
      v3 += sh[a + 3] * qaq[(a + 3) << 9];
    }
    const float v = (v0 + v1 + v2 + v3) * sinv;
    float s = v, ss = v * v;
#pragma unroll
    for (int off = 1; off < 64; off <<= 1) {
      s += __shfl_xor(s, off); ss += __shfl_xor(ss, off);
    }
    if (l == 0) { sh[128 + wv] = s; sh[136 + wv] = ss; }
    __syncthreads();
    float st = 0.f, sst = 0.f;
#pragma unroll
    for (int i = 0; i < 8; ++i) { st += sh[128 + i]; sst += sh[136 + i]; }
    const float mu = st * (1.0f / 512.0f);
    const float rstd = rsqrtf(sst * (1.0f / 512.0f) - mu * mu + 1e-5f);
    ((ushort_t*)(ws + OFF_XQB))[(q << 9) + tid] =
        f2bf((v - mu) * rstd * qg[tid] + qb[tid]);
  } else if (b < 912) {
    const int row = ((b - 784) << 3) + wv;
    const float* crow = ca + (row << 9);
    float x[8];
    float s = 0.f, ss = 0.f;
#pragma unroll
    for (int i = 0; i < 8; ++i) {
      x[i] = crow[l + (i << 6)];
      s += x[i]; ss += x[i] * x[i];
    }
#pragma unroll
    for (int off = 1; off < 64; off <<= 1) {
      s += __shfl_xor(s, off); ss += __shfl_xor(ss, off);
    }
    const float mu = s * (1.0f / 512.0f);
    const float rstd = rsqrtf(ss * (1.0f / 512.0f) - mu * mu + 1e-5f);
    ushort_t* xab = (ushort_t*)(ws + OFF_XAB);
#pragma unroll
    for (int i = 0; i < 8; ++i) {
      const int k = l + (i << 6);
      xab[(row << 9) + k] = f2bf((x[i] - mu) * rstd * ag[k] + ab[k]);
    }
  } else {
    const int w = b - 912;
    const float v0 = csum[(w << 9) + tid];
    const float v1 = ectx[(w << 9) + tid];
    float s = v0 + v1, ss = v0 * v0 + v1 * v1;
#pragma unroll
    for (int off = 1; off < 64; off <<= 1) {
      s += __shfl_xor(s, off); ss += __shfl_xor(ss, off);
    }
    if (l == 0) { sh[wv] = s; sh[8 + wv] = ss; }
    __syncthreads();
    float st = 0.f, sst = 0.f;
#pragma unroll
    for (int i = 0; i < 8; ++i) { st += sh[i]; sst += sh[8 + i]; }
    const float mu = st * (1.0f / 1024.0f);
    const float rstd = rsqrtf(sst * (1.0f / 1024.0f) - mu * mu + 1e-5f);
    ushort_t* xcb = (ushort_t*)(ws + OFF_XCB);
    xcb[(w << 10) + tid] = f2bf((v0 - mu) * rstd * cg[tid] + cb[tid]);
    xcb[(w << 10) + 512 + tid] =
        f2bf((v1 - mu) * rstd * cg[512 + tid] + cb[512 + tid]);
  }
}

// ======================== MFMA GEMM phases (32x32 tiles/wave) ===============
template <int PHASE>
__global__ __launch_bounds__(256) void gemm_kernel(
    float* __restrict__ ws, const float* __restrict__ ba,
    const float* __restrict__ bq, const float* __restrict__ bc,
    const float* __restrict__ rg) {
  const int b = blockIdx.x, tid = threadIdx.x;
  const int l = tid & 63, wv = tid >> 6;

  const ushort_t* A; const ushort_t* BT;
  float* outF = nullptr; ushort_t* outB = nullptr; ushort_t* outS = nullptr;
  const float* bias = nullptr; const float* scl = nullptr;
  int M, K, t;

  if (PHASE == 1) {
    if (b < 128) {
      A = (const ushort_t*)(ws + OFF_XAB); BT = (const ushort_t*)(ws + OFF_AW1T);
      M = 1024; K = 512; outB = (ushort_t*)(ws + OFF_HAB); bias = ba;
      t = (b << 2) + wv;
    } else if (b < 136) {
      A = (const ushort_t*)(ws + OFF_XQB); BT = (const ushort_t*)(ws + OFF_QW1T);
      M = 64; K = 512; outB = (ushort_t*)(ws + OFF_HQB); bias = bq;
      t = ((b - 128) << 2) + wv;
    } else {
      A = (const ushort_t*)(ws + OFF_XCB); BT = (const ushort_t*)(ws + OFF_CW1T);
      M = 16; K = 1024; outB = (ushort_t*)(ws + OFF_HCB); bias = bc;
      t = ((b - 136) << 2) + wv;
    }
  } else if (PHASE == 2) {
    if (b < 128) {
      A = (const ushort_t*)(ws + OFF_HAB); BT = (const ushort_t*)(ws + OFF_AW2T);
      M = 1024; K = 512; outF = ws + OFF_AHH;
      outS = (ushort_t*)(ws + OFF_AHHS); bias = ba; scl = rg;
      t = (b << 2) + wv;
    } else if (b < 136) {
      A = (const ushort_t*)(ws + OFF_HQB); BT = (const ushort_t*)(ws + OFF_QW2T);
      M = 64; K = 512; outF = ws + OFF_QH;
      outS = (ushort_t*)(ws + OFF_QHS); bias = bq; scl = rg + 512;
      t = ((b - 128) << 2) + wv;
    } else {
      A = (const ushort_t*)(ws + OFF_HCB); BT = (const ushort_t*)(ws + OFF_CW2T);
      M = 16; K = 512; outF = ws + OFF_CHH; bias = bc;
      t = ((b - 136) << 2) + wv;
    }
  } else {
    if (b < 128) {
      A = (const ushort_t*)(ws + OFF_AHHS); BT = (const ushort_t*)(ws + OFF_RW1LOT);
      M = 1024; K = 512; outF = ws + OFF_YA;
      t = (b << 2) + wv;
    } else {
      A = (const ushort_t*)(ws + OFF_QHS); BT = (const ushort_t*)(ws + OFF_RW1MIT);
      M = 64; K = 512; outF = ws + OFF_YQ;
      t = ((b - 128) << 2) + wv;
    }
  }

  const int rt = t >> 4, ct = t & 15;
  const int r0 = rt << 5, c0 = ct << 5;
  const int kh = (l >> 4) << 3;
  const ushort_t* ap[2];
  const ushort_t* bp[2];
#pragma unroll
  for (int fr = 0; fr < 2; ++fr) {
    int r = r0 + (fr << 4) + (l & 15);
    if (r > M - 1) r = M - 1;          // row clamp for small-M tiles
    ap[fr] = A + r * K + kh;
  }
#pragma unroll
  for (int cf = 0; cf < 2; ++cf)
    bp[cf] = BT + (c0 + (cf << 4) + (l & 15)) * K + kh;

  f32x4 acc[2][2] = {};
  const int nst = K >> 5;
#pragma unroll 4
  for (int ks = 0; ks < nst; ++ks) {
    bf16x8 afr[2], bfr[2];
#pragma unroll
    for (int fr = 0; fr < 2; ++fr)
      afr[fr] = __builtin_bit_cast(bf16x8, *(const uint4*)(ap[fr] + (ks << 5)));
#pragma unroll
    for (int cf = 0; cf < 2; ++cf)
      bfr[cf] = __builtin_bit_cast(bf16x8, *(const uint4*)(bp[cf] + (ks << 5)));
#pragma unroll
    for (int fr = 0; fr < 2; ++fr)
#pragma unroll
      for (int cf = 0; cf < 2; ++cf)
        acc[fr][cf] = __builtin_amdgcn_mfma_f32_16x16x32_bf16(
            afr[fr], bfr[cf], acc[fr][cf], 0, 0, 0);
  }

  const int rsub = (l >> 4) << 2, cl = l & 15;
#pragma unroll
  for (int fr = 0; fr < 2; ++fr) {
#pragma unroll
    for (int cf = 0; cf < 2; ++cf) {
      const int col = c0 + (cf << 4) + cl;
#pragma unroll
      for (int j = 0; j < 4; ++j) {
        const int row = r0 + (fr << 4) + rsub + j;
        if (row < M) {
          float v = acc[fr][cf][j];
          if (PHASE == 1) {
            outB[(row << 9) + col] = f2bf(gelu_fast(v + bias[col]));
          } else if (PHASE == 2) {
            v += bias[col];
            outF[(row << 9) + col] = v;
            if (outS) outS[(row << 9) + col] = f2bf(v * scl[col]);
          } else {
            outF[(row << 9) + col] = v;
          }
        }
      }
    }
  }
}

// ---------------------------- main fused kernel -----------------------------
// 1 block per (q-pair, w). 1024 threads = 16 waves; every wave MFMAs BOTH
// pairs on its 32 cols (acc0[4][2] + acc1[4][2]); sequential afr reuse keeps
// peak regs < 128 (no spill). BUILD(c+1) issued BEFORE MFMA(c) each chunk.
// LN mu/rs precomputed once into LDS after the chunk loop.
__global__ __launch_bounds__(1024, 4) void main_kernel(
    const float* __restrict__ AH, const float* __restrict__ QH,
    const float* __restrict__ CH, const ushort_t* __restrict__ WT2,
    const float* __restrict__ Ya, const float* __restrict__ Yq,
    const float* __restrict__ S1, const float* __restrict__ B1,
    const float* __restrict__ rb1, const float* __restrict__ rw2,
    const float* __restrict__ rb2, const float* __restrict__ cmass,
    float* __restrict__ out) {
  extern __shared__ char smem_raw[];
  float* qs = (float*)smem_raw;          // 1024 (2 q rows)
  float* cs = qs + 1024;                 // 512
  float* s1_s = cs + 512;                // 128 ([p*64+r]) -> mu after loop
  float* s2_s = s1_s + 128;              // 128            -> rs after loop
  float* rel_s = s2_s + 128;             // 128
  float* misc = rel_s + 128;             // 4
  uint4* apv = (uint4*)(smem_raw + 8192);  // 2 buf x 2 pair x 16KB

  const int tid = threadIdx.x;
  const int l = tid & 63;
  const int wv = tid >> 6;               // 0..15
  const int w = blockIdx.x & 15;
  const int q0 = (blockIdx.x >> 4) << 1;

  qs[tid] = QH[(q0 << 9) + tid];         // rows q0, q0+1 contiguous
  if (tid < 512) cs[tid] = CH[(w << 9) + tid];
  if (tid < 128) { s1_s[tid] = 0.f; s2_s[tid] = 0.f; rel_s[tid] = 0.f; }
  __syncthreads();

  const int p = wv >> 3;                 // build pair
  const int s = wv & 7;                  // build slot
  const int rloc = ((s & 3) << 4) + (l & 15);
  const float* arow = AH + (((w << 6) + rloc) << 9);
  const float* qsrc = qs + (p << 9);
  const int kh = (l >> 4) << 3;          // 0,8,16,24
  float s1a = 0.f, s2a = 0.f;

  // build chunk C (k in [C*128,(C+1)*128)) into buffer B; ksl = (s>>2)+2i
#define BUILD(C, B) do { \
    _Pragma("unroll") for (int i_ = 0; i_ < 2; ++i_) { \
      const int ksl_ = (s >> 2) + (i_ << 1); \
      const int kg_ = ((C) << 7) + (ksl_ << 5) + kh; \
      const int ka_ = kg_ & 511; \
      const float4 a0_ = *(const float4*)(arow + ka_); \
      const float4 a1_ = *(const float4*)(arow + ka_ + 4); \
      const float4 q0_ = *(const float4*)(qsrc + ka_); \
      const float4 q1_ = *(const float4*)(qsrc + ka_ + 4); \
      const float av_[8] = {a0_.x, a0_.y, a0_.z, a0_.w, a1_.x, a1_.y, a1_.z, a1_.w}; \
      const float qv_[8] = {q0_.x, q0_.y, q0_.z, q0_.w, q1_.x, q1_.y, q1_.z, q1_.w}; \
      float vv_[8]; \
      if ((C) < 4) { \
        _Pragma("unroll") for (int j_ = 0; j_ < 8; ++j_) { \
          const float aq_ = av_[j_] * qv_[j_]; \
          vv_[j_] = aq_; \
          s1a += av_[j_] + aq_; \
          s2a += av_[j_] * av_[j_] + aq_ * aq_; \
        } \
      } else { \
        const float4 c0_ = *(const float4*)(cs + ka_); \
        const float4 c1_ = *(const float4*)(cs + ka_ + 4); \
        const float cv_[8] = {c0_.x, c0_.y, c0_.z, c0_.w, c1_.x, c1_.y, c1_.z, c1_.w}; \
        _Pragma("unroll") for (int j_ = 0; j_ < 8; ++j_) { \
          const float dd_ = fabsf(av_[j_] - qv_[j_]) + cv_[j_]; \
          vv_[j_] = dd_; \
          s1a += dd_; \
          s2a += dd_ * dd_; \
        } \
      } \
      union { __bf16 bv[8]; uint4 u4; } pk_; \
      _Pragma("unroll") for (int j_ = 0; j_ < 8; ++j_) pk_.bv[j_] = (__bf16)vv_[j_]; \
      apv[((B) << 11) + (p << 10) + (ksl_ << 8) + ((s & 3) << 6) + l] = pk_.u4; \
    } } while (0)

  // ---- prologue: build chunk 0 into buf 0 + per-pair q-segment stats
  BUILD(0, 0);
  if ((wv & 7) == 0) {                   // wv==0 -> p=0, wv==8 -> p=1
    float sq = 0.f, sqq = 0.f;
#pragma unroll
    for (int it = 0; it < 8; ++it) {
      const float vq = qsrc[l + (it << 6)];
      sq += vq; sqq += vq * vq;
    }
#pragma unroll
    for (int off = 1; off < 64; off <<= 1) {
      sq += __shfl_xor(sq, off); sqq += __shfl_xor(sqq, off);
    }
    if (l == 0) { misc[(p << 1)] = sq; misc[(p << 1) + 1] = sqq; }
  }
  __syncthreads();

  // ---- chunk loop: BUILD(c+1) first (loads in flight), then MFMA(c) -------
  f32x4 acc0[4][2] = {}, acc1[4][2] = {};
  const int ncb = (wv << 5) + (l & 15);  // wave col base
#pragma unroll
  for (int c = 0; c < 8; ++c) {
    if (c < 7) {
      BUILD(c + 1, (c + 1) & 1);
    } else {
      // fold per-thread stats into per-pair per-row LDS totals
      s1a += __shfl_xor(s1a, 16); s1a += __shfl_xor(s1a, 32);
      s2a += __shfl_xor(s2a, 16); s2a += __shfl_xor(s2a, 32);
      if ((l >> 4) == 0) {
        atomicAdd(&s1_s[(p << 6) + rloc], s1a);
        atomicAdd(&s2_s[(p << 6) + rloc], s2a);
      }
    }
    const uint4* cbuf = apv + ((c & 1) << 11);
#pragma unroll
    for (int ksl = 0; ksl < 4; ++ksl) {
      const int ks32 = (c << 2) + ksl;
      const bf16x8 bfr0 = __builtin_bit_cast(bf16x8,
          *(const uint4*)(WT2 + (ks32 << 14) + (ncb << 5) + kh));
      const bf16x8 bfr1 = __builtin_bit_cast(bf16x8,
          *(const uint4*)(WT2 + (ks32 << 14) + ((ncb + 16) << 5) + kh));
      bf16x8 afr[4];
      // pair 0
#pragma unroll
      for (int fr = 0; fr < 4; ++fr)
        afr[fr] = __builtin_bit_cast(bf16x8, cbuf[(ksl << 8) + (fr << 6) + l]);
#pragma unroll
      for (int fr = 0; fr < 4; ++fr) {
        acc0[fr][0] = __builtin_amdgcn_mfma_f32_16x16x32_bf16(
            afr[fr], bfr0, acc0[fr][0], 0, 0, 0);
        acc0[fr][1] = __builtin_amdgcn_mfma_f32_16x16x32_bf16(
            afr[fr], bfr1, acc0[fr][1], 0, 0, 0);
      }
      // pair 1 (reuse afr registers)
#pragma unroll
      for (int fr = 0; fr < 4; ++fr)
        afr[fr] = __builtin_bit_cast(bf16x8,
            cbuf[(1 << 10) + (ksl << 8) + (fr << 6) + l]);
#pragma unroll
      for (int fr = 0; fr < 4; ++fr) {
        acc1[fr][0] = __builtin_amdgcn_mfma_f32_16x16x32_bf16(
            afr[fr], bfr0, acc1[fr][0], 0, 0, 0);
        acc1[fr][1] = __builtin_amdgcn_mfma_f32_16x16x32_bf16(
            afr[fr], bfr1, acc1[fr][1], 0, 0, 0);
      }
    }
    __syncthreads();
  }
#undef BUILD

  // ---- finalize LN stats: 128 (pair,row) mu/rs computed once --------------
  if (tid < 128) {
    const int pp = tid >> 6;
    const float s1r = s1_s[tid] + misc[pp << 1];
    const float s2r = s2_s[tid] + misc[(pp << 1) + 1];
    const float mu = s1r * (1.0f / 2048.0f);
    const float rs = rsqrtf(s2r * (1.0f / 2048.0f) - mu * mu + 1e-5f);
    s1_s[tid] = mu;
    s2_s[tid] = rs;
  }
  __syncthreads();

  // ---- epilogue: LN-fold + gelu + dot(rw2) -> per-row relevance (2 pairs) --
  {
    float yqv0[2], yqv1[2], s1c[2], b1c[2], w2c[2];
#pragma unroll
    for (int cf = 0; cf < 2; ++cf) {
      const int n = ncb + (cf << 4);
      yqv0[cf] = Yq[(q0 << 9) + n];
      yqv1[cf] = Yq[((q0 + 1) << 9) + n];
      s1c[cf] = S1[n];
      b1c[cf] = B1[n] + rb1[n];
      w2c[cf] = rw2[n];
    }
    const float* yab = Ya + (w << 15) + ncb;
    const int rsub = (l >> 4) << 2;
#pragma unroll
    for (int fr = 0; fr < 4; ++fr) {
#pragma unroll
      for (int j = 0; j < 4; ++j) {
        const int r = (fr << 4) + rsub + j;
        const float ya0 = yab[(r << 9)];
        const float ya1 = yab[(r << 9) + 16];
        // pair 0
        {
          const float mu = s1_s[r], rs = s2_s[r];
          float rp = gelu_fast(rs * (acc0[fr][0][j] + ya0 + yqv0[0] - mu * s1c[0]) + b1c[0]) * w2c[0]
                   + gelu_fast(rs * (acc0[fr][1][j] + ya1 + yqv0[1] - mu * s1c[1]) + b1c[1]) * w2c[1];
          rp += __shfl_xor(rp, 1); rp += __shfl_xor(rp, 2);
          rp += __shfl_xor(rp, 4); rp += __shfl_xor(rp, 8);
          if ((l & 15) == 0) atomicAdd(&rel_s[r], rp);
        }
        // pair 1
        {
          const float mu = s1_s[64 + r], rs = s2_s[64 + r];
          float rp = gelu_fast(rs * (acc1[fr][0][j] + ya0 + yqv1[0] - mu * s1c[0]) + b1c[0]) * w2c[0]
                   + gelu_fast(rs * (acc1[fr][1][j] + ya1 + yqv1[1] - mu * s1c[1]) + b1c[1]) * w2c[1];
          rp += __shfl_xor(rp, 1); rp += __shfl_xor(rp, 2);
          rp += __shfl_xor(rp, 4); rp += __shfl_xor(rp, 8);
          if ((l & 15) == 0) atomicAdd(&rel_s[64 + r], rp);
        }
      }
    }
  }
  __syncthreads();

  // ---- softmax over atoms + entropy (2 pairs: tid<128)
  if (tid < 128) {
    const int pp = tid >> 6, a = tid & 63;
    const int qw = ((q0 + pp) << 4) + w;
    const float relv = rel_s[(pp << 6) + a] + rb2[0];
    const float x = logf(fmaxf(cmass[(w << 6) + a], 1e-8f)) + relv;
    float m = x;
#pragma unroll
    for (int off = 1; off < 64; off <<= 1) m = fmaxf(m, __shfl_xor(m, off));
    const float pv = expf(x - m);
    float sv = pv;
#pragma unroll
    for (int off = 1; off < 64; off <<= 1) sv += __shfl_xor(sv, off);
    float mix = pv / fmaxf(sv, 1e-8f);
    float s2 = mix;
#pragma unroll
    for (int off = 1; off < 64; off <<= 1) s2 += __shfl_xor(s2, off);
    mix = mix / fmaxf(s2, 1e-8f);
    const float et = -mix * logf(fmaxf(mix, 1e-8f));
    float ent = et;
#pragma unroll
    for (int off = 1; off < 64; off <<= 1) ent += __shfl_xor(ent, off);
    out[(qw << 6) + a] = mix;                   // mixed[q][w][a]
    if (a == 0) out[65536 + qw] = ent;          // entropy[q][w]
  }
}

// ---------------------------------------------------------------------------
extern "C" void kernel_launch(void* const* d_in, const int* in_sizes, int n_in,
                              void* d_out, int out_size, void* d_ws, size_t ws_size,
                              hipStream_t stream) {
  (void)in_sizes; (void)n_in; (void)out_size; (void)ws_size;
  const float* q_atoms = (const float*)d_in[0];
  const float* q_mass  = (const float*)d_in[1];
  const float* c_atoms = (const float*)d_in[2];
  const float* c_mass  = (const float*)d_in[3];
  const float* c_sum   = (const float*)d_in[4];
  const float* e_ctx   = (const float*)d_in[5];
  const float* qg  = (const float*)d_in[6];  const float* qb  = (const float*)d_in[7];
  const float* qw1 = (const float*)d_in[8];  const float* qb1 = (const float*)d_in[9];
  const float* qw2 = (const float*)d_in[10]; const float* qb2 = (const float*)d_in[11];
  const float* ag  = (const float*)d_in[12]; const float* ab  = (const float*)d_in[13];
  const float* aw1 = (const float*)d_in[14]; const float* ab1 = (const float*)d_in[15];
  const float* aw2 = (const float*)d_in[16]; const float* ab2 = (const float*)d_in[17];
  const float* cg  = (const float*)d_in[18]; const float* cb  = (const float*)d_in[19];
  const float* cw1 = (const float*)d_in[20]; const float* cb1 = (const float*)d_in[21];
  const float* cw2 = (const float*)d_in[22]; const float* cb2 = (const float*)d_in[23];
  const float* rg  = (const float*)d_in[24]; const float* rb  = (const float*)d_in[25];
  const float* rw1 = (const float*)d_in[26]; const float* rb1 = (const float*)d_in[27];
  const float* rw2 = (const float*)d_in[28]; const float* rb2 = (const float*)d_in[29];

  float* ws = (float*)d_ws;
  float* out = (float*)d_out;

  hipMemsetAsync(ws + OFF_S1, 0, 1024 * sizeof(float), stream);  // S1+B1
  pre0_kernel<<<928, 512, 0, stream>>>(q_atoms, q_mass, c_atoms, c_sum, e_ctx,
                                       qg, qb, ag, ab, cg, cb, rw1, rg, rb,
                                       aw1, qw1, cw1, aw2, qw2, cw2, ws);
  gemm_kernel<1><<<140, 256, 0, stream>>>(ws, ab1, qb1, cb1, rg);
  gemm_kernel<2><<<140, 256, 0, stream>>>(ws, ab2, qb2, cb2, rg);
  gemm_kernel<3><<<136, 256, 0, stream>>>(ws, nullptr, nullptr, nullptr, rg);

  static const size_t MAIN_SMEM = 8192 + 65536;  // 73728 B -> 2 blocks/CU
  hipFuncSetAttribute((const void*)main_kernel,
                      hipFuncAttributeMaxDynamicSharedMemorySize, (int)MAIN_SMEM);
  main_kernel<<<512, 1024, MAIN_SMEM, stream>>>(
      ws + OFF_AHH, ws + OFF_QH, ws + OFF_CHH,
      (const ushort_t*)(ws + OFF_WT2), ws + OFF_YA, ws + OFF_YQ,
      ws + OFF_S1, ws + OFF_B1, rb1, rw2, rb2, c_mass, out);
}

// Round 11
// 179.545 us; speedup vs baseline: 1.7168x; 1.0287x over previous
//
#include <hip/hip_runtime.h>

// ---------------------------------------------------------------------------
// QueryConditionedTransportScorerV3 on MI355X (gfx950)
// Q=64 W=16 A=64 D=H=512.
//   fused@rw1 = Ya[w,a] + Yq[q] + [a*q ; |a-q|+c] @ (rg*rw1)[1024:2048] (MFMA)
//   h = rstd*(sum - mu*S1) + (rb1 + rb@rw1); gelu; @rw2; softmax+entropy fused
// Round 11: main kernel reshaped to 512 threads / 8 waves with
//   __launch_bounds__(512,2) -> 256-reg cap. Wave = 64r x 64c x 2 pairs
//   (acc 128 AGPR + ~90 VGPR < 256: NO spill). MFMA:LDS-read ratio doubles.
//   Pre-path unchanged.
// ---------------------------------------------------------------------------

#define DEV static __device__ __forceinline__

typedef __attribute__((ext_vector_type(8))) __bf16 bf16x8;
typedef __attribute__((ext_vector_type(4))) float f32x4;
typedef unsigned short ushort_t;

DEV ushort_t f2bf(float f) {
  unsigned u = __builtin_bit_cast(unsigned, f);
  u = (u + 0x7fffu + ((u >> 16) & 1u)) >> 16;
  return (ushort_t)u;
}

// branch-free erf (Abramowitz-Stegun 7.1.26, |err| <= 1.5e-7)
DEV float gelu_fast(float x) {
  const float y = x * 0.70710678118654752f;
  const float z = fabsf(y);
  const float t = __fdividef(1.0f, 1.0f + 0.3275911f * z);
  float p = 1.061405429f;
  p = p * t - 1.453152027f;
  p = p * t + 1.421413741f;
  p = p * t - 0.284496736f;
  p = p * t + 0.254829592f;
  const float e = 1.0f - p * t * __expf(-z * z);
  const float erfv = copysignf(e, y);
  return 0.5f * x * (1.0f + erfv);
}

// ---- ws layout (float offsets) --------------------------------------------
#define OFF_XQB    0          // bf16 64x512    (aliased by QHS after P1)
#define OFF_XAB    16384      // bf16 1024x512  (aliased by AHHS after P1)
#define OFF_XCB    278528     // bf16 16x1024   (aliased by CHH f32 after P1)
#define OFF_HAB    286720     // bf16 1024x512
#define OFF_HQB    548864     // bf16 64x512
#define OFF_HCB    565248     // bf16 16x512
#define OFF_AHH    569344     // f32 1024x512
#define OFF_QH     1093632    // f32 64x512
#define OFF_S1     1126400    // f32 512
#define OFF_B1     1126912    // f32 512
#define OFF_WT2    1127424    // bf16 k-tiled hi rw1 (rg-scaled), 524288 el
#define OFF_RW1LOT 1389568    // bf16 [512n][512k] rw1[0:512]
#define OFF_RW1MIT 1520640    // bf16 [512n][512k] rw1[512:1024]
#define OFF_AW1T   1651712    // bf16 [512][512]   ┐
#define OFF_QW1T   1782784    // bf16 [512][512]   ├ dead after P1 -> YA
#define OFF_CW1T   1913856    // bf16 [512][1024]  ┘
#define OFF_AW2T   2176000    // bf16 [512][512]   ┐ dead after P2 -> YQ
#define OFF_QW2T   2307072    // bf16 [512][512]   ┘
#define OFF_CW2T   2438144    // bf16 [512][512]   (end: 2569216 fl)
#define OFF_YA     OFF_AW1T   // f32 1024x512
#define OFF_YQ     OFF_AW2T   // f32 64x512
#define OFF_CHH    OFF_XCB    // f32 16x512
#define OFF_AHHS   OFF_XAB    // bf16 1024x512 (ahh*rg_lo)
#define OFF_QHS    OFF_XQB    // bf16 64x512   (qh*rg_mid)

// WT2 k-tiled layout: element (n, k2) at (k2>>5)*16384 + n*32 + (k2&31).

// ======================== P0: wide prep kernel ==============================
DEV void transpose_tile(const float* __restrict__ src, int koff, int kt, int ct,
                        ushort_t* __restrict__ dst, int ldk, float* sh, int tid) {
  float (*t)[65] = (float(*)[65])sh;
  for (int idx = tid; idx < 4096; idx += 512) {
    const int r = idx >> 6, c = idx & 63;
    t[r][c] = src[(koff + kt + r) * 512 + ct + c];
  }
  __syncthreads();
  for (int idx = tid; idx < 4096; idx += 512) {
    const int c = idx >> 6, r = idx & 63;
    dst[(ct + c) * ldk + kt + r] = f2bf(t[r][c]);
  }
}

// roles: [0,128) WT2 | [128,192) rw1loT | [192,256) rw1midT | [256,320) aw1T
// [320,384) qw1T | [384,512) cw1T | [512,576) aw2T | [576,640) qw2T
// [640,704) cw2T | [704,720) S1/B1 | [720,784) q pool+LN | [784,912) a LN
// [912,928) c concat+LN
__global__ __launch_bounds__(512) void pre0_kernel(
    const float* __restrict__ qa, const float* __restrict__ qm,
    const float* __restrict__ ca, const float* __restrict__ csum,
    const float* __restrict__ ectx,
    const float* __restrict__ qg, const float* __restrict__ qb,
    const float* __restrict__ ag, const float* __restrict__ ab,
    const float* __restrict__ cg, const float* __restrict__ cb,
    const float* __restrict__ rw1, const float* __restrict__ rg,
    const float* __restrict__ rb,
    const float* __restrict__ aw1, const float* __restrict__ qw1,
    const float* __restrict__ cw1, const float* __restrict__ aw2,
    const float* __restrict__ qw2, const float* __restrict__ cw2,
    float* __restrict__ ws) {
  __shared__ float sh[4160];
  const int b = blockIdx.x, tid = threadIdx.x, l = tid & 63, wv = tid >> 6;

  if (b < 128) {
    ushort_t* WT = (ushort_t*)(ws + OFF_WT2);
    float (*t)[65] = (float(*)[65])sh;
    const int kt = (b >> 3) << 6;
    const int ct = (b & 7) << 6;
    for (int idx = tid; idx < 4096; idx += 512) {
      const int r = idx >> 6, c = idx & 63;
      t[r][c] = rg[1024 + kt + r] * rw1[(1024 + kt + r) * 512 + ct + c];
    }
    __syncthreads();
    for (int idx = tid; idx < 4096; idx += 512) {
      const int c = idx >> 6, r = idx & 63;
      const int n = ct + c, k2 = kt + r;
      WT[((k2 >> 5) << 14) + (n << 5) + (k2 & 31)] = f2bf(t[r][c]);
    }
  } else if (b < 192) {
    const int bb = b - 128;
    transpose_tile(rw1, 0, (bb >> 3) << 6, (bb & 7) << 6,
                   (ushort_t*)(ws + OFF_RW1LOT), 512, sh, tid);
  } else if (b < 256) {
    const int bb = b - 192;
    transpose_tile(rw1, 512, (bb >> 3) << 6, (bb & 7) << 6,
                   (ushort_t*)(ws + OFF_RW1MIT), 512, sh, tid);
  } else if (b < 320) {
    const int bb = b - 256;
    transpose_tile(aw1, 0, (bb >> 3) << 6, (bb & 7) << 6,
                   (ushort_t*)(ws + OFF_AW1T), 512, sh, tid);
  } else if (b < 384) {
    const int bb = b - 320;
    transpose_tile(qw1, 0, (bb >> 3) << 6, (bb & 7) << 6,
                   (ushort_t*)(ws + OFF_QW1T), 512, sh, tid);
  } else if (b < 512) {
    const int bb = b - 384;
    transpose_tile(cw1, 0, (bb >> 3) << 6, (bb & 7) << 6,
                   (ushort_t*)(ws + OFF_CW1T), 1024, sh, tid);
  } else if (b < 576) {
    const int bb = b - 512;
    transpose_tile(aw2, 0, (bb >> 3) << 6, (bb & 7) << 6,
                   (ushort_t*)(ws + OFF_AW2T), 512, sh, tid);
  } else if (b < 640) {
    const int bb = b - 576;
    transpose_tile(qw2, 0, (bb >> 3) << 6, (bb & 7) << 6,
                   (ushort_t*)(ws + OFF_QW2T), 512, sh, tid);
  } else if (b < 704) {
    const int bb = b - 640;
    transpose_tile(cw2, 0, (bb >> 3) << 6, (bb & 7) << 6,
                   (ushort_t*)(ws + OFF_CW2T), 512, sh, tid);
  } else if (b < 720) {
    const int kc = (b - 704) << 7;
    float s0 = 0.f, s1 = 0.f, b0 = 0.f, b1v = 0.f;
    for (int k = kc; k < kc + 128; k += 2) {
      const float wa = rw1[(k << 9) + tid];
      const float wb = rw1[((k + 1) << 9) + tid];
      s0 += rg[k] * wa; b0 += rb[k] * wa;
      s1 += rg[k + 1] * wb; b1v += rb[k + 1] * wb;
    }
    atomicAdd(ws + OFF_S1 + tid, s0 + s1);
    atomicAdd(ws + OFF_B1 + tid, b0 + b1v);
  } else if (b < 784) {
    const int q = b - 720;
    if (wv == 0) {
      float m = fmaxf(qm[(q << 6) + l], 0.f);
      sh[l] = m;
      float s = m;
#pragma unroll
      for (int off = 1; off < 64; off <<= 1) s += __shfl_xor(s, off);
      if (l == 0) sh[64] = 1.0f / fmaxf(s, 1e-8f);
    }
    __syncthreads();
    const float sinv = sh[64];
    const float* qaq = qa + (q << 15) + tid;
    float v0 = 0.f, v1 = 0.f, v2 = 0.f, v3 = 0.f;
#pragma unroll 4
    for (int a = 0; a < 64; a += 4) {
      v0 += sh[a] * qaq[a << 9];
      v1 += sh[a + 1] * qaq[(a + 1) << 9];
      v2 += sh[a + 2] * qaq[(a + 2) << 9];
      v3 += sh[a + 3] * qaq[(a + 3) << 9];
    }
    const float v = (v0 + v1 + v2 + v3) * sinv;
    float s = v, ss = v * v;
#pragma unroll
    for (int off = 1; off < 64; off <<= 1) {
      s += __shfl_xor(s, off); ss += __shfl_xor(ss, off);
    }
    if (l == 0) { sh[128 + wv] = s; sh[136 + wv] = ss; }
    __syncthreads();
    float st = 0.f, sst = 0.f;
#pragma unroll
    for (int i = 0; i < 8; ++i) { st += sh[128 + i]; sst += sh[136 + i]; }
    const float mu = st * (1.0f / 512.0f);
    const float rstd = rsqrtf(sst * (1.0f / 512.0f) - mu * mu + 1e-5f);
    ((ushort_t*)(ws + OFF_XQB))[(q << 9) + tid] =
        f2bf((v - mu) * rstd * qg[tid] + qb[tid]);
  } else if (b < 912) {
    const int row = ((b - 784) << 3) + wv;
    const float* crow = ca + (row << 9);
    float x[8];
    float s = 0.f, ss = 0.f;
#pragma unroll
    for (int i = 0; i < 8; ++i) {
      x[i] = crow[l + (i << 6)];
      s += x[i]; ss += x[i] * x[i];
    }
#pragma unroll
    for (int off = 1; off < 64; off <<= 1) {
      s += __shfl_xor(s, off); ss += __shfl_xor(ss, off);
    }
    const float mu = s * (1.0f / 512.0f);
    const float rstd = rsqrtf(ss * (1.0f / 512.0f) - mu * mu + 1e-5f);
    ushort_t* xab = (ushort_t*)(ws + OFF_XAB);
#pragma unroll
    for (int i = 0; i < 8; ++i) {
      const int k = l + (i << 6);
      xab[(row << 9) + k] = f2bf((x[i] - mu) * rstd * ag[k] + ab[k]);
    }
  } else {
    const int w = b - 912;
    const float v0 = csum[(w << 9) + tid];
    const float v1 = ectx[(w << 9) + tid];
    float s = v0 + v1, ss = v0 * v0 + v1 * v1;
#pragma unroll
    for (int off = 1; off < 64; off <<= 1) {
      s += __shfl_xor(s, off); ss += __shfl_xor(ss, off);
    }
    if (l == 0) { sh[wv] = s; sh[8 + wv] = ss; }
    __syncthreads();
    float st = 0.f, sst = 0.f;
#pragma unroll
    for (int i = 0; i < 8; ++i) { st += sh[i]; sst += sh[8 + i]; }
    const float mu = st * (1.0f / 1024.0f);
    const float rstd = rsqrtf(sst * (1.0f / 1024.0f) - mu * mu + 1e-5f);
    ushort_t* xcb = (ushort_t*)(ws + OFF_XCB);
    xcb[(w << 10) + tid] = f2bf((v0 - mu) * rstd * cg[tid] + cb[tid]);
    xcb[(w << 10) + 512 + tid] =
        f2bf((v1 - mu) * rstd * cg[512 + tid] + cb[512 + tid]);
  }
}

// ======================== MFMA GEMM phases (32x32 tiles/wave) ===============
template <int PHASE>
__global__ __launch_bounds__(256) void gemm_kernel(
    float* __restrict__ ws, const float* __restrict__ ba,
    const float* __restrict__ bq, const float* __restrict__ bc,
    const float* __restrict__ rg) {
  const int b = blockIdx.x, tid = threadIdx.x;
  const int l = tid & 63, wv = tid >> 6;

  const ushort_t* A; const ushort_t* BT;
  float* outF = nullptr; ushort_t* outB = nullptr; ushort_t* outS = nullptr;
  const float* bias = nullptr; const float* scl = nullptr;
  int M, K, t;

  if (PHASE == 1) {
    if (b < 128) {
      A = (const ushort_t*)(ws + OFF_XAB); BT = (const ushort_t*)(ws + OFF_AW1T);
      M = 1024; K = 512; outB = (ushort_t*)(ws + OFF_HAB); bias = ba;
      t = (b << 2) + wv;
    } else if (b < 136) {
      A = (const ushort_t*)(ws + OFF_XQB); BT = (const ushort_t*)(ws + OFF_QW1T);
      M = 64; K = 512; outB = (ushort_t*)(ws + OFF_HQB); bias = bq;
      t = ((b - 128) << 2) + wv;
    } else {
      A = (const ushort_t*)(ws + OFF_XCB); BT = (const ushort_t*)(ws + OFF_CW1T);
      M = 16; K = 1024; outB = (ushort_t*)(ws + OFF_HCB); bias = bc;
      t = ((b - 136) << 2) + wv;
    }
  } else if (PHASE == 2) {
    if (b < 128) {
      A = (const ushort_t*)(ws + OFF_HAB); BT = (const ushort_t*)(ws + OFF_AW2T);
      M = 1024; K = 512; outF = ws + OFF_AHH;
      outS = (ushort_t*)(ws + OFF_AHHS); bias = ba; scl = rg;
      t = (b << 2) + wv;
    } else if (b < 136) {
      A = (const ushort_t*)(ws + OFF_HQB); BT = (const ushort_t*)(ws + OFF_QW2T);
      M = 64; K = 512; outF = ws + OFF_QH;
      outS = (ushort_t*)(ws + OFF_QHS); bias = bq; scl = rg + 512;
      t = ((b - 128) << 2) + wv;
    } else {
      A = (const ushort_t*)(ws + OFF_HCB); BT = (const ushort_t*)(ws + OFF_CW2T);
      M = 16; K = 512; outF = ws + OFF_CHH; bias = bc;
      t = ((b - 136) << 2) + wv;
    }
  } else {
    if (b < 128) {
      A = (const ushort_t*)(ws + OFF_AHHS); BT = (const ushort_t*)(ws + OFF_RW1LOT);
      M = 1024; K = 512; outF = ws + OFF_YA;
      t = (b << 2) + wv;
    } else {
      A = (const ushort_t*)(ws + OFF_QHS); BT = (const ushort_t*)(ws + OFF_RW1MIT);
      M = 64; K = 512; outF = ws + OFF_YQ;
      t = ((b - 128) << 2) + wv;
    }
  }

  const int rt = t >> 4, ct = t & 15;
  const int r0 = rt << 5, c0 = ct << 5;
  const int kh = (l >> 4) << 3;
  const ushort_t* ap[2];
  const ushort_t* bp[2];
#pragma unroll
  for (int fr = 0; fr < 2; ++fr) {
    int r = r0 + (fr << 4) + (l & 15);
    if (r > M - 1) r = M - 1;          // row clamp for small-M tiles
    ap[fr] = A + r * K + kh;
  }
#pragma unroll
  for (int cf = 0; cf < 2; ++cf)
    bp[cf] = BT + (c0 + (cf << 4) + (l & 15)) * K + kh;

  f32x4 acc[2][2] = {};
  const int nst = K >> 5;
#pragma unroll 4
  for (int ks = 0; ks < nst; ++ks) {
    bf16x8 afr[2], bfr[2];
#pragma unroll
    for (int fr = 0; fr < 2; ++fr)
      afr[fr] = __builtin_bit_cast(bf16x8, *(const uint4*)(ap[fr] + (ks << 5)));
#pragma unroll
    for (int cf = 0; cf < 2; ++cf)
      bfr[cf] = __builtin_bit_cast(bf16x8, *(const uint4*)(bp[cf] + (ks << 5)));
#pragma unroll
    for (int fr = 0; fr < 2; ++fr)
#pragma unroll
      for (int cf = 0; cf < 2; ++cf)
        acc[fr][cf] = __builtin_amdgcn_mfma_f32_16x16x32_bf16(
            afr[fr], bfr[cf], acc[fr][cf], 0, 0, 0);
  }

  const int rsub = (l >> 4) << 2, cl = l & 15;
#pragma unroll
  for (int fr = 0; fr < 2; ++fr) {
#pragma unroll
    for (int cf = 0; cf < 2; ++cf) {
      const int col = c0 + (cf << 4) + cl;
#pragma unroll
      for (int j = 0; j < 4; ++j) {
        const int row = r0 + (fr << 4) + rsub + j;
        if (row < M) {
          float v = acc[fr][cf][j];
          if (PHASE == 1) {
            outB[(row << 9) + col] = f2bf(gelu_fast(v + bias[col]));
          } else if (PHASE == 2) {
            v += bias[col];
            outF[(row << 9) + col] = v;
            if (outS) outS[(row << 9) + col] = f2bf(v * scl[col]);
          } else {
            outF[(row << 9) + col] = v;
          }
        }
      }
    }
  }
}

// ---------------------------- main fused kernel -----------------------------
// 1 block per (q-pair, w). 512 threads = 8 waves; __launch_bounds__(512,2)
// -> 256-reg cap. Wave wv: cols [wv*64, wv*64+64), 64 rows, BOTH pairs:
// acc0[4][4] + acc1[4][4] = 128 AGPR, ~90 VGPR working set -> no spill.
// Build: pair p = wv>>2, row-slot s = wv&3, 4 k-slices each (32 elem/chunk).
// K-chunk 128, 8 chunks, double-buffered 2x(2x16KB) LDS.
__global__ __launch_bounds__(512, 2) void main_kernel(
    const float* __restrict__ AH, const float* __restrict__ QH,
    const float* __restrict__ CH, const ushort_t* __restrict__ WT2,
    const float* __restrict__ Ya, const float* __restrict__ Yq,
    const float* __restrict__ S1, const float* __restrict__ B1,
    const float* __restrict__ rb1, const float* __restrict__ rw2,
    const float* __restrict__ rb2, const float* __restrict__ cmass,
    float* __restrict__ out) {
  extern __shared__ char smem_raw[];
  float* qs = (float*)smem_raw;          // 1024 (2 q rows)
  float* cs = qs + 1024;                 // 512
  float* s1_s = cs + 512;                // 128 ([p*64+r]) -> mu after loop
  float* s2_s = s1_s + 128;              // 128            -> rs after loop
  float* rel_s = s2_s + 128;             // 128
  float* misc = rel_s + 128;             // 4
  uint4* apv = (uint4*)(smem_raw + 8192);  // 2 buf x 2 pair x 16KB

  const int tid = threadIdx.x;           // 0..511
  const int l = tid & 63;
  const int wv = tid >> 6;               // 0..7
  const int w = blockIdx.x & 15;
  const int q0 = (blockIdx.x >> 4) << 1;

  qs[tid] = QH[(q0 << 9) + tid];
  qs[tid + 512] = QH[(q0 << 9) + 512 + tid];
  cs[tid] = CH[(w << 9) + tid];
  if (tid < 128) { s1_s[tid] = 0.f; s2_s[tid] = 0.f; rel_s[tid] = 0.f; }
  __syncthreads();

  const int p = wv >> 2;                 // build pair 0..1
  const int s = wv & 3;                  // build row-slot 0..3
  const int rloc = (s << 4) + (l & 15);
  const float* arow = AH + (((w << 6) + rloc) << 9);
  const float* qsrc = qs + (p << 9);
  const int kh = (l >> 4) << 3;          // 0,8,16,24
  float s1a = 0.f, s2a = 0.f;

  // build chunk C (k in [C*128,(C+1)*128)) into buffer B; 4 k-slices/thread
#define BUILD(C, B) do { \
    _Pragma("unroll") for (int ksl_ = 0; ksl_ < 4; ++ksl_) { \
      const int kg_ = ((C) << 7) + (ksl_ << 5) + kh; \
      const int ka_ = kg_ & 511; \
      const float4 a0_ = *(const float4*)(arow + ka_); \
      const float4 a1_ = *(const float4*)(arow + ka_ + 4); \
      const float4 q0_ = *(const float4*)(qsrc + ka_); \
      const float4 q1_ = *(const float4*)(qsrc + ka_ + 4); \
      const float av_[8] = {a0_.x, a0_.y, a0_.z, a0_.w, a1_.x, a1_.y, a1_.z, a1_.w}; \
      const float qv_[8] = {q0_.x, q0_.y, q0_.z, q0_.w, q1_.x, q1_.y, q1_.z, q1_.w}; \
      float vv_[8]; \
      if ((C) < 4) { \
        _Pragma("unroll") for (int j_ = 0; j_ < 8; ++j_) { \
          const float aq_ = av_[j_] * qv_[j_]; \
          vv_[j_] = aq_; \
          s1a += av_[j_] + aq_; \
          s2a += av_[j_] * av_[j_] + aq_ * aq_; \
        } \
      } else { \
        const float4 c0_ = *(const float4*)(cs + ka_); \
        const float4 c1_ = *(const float4*)(cs + ka_ + 4); \
        const float cv_[8] = {c0_.x, c0_.y, c0_.z, c0_.w, c1_.x, c1_.y, c1_.z, c1_.w}; \
        _Pragma("unroll") for (int j_ = 0; j_ < 8; ++j_) { \
          const float dd_ = fabsf(av_[j_] - qv_[j_]) + cv_[j_]; \
          vv_[j_] = dd_; \
          s1a += dd_; \
          s2a += dd_ * dd_; \
        } \
      } \
      union { __bf16 bv[8]; uint4 u4; } pk_; \
      _Pragma("unroll") for (int j_ = 0; j_ < 8; ++j_) pk_.bv[j_] = (__bf16)vv_[j_]; \
      apv[((B) << 11) + (p << 10) + (ksl_ << 8) + (s << 6) + l] = pk_.u4; \
    } } while (0)

  // ---- prologue: build chunk 0 into buf 0 + per-pair q-segment stats
  BUILD(0, 0);
  if ((wv & 3) == 0) {                   // wv==0 -> p=0, wv==4 -> p=1
    float sq = 0.f, sqq = 0.f;
#pragma unroll
    for (int it = 0; it < 8; ++it) {
      const float vq = qsrc[l + (it << 6)];
      sq += vq; sqq += vq * vq;
    }
#pragma unroll
    for (int off = 1; off < 64; off <<= 1) {
      sq += __shfl_xor(sq, off); sqq += __shfl_xor(sqq, off);
    }
    if (l == 0) { misc[(p << 1)] = sq; misc[(p << 1) + 1] = sqq; }
  }
  __syncthreads();

  // ---- chunk loop: BUILD(c+1) first (loads in flight), then MFMA(c) -------
  f32x4 acc0[4][4] = {}, acc1[4][4] = {};
  const int ncb = (wv << 6) + (l & 15);  // wave col base (wave: 64 cols)
#pragma unroll
  for (int c = 0; c < 8; ++c) {
    if (c < 7) {
      BUILD(c + 1, (c + 1) & 1);
    } else {
      // fold per-thread stats into per-pair per-row LDS totals
      s1a += __shfl_xor(s1a, 16); s1a += __shfl_xor(s1a, 32);
      s2a += __shfl_xor(s2a, 16); s2a += __shfl_xor(s2a, 32);
      if ((l >> 4) == 0) {
        atomicAdd(&s1_s[(p << 6) + rloc], s1a);
        atomicAdd(&s2_s[(p << 6) + rloc], s2a);
      }
    }
    const uint4* cbuf = apv + ((c & 1) << 11);
#pragma unroll
    for (int ksl = 0; ksl < 4; ++ksl) {
      const int ks32 = (c << 2) + ksl;
      bf16x8 bfr[4];
#pragma unroll
      for (int cf = 0; cf < 4; ++cf)
        bfr[cf] = __builtin_bit_cast(bf16x8,
            *(const uint4*)(WT2 + (ks32 << 14) + ((ncb + (cf << 4)) << 5) + kh));
      bf16x8 afr;
      // pair 0
#pragma unroll
      for (int fr = 0; fr < 4; ++fr) {
        afr = __builtin_bit_cast(bf16x8, cbuf[(ksl << 8) + (fr << 6) + l]);
#pragma unroll
        for (int cf = 0; cf < 4; ++cf)
          acc0[fr][cf] = __builtin_amdgcn_mfma_f32_16x16x32_bf16(
              afr, bfr[cf], acc0[fr][cf], 0, 0, 0);
      }
      // pair 1 (reuse afr register)
#pragma unroll
      for (int fr = 0; fr < 4; ++fr) {
        afr = __builtin_bit_cast(bf16x8,
            cbuf[(1 << 10) + (ksl << 8) + (fr << 6) + l]);
#pragma unroll
        for (int cf = 0; cf < 4; ++cf)
          acc1[fr][cf] = __builtin_amdgcn_mfma_f32_16x16x32_bf16(
              afr, bfr[cf], acc1[fr][cf], 0, 0, 0);
      }
    }
    __syncthreads();
  }
#undef BUILD

  // ---- finalize LN stats: 128 (pair,row) mu/rs computed once --------------
  if (tid < 128) {
    const int pp = tid >> 6;
    const float s1r = s1_s[tid] + misc[pp << 1];
    const float s2r = s2_s[tid] + misc[(pp << 1) + 1];
    const float mu = s1r * (1.0f / 2048.0f);
    const float rs = rsqrtf(s2r * (1.0f / 2048.0f) - mu * mu + 1e-5f);
    s1_s[tid] = mu;
    s2_s[tid] = rs;
  }
  __syncthreads();

  // ---- epilogue: LN-fold + gelu + dot(rw2) -> per-row relevance (2 pairs) --
  {
    float yqv0[4], yqv1[4], s1c[4], b1c[4], w2c[4];
#pragma unroll
    for (int cf = 0; cf < 4; ++cf) {
      const int n = ncb + (cf << 4);
      yqv0[cf] = Yq[(q0 << 9) + n];
      yqv1[cf] = Yq[((q0 + 1) << 9) + n];
      s1c[cf] = S1[n];
      b1c[cf] = B1[n] + rb1[n];
      w2c[cf] = rw2[n];
    }
    const float* yab = Ya + (w << 15) + ncb;
    const int rsub = (l >> 4) << 2;
#pragma unroll
    for (int fr = 0; fr < 4; ++fr) {
#pragma unroll
      for (int j = 0; j < 4; ++j) {
        const int r = (fr << 4) + rsub + j;
        const float mu0 = s1_s[r], rs0 = s2_s[r];
        const float mu1 = s1_s[64 + r], rs1 = s2_s[64 + r];
        float rp0 = 0.f, rp1 = 0.f;
#pragma unroll
        for (int cf = 0; cf < 4; ++cf) {
          const float ya = yab[(r << 9) + (cf << 4)];
          rp0 += gelu_fast(rs0 * (acc0[fr][cf][j] + ya + yqv0[cf] - mu0 * s1c[cf]) + b1c[cf]) * w2c[cf];
          rp1 += gelu_fast(rs1 * (acc1[fr][cf][j] + ya + yqv1[cf] - mu1 * s1c[cf]) + b1c[cf]) * w2c[cf];
        }
        rp0 += __shfl_xor(rp0, 1); rp0 += __shfl_xor(rp0, 2);
        rp0 += __shfl_xor(rp0, 4); rp0 += __shfl_xor(rp0, 8);
        rp1 += __shfl_xor(rp1, 1); rp1 += __shfl_xor(rp1, 2);
        rp1 += __shfl_xor(rp1, 4); rp1 += __shfl_xor(rp1, 8);
        if ((l & 15) == 0) {
          atomicAdd(&rel_s[r], rp0);
          atomicAdd(&rel_s[64 + r], rp1);
        }
      }
    }
  }
  __syncthreads();

  // ---- softmax over atoms + entropy (2 pairs: tid<128)
  if (tid < 128) {
    const int pp = tid >> 6, a = tid & 63;
    const int qw = ((q0 + pp) << 4) + w;
    const float relv = rel_s[(pp << 6) + a] + rb2[0];
    const float x = logf(fmaxf(cmass[(w << 6) + a], 1e-8f)) + relv;
    float m = x;
#pragma unroll
    for (int off = 1; off < 64; off <<= 1) m = fmaxf(m, __shfl_xor(m, off));
    const float pv = expf(x - m);
    float sv = pv;
#pragma unroll
    for (int off = 1; off < 64; off <<= 1) sv += __shfl_xor(sv, off);
    float mix = pv / fmaxf(sv, 1e-8f);
    float s2 = mix;
#pragma unroll
    for (int off = 1; off < 64; off <<= 1) s2 += __shfl_xor(s2, off);
    mix = mix / fmaxf(s2, 1e-8f);
    const float et = -mix * logf(fmaxf(mix, 1e-8f));
    float ent = et;
#pragma unroll
    for (int off = 1; off < 64; off <<= 1) ent += __shfl_xor(ent, off);
    out[(qw << 6) + a] = mix;                   // mixed[q][w][a]
    if (a == 0) out[65536 + qw] = ent;          // entropy[q][w]
  }
}

// ---------------------------------------------------------------------------
extern "C" void kernel_launch(void* const* d_in, const int* in_sizes, int n_in,
                              void* d_out, int out_size, void* d_ws, size_t ws_size,
                              hipStream_t stream) {
  (void)in_sizes; (void)n_in; (void)out_size; (void)ws_size;
  const float* q_atoms = (const float*)d_in[0];
  const float* q_mass  = (const float*)d_in[1];
  const float* c_atoms = (const float*)d_in[2];
  const float* c_mass  = (const float*)d_in[3];
  const float* c_sum   = (const float*)d_in[4];
  const float* e_ctx   = (const float*)d_in[5];
  const float* qg  = (const float*)d_in[6];  const float* qb  = (const float*)d_in[7];
  const float* qw1 = (const float*)d_in[8];  const float* qb1 = (const float*)d_in[9];
  const float* qw2 = (const float*)d_in[10]; const float* qb2 = (const float*)d_in[11];
  const float* ag  = (const float*)d_in[12]; const float* ab  = (const float*)d_in[13];
  const float* aw1 = (const float*)d_in[14]; const float* ab1 = (const float*)d_in[15];
  const float* aw2 = (const float*)d_in[16]; const float* ab2 = (const float*)d_in[17];
  const float* cg  = (const float*)d_in[18]; const float* cb  = (const float*)d_in[19];
  const float* cw1 = (const float*)d_in[20]; const float* cb1 = (const float*)d_in[21];
  const float* cw2 = (const float*)d_in[22]; const float* cb2 = (const float*)d_in[23];
  const float* rg  = (const float*)d_in[24]; const float* rb  = (const float*)d_in[25];
  const float* rw1 = (const float*)d_in[26]; const float* rb1 = (const float*)d_in[27];
  const float* rw2 = (const float*)d_in[28]; const float* rb2 = (const float*)d_in[29];

  float* ws = (float*)d_ws;
  float* out = (float*)d_out;

  hipMemsetAsync(ws + OFF_S1, 0, 1024 * sizeof(float), stream);  // S1+B1
  pre0_kernel<<<928, 512, 0, stream>>>(q_atoms, q_mass, c_atoms, c_sum, e_ctx,
                                       qg, qb, ag, ab, cg, cb, rw1, rg, rb,
                                       aw1, qw1, cw1, aw2, qw2, cw2, ws);
  gemm_kernel<1><<<140, 256, 0, stream>>>(ws, ab1, qb1, cb1, rg);
  gemm_kernel<2><<<140, 256, 0, stream>>>(ws, ab2, qb2, cb2, rg);
  gemm_kernel<3><<<136, 256, 0, stream>>>(ws, nullptr, nullptr, nullptr, rg);

  static const size_t MAIN_SMEM = 8192 + 65536;  // 73728 B
  hipFuncSetAttribute((const void*)main_kernel,
                      hipFuncAttributeMaxDynamicSharedMemorySize, (int)MAIN_SMEM);
  main_kernel<<<512, 512, MAIN_SMEM, stream>>>(
      ws + OFF_AHH, ws + OFF_QH, ws + OFF_CHH,
      (const ushort_t*)(ws + OFF_WT2), ws + OFF_YA, ws + OFF_YQ,
      ws + OFF_S1, ws + OFF_B1, rb1, rw2, rb2, c_mass, out);
}

// Round 12
// 170.850 us; speedup vs baseline: 1.8042x; 1.0509x over previous
//
#include <hip/hip_runtime.h>

// ---------------------------------------------------------------------------
// QueryConditionedTransportScorerV3 on MI355X (gfx950)
// Q=64 W=16 A=64 D=H=512.
//   fused@rw1 = Ya[w,a] + Yq[q] + [a*q ; |a-q|+c] @ (rg*rw1)[1024:2048] (MFMA)
//   h = rstd*(sum - mu*S1) + (rb1 + rb@rw1); gelu; @rw2; softmax+entropy fused
// Round 12: r11 + rolling B prefetch (ksl+1 loaded under ksl's MFMAs),
//   register-lean 4-element BUILD groups to pay for the prefetch regs,
//   setprio(1) around MFMA clusters. Canary: WRITE_SIZE must stay < 10 MB.
// ---------------------------------------------------------------------------

#define DEV static __device__ __forceinline__

typedef __attribute__((ext_vector_type(8))) __bf16 bf16x8;
typedef __attribute__((ext_vector_type(4))) float f32x4;
typedef unsigned short ushort_t;

DEV ushort_t f2bf(float f) {
  unsigned u = __builtin_bit_cast(unsigned, f);
  u = (u + 0x7fffu + ((u >> 16) & 1u)) >> 16;
  return (ushort_t)u;
}

// branch-free erf (Abramowitz-Stegun 7.1.26, |err| <= 1.5e-7)
DEV float gelu_fast(float x) {
  const float y = x * 0.70710678118654752f;
  const float z = fabsf(y);
  const float t = __fdividef(1.0f, 1.0f + 0.3275911f * z);
  float p = 1.061405429f;
  p = p * t - 1.453152027f;
  p = p * t + 1.421413741f;
  p = p * t - 0.284496736f;
  p = p * t + 0.254829592f;
  const float e = 1.0f - p * t * __expf(-z * z);
  const float erfv = copysignf(e, y);
  return 0.5f * x * (1.0f + erfv);
}

// ---- ws layout (float offsets) --------------------------------------------
#define OFF_XQB    0          // bf16 64x512    (aliased by QHS after P1)
#define OFF_XAB    16384      // bf16 1024x512  (aliased by AHHS after P1)
#define OFF_XCB    278528     // bf16 16x1024   (aliased by CHH f32 after P1)
#define OFF_HAB    286720     // bf16 1024x512
#define OFF_HQB    548864     // bf16 64x512
#define OFF_HCB    565248     // bf16 16x512
#define OFF_AHH    569344     // f32 1024x512
#define OFF_QH     1093632    // f32 64x512
#define OFF_S1     1126400    // f32 512
#define OFF_B1     1126912    // f32 512
#define OFF_WT2    1127424    // bf16 k-tiled hi rw1 (rg-scaled), 524288 el
#define OFF_RW1LOT 1389568    // bf16 [512n][512k] rw1[0:512]
#define OFF_RW1MIT 1520640    // bf16 [512n][512k] rw1[512:1024]
#define OFF_AW1T   1651712    // bf16 [512][512]   ┐
#define OFF_QW1T   1782784    // bf16 [512][512]   ├ dead after P1 -> YA
#define OFF_CW1T   1913856    // bf16 [512][1024]  ┘
#define OFF_AW2T   2176000    // bf16 [512][512]   ┐ dead after P2 -> YQ
#define OFF_QW2T   2307072    // bf16 [512][512]   ┘
#define OFF_CW2T   2438144    // bf16 [512][512]   (end: 2569216 fl)
#define OFF_YA     OFF_AW1T   // f32 1024x512
#define OFF_YQ     OFF_AW2T   // f32 64x512
#define OFF_CHH    OFF_XCB    // f32 16x512
#define OFF_AHHS   OFF_XAB    // bf16 1024x512 (ahh*rg_lo)
#define OFF_QHS    OFF_XQB    // bf16 64x512   (qh*rg_mid)

// WT2 k-tiled layout: element (n, k2) at (k2>>5)*16384 + n*32 + (k2&31).

// ======================== P0: wide prep kernel ==============================
DEV void transpose_tile(const float* __restrict__ src, int koff, int kt, int ct,
                        ushort_t* __restrict__ dst, int ldk, float* sh, int tid) {
  float (*t)[65] = (float(*)[65])sh;
  for (int idx = tid; idx < 4096; idx += 512) {
    const int r = idx >> 6, c = idx & 63;
    t[r][c] = src[(koff + kt + r) * 512 + ct + c];
  }
  __syncthreads();
  for (int idx = tid; idx < 4096; idx += 512) {
    const int c = idx >> 6, r = idx & 63;
    dst[(ct + c) * ldk + kt + r] = f2bf(t[r][c]);
  }
}

// roles: [0,128) WT2 | [128,192) rw1loT | [192,256) rw1midT | [256,320) aw1T
// [320,384) qw1T | [384,512) cw1T | [512,576) aw2T | [576,640) qw2T
// [640,704) cw2T | [704,720) S1/B1 | [720,784) q pool+LN | [784,912) a LN
// [912,928) c concat+LN
__global__ __launch_bounds__(512) void pre0_kernel(
    const float* __restrict__ qa, const float* __restrict__ qm,
    const float* __restrict__ ca, const float* __restrict__ csum,
    const float* __restrict__ ectx,
    const float* __restrict__ qg, const float* __restrict__ qb,
    const float* __restrict__ ag, const float* __restrict__ ab,
    const float* __restrict__ cg, const float* __restrict__ cb,
    const float* __restrict__ rw1, const float* __restrict__ rg,
    const float* __restrict__ rb,
    const float* __restrict__ aw1, const float* __restrict__ qw1,
    const float* __restrict__ cw1, const float* __restrict__ aw2,
    const float* __restrict__ qw2, const float* __restrict__ cw2,
    float* __restrict__ ws) {
  __shared__ float sh[4160];
  const int b = blockIdx.x, tid = threadIdx.x, l = tid & 63, wv = tid >> 6;

  if (b < 128) {
    ushort_t* WT = (ushort_t*)(ws + OFF_WT2);
    float (*t)[65] = (float(*)[65])sh;
    const int kt = (b >> 3) << 6;
    const int ct = (b & 7) << 6;
    for (int idx = tid; idx < 4096; idx += 512) {
      const int r = idx >> 6, c = idx & 63;
      t[r][c] = rg[1024 + kt + r] * rw1[(1024 + kt + r) * 512 + ct + c];
    }
    __syncthreads();
    for (int idx = tid; idx < 4096; idx += 512) {
      const int c = idx >> 6, r = idx & 63;
      const int n = ct + c, k2 = kt + r;
      WT[((k2 >> 5) << 14) + (n << 5) + (k2 & 31)] = f2bf(t[r][c]);
    }
  } else if (b < 192) {
    const int bb = b - 128;
    transpose_tile(rw1, 0, (bb >> 3) << 6, (bb & 7) << 6,
                   (ushort_t*)(ws + OFF_RW1LOT), 512, sh, tid);
  } else if (b < 256) {
    const int bb = b - 192;
    transpose_tile(rw1, 512, (bb >> 3) << 6, (bb & 7) << 6,
                   (ushort_t*)(ws + OFF_RW1MIT), 512, sh, tid);
  } else if (b < 320) {
    const int bb = b - 256;
    transpose_tile(aw1, 0, (bb >> 3) << 6, (bb & 7) << 6,
                   (ushort_t*)(ws + OFF_AW1T), 512, sh, tid);
  } else if (b < 384) {
    const int bb = b - 320;
    transpose_tile(qw1, 0, (bb >> 3) << 6, (bb & 7) << 6,
                   (ushort_t*)(ws + OFF_QW1T), 512, sh, tid);
  } else if (b < 512) {
    const int bb = b - 384;
    transpose_tile(cw1, 0, (bb >> 3) << 6, (bb & 7) << 6,
                   (ushort_t*)(ws + OFF_CW1T), 1024, sh, tid);
  } else if (b < 576) {
    const int bb = b - 512;
    transpose_tile(aw2, 0, (bb >> 3) << 6, (bb & 7) << 6,
                   (ushort_t*)(ws + OFF_AW2T), 512, sh, tid);
  } else if (b < 640) {
    const int bb = b - 576;
    transpose_tile(qw2, 0, (bb >> 3) << 6, (bb & 7) << 6,
                   (ushort_t*)(ws + OFF_QW2T), 512, sh, tid);
  } else if (b < 704) {
    const int bb = b - 640;
    transpose_tile(cw2, 0, (bb >> 3) << 6, (bb & 7) << 6,
                   (ushort_t*)(ws + OFF_CW2T), 512, sh, tid);
  } else if (b < 720) {
    const int kc = (b - 704) << 7;
    float s0 = 0.f, s1 = 0.f, b0 = 0.f, b1v = 0.f;
    for (int k = kc; k < kc + 128; k += 2) {
      const float wa = rw1[(k << 9) + tid];
      const float wb = rw1[((k + 1) << 9) + tid];
      s0 += rg[k] * wa; b0 += rb[k] * wa;
      s1 += rg[k + 1] * wb; b1v += rb[k + 1] * wb;
    }
    atomicAdd(ws + OFF_S1 + tid, s0 + s1);
    atomicAdd(ws + OFF_B1 + tid, b0 + b1v);
  } else if (b < 784) {
    const int q = b - 720;
    if (wv == 0) {
      float m = fmaxf(qm[(q << 6) + l], 0.f);
      sh[l] = m;
      float s = m;
#pragma unroll
      for (int off = 1; off < 64; off <<= 1) s += __shfl_xor(s, off);
      if (l == 0) sh[64] = 1.0f / fmaxf(s, 1e-8f);
    }
    __syncthreads();
    const float sinv = sh[64];
    const float* qaq = qa + (q << 15) + tid;
    float v0 = 0.f, v1 = 0.f, v2 = 0.f, v3 = 0.f;
#pragma unroll 4
    for (int a = 0; a < 64; a += 4) {
      v0 += sh[a] * qaq[a << 9];
      v1 += sh[a + 1] * qaq[(a + 1) << 9];
      v2 += sh[a + 2] * qaq[(a + 2) << 9];
      v3 += sh[a + 3] * qaq[(a + 3) << 9];
    }
    const float v = (v0 + v1 + v2 + v3) * sinv;
    float s = v, ss = v * v;
#pragma unroll
    for (int off = 1; off < 64; off <<= 1) {
      s += __shfl_xor(s, off); ss += __shfl_xor(ss, off);
    }
    if (l == 0) { sh[128 + wv] = s; sh[136 + wv] = ss; }
    __syncthreads();
    float st = 0.f, sst = 0.f;
#pragma unroll
    for (int i = 0; i < 8; ++i) { st += sh[128 + i]; sst += sh[136 + i]; }
    const float mu = st * (1.0f / 512.0f);
    const float rstd = rsqrtf(sst * (1.0f / 512.0f) - mu * mu + 1e-5f);
    ((ushort_t*)(ws + OFF_XQB))[(q << 9) + tid] =
        f2bf((v - mu) * rstd * qg[tid] + qb[tid]);
  } else if (b < 912) {
    const int row = ((b - 784) << 3) + wv;
    const float* crow = ca + (row << 9);
    float x[8];
    float s = 0.f, ss = 0.f;
#pragma unroll
    for (int i = 0; i < 8; ++i) {
      x[i] = crow[l + (i << 6)];
      s += x[i]; ss += x[i] * x[i];
    }
#pragma unroll
    for (int off = 1; off < 64; off <<= 1) {
      s += __shfl_xor(s, off); ss += __shfl_xor(ss, off);
    }
    const float mu = s * (1.0f / 512.0f);
    const float rstd = rsqrtf(ss * (1.0f / 512.0f) - mu * mu + 1e-5f);
    ushort_t* xab = (ushort_t*)(ws + OFF_XAB);
#pragma unroll
    for (int i = 0; i < 8; ++i) {
      const int k = l + (i << 6);
      xab[(row << 9) + k] = f2bf((x[i] - mu) * rstd * ag[k] + ab[k]);
    }
  } else {
    const int w = b - 912;
    const float v0 = csum[(w << 9) + tid];
    const float v1 = ectx[(w << 9) + tid];
    float s = v0 + v1, ss = v0 * v0 + v1 * v1;
#pragma unroll
    for (int off = 1; off < 64; off <<= 1) {
      s += __shfl_xor(s, off); ss += __shfl_xor(ss, off);
    }
    if (l == 0) { sh[wv] = s; sh[8 + wv] = ss; }
    __syncthreads();
    float st = 0.f, sst = 0.f;
#pragma unroll
    for (int i = 0; i < 8; ++i) { st += sh[i]; sst += sh[8 + i]; }
    const float mu = st * (1.0f / 1024.0f);
    const float rstd = rsqrtf(sst * (1.0f / 1024.0f) - mu * mu + 1e-5f);
    ushort_t* xcb = (ushort_t*)(ws + OFF_XCB);
    xcb[(w << 10) + tid] = f2bf((v0 - mu) * rstd * cg[tid] + cb[tid]);
    xcb[(w << 10) + 512 + tid] =
        f2bf((v1 - mu) * rstd * cg[512 + tid] + cb[512 + tid]);
  }
}

// ======================== MFMA GEMM phases (32x32 tiles/wave) ===============
template <int PHASE>
__global__ __launch_bounds__(256) void gemm_kernel(
    float* __restrict__ ws, const float* __restrict__ ba,
    const float* __restrict__ bq, const float* __restrict__ bc,
    const float* __restrict__ rg) {
  const int b = blockIdx.x, tid = threadIdx.x;
  const int l = tid & 63, wv = tid >> 6;

  const ushort_t* A; const ushort_t* BT;
  float* outF = nullptr; ushort_t* outB = nullptr; ushort_t* outS = nullptr;
  const float* bias = nullptr; const float* scl = nullptr;
  int M, K, t;

  if (PHASE == 1) {
    if (b < 128) {
      A = (const ushort_t*)(ws + OFF_XAB); BT = (const ushort_t*)(ws + OFF_AW1T);
      M = 1024; K = 512; outB = (ushort_t*)(ws + OFF_HAB); bias = ba;
      t = (b << 2) + wv;
    } else if (b < 136) {
      A = (const ushort_t*)(ws + OFF_XQB); BT = (const ushort_t*)(ws + OFF_QW1T);
      M = 64; K = 512; outB = (ushort_t*)(ws + OFF_HQB); bias = bq;
      t = ((b - 128) << 2) + wv;
    } else {
      A = (const ushort_t*)(ws + OFF_XCB); BT = (const ushort_t*)(ws + OFF_CW1T);
      M = 16; K = 1024; outB = (ushort_t*)(ws + OFF_HCB); bias = bc;
      t = ((b - 136) << 2) + wv;
    }
  } else if (PHASE == 2) {
    if (b < 128) {
      A = (const ushort_t*)(ws + OFF_HAB); BT = (const ushort_t*)(ws + OFF_AW2T);
      M = 1024; K = 512; outF = ws + OFF_AHH;
      outS = (ushort_t*)(ws + OFF_AHHS); bias = ba; scl = rg;
      t = (b << 2) + wv;
    } else if (b < 136) {
      A = (const ushort_t*)(ws + OFF_HQB); BT = (const ushort_t*)(ws + OFF_QW2T);
      M = 64; K = 512; outF = ws + OFF_QH;
      outS = (ushort_t*)(ws + OFF_QHS); bias = bq; scl = rg + 512;
      t = ((b - 128) << 2) + wv;
    } else {
      A = (const ushort_t*)(ws + OFF_HCB); BT = (const ushort_t*)(ws + OFF_CW2T);
      M = 16; K = 512; outF = ws + OFF_CHH; bias = bc;
      t = ((b - 136) << 2) + wv;
    }
  } else {
    if (b < 128) {
      A = (const ushort_t*)(ws + OFF_AHHS); BT = (const ushort_t*)(ws + OFF_RW1LOT);
      M = 1024; K = 512; outF = ws + OFF_YA;
      t = (b << 2) + wv;
    } else {
      A = (const ushort_t*)(ws + OFF_QHS); BT = (const ushort_t*)(ws + OFF_RW1MIT);
      M = 64; K = 512; outF = ws + OFF_YQ;
      t = ((b - 128) << 2) + wv;
    }
  }

  const int rt = t >> 4, ct = t & 15;
  const int r0 = rt << 5, c0 = ct << 5;
  const int kh = (l >> 4) << 3;
  const ushort_t* ap[2];
  const ushort_t* bp[2];
#pragma unroll
  for (int fr = 0; fr < 2; ++fr) {
    int r = r0 + (fr << 4) + (l & 15);
    if (r > M - 1) r = M - 1;          // row clamp for small-M tiles
    ap[fr] = A + r * K + kh;
  }
#pragma unroll
  for (int cf = 0; cf < 2; ++cf)
    bp[cf] = BT + (c0 + (cf << 4) + (l & 15)) * K + kh;

  f32x4 acc[2][2] = {};
  const int nst = K >> 5;
#pragma unroll 4
  for (int ks = 0; ks < nst; ++ks) {
    bf16x8 afr[2], bfr[2];
#pragma unroll
    for (int fr = 0; fr < 2; ++fr)
      afr[fr] = __builtin_bit_cast(bf16x8, *(const uint4*)(ap[fr] + (ks << 5)));
#pragma unroll
    for (int cf = 0; cf < 2; ++cf)
      bfr[cf] = __builtin_bit_cast(bf16x8, *(const uint4*)(bp[cf] + (ks << 5)));
#pragma unroll
    for (int fr = 0; fr < 2; ++fr)
#pragma unroll
      for (int cf = 0; cf < 2; ++cf)
        acc[fr][cf] = __builtin_amdgcn_mfma_f32_16x16x32_bf16(
            afr[fr], bfr[cf], acc[fr][cf], 0, 0, 0);
  }

  const int rsub = (l >> 4) << 2, cl = l & 15;
#pragma unroll
  for (int fr = 0; fr < 2; ++fr) {
#pragma unroll
    for (int cf = 0; cf < 2; ++cf) {
      const int col = c0 + (cf << 4) + cl;
#pragma unroll
      for (int j = 0; j < 4; ++j) {
        const int row = r0 + (fr << 4) + rsub + j;
        if (row < M) {
          float v = acc[fr][cf][j];
          if (PHASE == 1) {
            outB[(row << 9) + col] = f2bf(gelu_fast(v + bias[col]));
          } else if (PHASE == 2) {
            v += bias[col];
            outF[(row << 9) + col] = v;
            if (outS) outS[(row << 9) + col] = f2bf(v * scl[col]);
          } else {
            outF[(row << 9) + col] = v;
          }
        }
      }
    }
  }
}

// ---------------------------- main fused kernel -----------------------------
// 1 block per (q-pair, w). 512 threads = 8 waves; __launch_bounds__(512,2)
// -> 256-reg cap. Wave wv: cols [wv*64, wv*64+64), 64 rows, BOTH pairs:
// acc0[4][4] + acc1[4][4] = 128 AGPR. Rolling B prefetch (ksl+1 under ksl's
// MFMAs); BUILD uses 4-element groups to stay register-lean.
__global__ __launch_bounds__(512, 2) void main_kernel(
    const float* __restrict__ AH, const float* __restrict__ QH,
    const float* __restrict__ CH, const ushort_t* __restrict__ WT2,
    const float* __restrict__ Ya, const float* __restrict__ Yq,
    const float* __restrict__ S1, const float* __restrict__ B1,
    const float* __restrict__ rb1, const float* __restrict__ rw2,
    const float* __restrict__ rb2, const float* __restrict__ cmass,
    float* __restrict__ out) {
  extern __shared__ char smem_raw[];
  float* qs = (float*)smem_raw;          // 1024 (2 q rows)
  float* cs = qs + 1024;                 // 512
  float* s1_s = cs + 512;                // 128 ([p*64+r]) -> mu after loop
  float* s2_s = s1_s + 128;              // 128            -> rs after loop
  float* rel_s = s2_s + 128;             // 128
  float* misc = rel_s + 128;             // 4
  uint4* apv = (uint4*)(smem_raw + 8192);  // 2 buf x 2 pair x 16KB

  const int tid = threadIdx.x;           // 0..511
  const int l = tid & 63;
  const int wv = tid >> 6;               // 0..7
  const int w = blockIdx.x & 15;
  const int q0 = (blockIdx.x >> 4) << 1;

  qs[tid] = QH[(q0 << 9) + tid];
  qs[tid + 512] = QH[(q0 << 9) + 512 + tid];
  cs[tid] = CH[(w << 9) + tid];
  if (tid < 128) { s1_s[tid] = 0.f; s2_s[tid] = 0.f; rel_s[tid] = 0.f; }
  __syncthreads();

  const int p = wv >> 2;                 // build pair 0..1
  const int s = wv & 3;                  // build row-slot 0..3
  const int rloc = (s << 4) + (l & 15);
  const float* arow = AH + (((w << 6) + rloc) << 9);
  const float* qsrc = qs + (p << 9);
  const int kh = (l >> 4) << 3;          // 0,8,16,24
  float s1a = 0.f, s2a = 0.f;

  // build chunk C (k in [C*128,(C+1)*128)) into buffer B; 4-elem groups,
  // minimal live registers (one float4 triple at a time).
#define BUILD(C, B) do { \
    _Pragma("unroll") for (int ksl_ = 0; ksl_ < 4; ++ksl_) { \
      const int kg_ = ((C) << 7) + (ksl_ << 5) + kh; \
      const int ka_ = kg_ & 511; \
      union { __bf16 bv[8]; uint4 u4; } pk_; \
      _Pragma("unroll") for (int h_ = 0; h_ < 2; ++h_) { \
        const float4 a_ = *(const float4*)(arow + ka_ + (h_ << 2)); \
        const float4 qv_ = *(const float4*)(qsrc + ka_ + (h_ << 2)); \
        float v0_, v1_, v2_, v3_; \
        if ((C) < 4) { \
          v0_ = a_.x * qv_.x; v1_ = a_.y * qv_.y; \
          v2_ = a_.z * qv_.z; v3_ = a_.w * qv_.w; \
          s1a += (a_.x + a_.y + a_.z + a_.w) + (v0_ + v1_ + v2_ + v3_); \
          s2a += (a_.x * a_.x + a_.y * a_.y + a_.z * a_.z + a_.w * a_.w) + \
                 (v0_ * v0_ + v1_ * v1_ + v2_ * v2_ + v3_ * v3_); \
        } else { \
          const float4 c_ = *(const float4*)(cs + ka_ + (h_ << 2)); \
          v0_ = fabsf(a_.x - qv_.x) + c_.x; \
          v1_ = fabsf(a_.y - qv_.y) + c_.y; \
          v2_ = fabsf(a_.z - qv_.z) + c_.z; \
          v3_ = fabsf(a_.w - qv_.w) + c_.w; \
          s1a += v0_ + v1_ + v2_ + v3_; \
          s2a += v0_ * v0_ + v1_ * v1_ + v2_ * v2_ + v3_ * v3_; \
        } \
        pk_.bv[(h_ << 2) + 0] = (__bf16)v0_; \
        pk_.bv[(h_ << 2) + 1] = (__bf16)v1_; \
        pk_.bv[(h_ << 2) + 2] = (__bf16)v2_; \
        pk_.bv[(h_ << 2) + 3] = (__bf16)v3_; \
      } \
      apv[((B) << 11) + (p << 10) + (ksl_ << 8) + (s << 6) + l] = pk_.u4; \
    } } while (0)

  // ---- prologue: build chunk 0 into buf 0 + per-pair q-segment stats
  BUILD(0, 0);
  if ((wv & 3) == 0) {                   // wv==0 -> p=0, wv==4 -> p=1
    float sq = 0.f, sqq = 0.f;
#pragma unroll
    for (int it = 0; it < 8; ++it) {
      const float vq = qsrc[l + (it << 6)];
      sq += vq; sqq += vq * vq;
    }
#pragma unroll
    for (int off = 1; off < 64; off <<= 1) {
      sq += __shfl_xor(sq, off); sqq += __shfl_xor(sqq, off);
    }
    if (l == 0) { misc[(p << 1)] = sq; misc[(p << 1) + 1] = sqq; }
  }
  __syncthreads();

  // ---- chunk loop: BUILD(c+1), then MFMA(c) with rolling B prefetch -------
  f32x4 acc0[4][4] = {}, acc1[4][4] = {};
  const int ncb = (wv << 6) + (l & 15);  // wave col base (wave: 64 cols)
  const int boff = (ncb << 5) + kh;      // per-lane B offset within a slice
#pragma unroll
  for (int c = 0; c < 8; ++c) {
    if (c < 7) {
      BUILD(c + 1, (c + 1) & 1);
    } else {
      // fold per-thread stats into per-pair per-row LDS totals
      s1a += __shfl_xor(s1a, 16); s1a += __shfl_xor(s1a, 32);
      s2a += __shfl_xor(s2a, 16); s2a += __shfl_xor(s2a, 32);
      if ((l >> 4) == 0) {
        atomicAdd(&s1_s[(p << 6) + rloc], s1a);
        atomicAdd(&s2_s[(p << 6) + rloc], s2a);
      }
    }
    const uint4* cbuf = apv + ((c & 1) << 11);
    const ushort_t* wb = WT2 + ((c << 2) << 14) + boff;   // chunk B base
    // preload B for ksl = 0
    uint4 bn0 = *(const uint4*)(wb);
    uint4 bn1 = *(const uint4*)(wb + (16 << 5));
    uint4 bn2 = *(const uint4*)(wb + (32 << 5));
    uint4 bn3 = *(const uint4*)(wb + (48 << 5));
#pragma unroll
    for (int ksl = 0; ksl < 4; ++ksl) {
      const bf16x8 bf0 = __builtin_bit_cast(bf16x8, bn0);
      const bf16x8 bf1 = __builtin_bit_cast(bf16x8, bn1);
      const bf16x8 bf2 = __builtin_bit_cast(bf16x8, bn2);
      const bf16x8 bf3 = __builtin_bit_cast(bf16x8, bn3);
      if (ksl < 3) {                     // prefetch B for ksl+1
        const ushort_t* wn = wb + ((ksl + 1) << 14);
        bn0 = *(const uint4*)(wn);
        bn1 = *(const uint4*)(wn + (16 << 5));
        bn2 = *(const uint4*)(wn + (32 << 5));
        bn3 = *(const uint4*)(wn + (48 << 5));
      }
      bf16x8 afr;
      __builtin_amdgcn_s_setprio(1);
      // pair 0
#pragma unroll
      for (int fr = 0; fr < 4; ++fr) {
        afr = __builtin_bit_cast(bf16x8, cbuf[(ksl << 8) + (fr << 6) + l]);
        acc0[fr][0] = __builtin_amdgcn_mfma_f32_16x16x32_bf16(afr, bf0, acc0[fr][0], 0, 0, 0);
        acc0[fr][1] = __builtin_amdgcn_mfma_f32_16x16x32_bf16(afr, bf1, acc0[fr][1], 0, 0, 0);
        acc0[fr][2] = __builtin_amdgcn_mfma_f32_16x16x32_bf16(afr, bf2, acc0[fr][2], 0, 0, 0);
        acc0[fr][3] = __builtin_amdgcn_mfma_f32_16x16x32_bf16(afr, bf3, acc0[fr][3], 0, 0, 0);
      }
      // pair 1 (reuse afr register)
#pragma unroll
      for (int fr = 0; fr < 4; ++fr) {
        afr = __builtin_bit_cast(bf16x8, cbuf[(1 << 10) + (ksl << 8) + (fr << 6) + l]);
        acc1[fr][0] = __builtin_amdgcn_mfma_f32_16x16x32_bf16(afr, bf0, acc1[fr][0], 0, 0, 0);
        acc1[fr][1] = __builtin_amdgcn_mfma_f32_16x16x32_bf16(afr, bf1, acc1[fr][1], 0, 0, 0);
        acc1[fr][2] = __builtin_amdgcn_mfma_f32_16x16x32_bf16(afr, bf2, acc1[fr][2], 0, 0, 0);
        acc1[fr][3] = __builtin_amdgcn_mfma_f32_16x16x32_bf16(afr, bf3, acc1[fr][3], 0, 0, 0);
      }
      __builtin_amdgcn_s_setprio(0);
    }
    __syncthreads();
  }
#undef BUILD

  // ---- finalize LN stats: 128 (pair,row) mu/rs computed once --------------
  if (tid < 128) {
    const int pp = tid >> 6;
    const float s1r = s1_s[tid] + misc[pp << 1];
    const float s2r = s2_s[tid] + misc[(pp << 1) + 1];
    const float mu = s1r * (1.0f / 2048.0f);
    const float rs = rsqrtf(s2r * (1.0f / 2048.0f) - mu * mu + 1e-5f);
    s1_s[tid] = mu;
    s2_s[tid] = rs;
  }
  __syncthreads();

  // ---- epilogue: LN-fold + gelu + dot(rw2) -> per-row relevance (2 pairs) --
  {
    float yqv0[4], yqv1[4], s1c[4], b1c[4], w2c[4];
#pragma unroll
    for (int cf = 0; cf < 4; ++cf) {
      const int n = ncb + (cf << 4);
      yqv0[cf] = Yq[(q0 << 9) + n];
      yqv1[cf] = Yq[((q0 + 1) << 9) + n];
      s1c[cf] = S1[n];
      b1c[cf] = B1[n] + rb1[n];
      w2c[cf] = rw2[n];
    }
    const float* yab = Ya + (w << 15) + ncb;
    const int rsub = (l >> 4) << 2;
#pragma unroll
    for (int fr = 0; fr < 4; ++fr) {
#pragma unroll
      for (int j = 0; j < 4; ++j) {
        const int r = (fr << 4) + rsub + j;
        const float mu0 = s1_s[r], rs0 = s2_s[r];
        const float mu1 = s1_s[64 + r], rs1 = s2_s[64 + r];
        float rp0 = 0.f, rp1 = 0.f;
#pragma unroll
        for (int cf = 0; cf < 4; ++cf) {
          const float ya = yab[(r << 9) + (cf << 4)];
          rp0 += gelu_fast(rs0 * (acc0[fr][cf][j] + ya + yqv0[cf] - mu0 * s1c[cf]) + b1c[cf]) * w2c[cf];
          rp1 += gelu_fast(rs1 * (acc1[fr][cf][j] + ya + yqv1[cf] - mu1 * s1c[cf]) + b1c[cf]) * w2c[cf];
        }
        rp0 += __shfl_xor(rp0, 1); rp0 += __shfl_xor(rp0, 2);
        rp0 += __shfl_xor(rp0, 4); rp0 += __shfl_xor(rp0, 8);
        rp1 += __shfl_xor(rp1, 1); rp1 += __shfl_xor(rp1, 2);
        rp1 += __shfl_xor(rp1, 4); rp1 += __shfl_xor(rp1, 8);
        if ((l & 15) == 0) {
          atomicAdd(&rel_s[r], rp0);
          atomicAdd(&rel_s[64 + r], rp1);
        }
      }
    }
  }
  __syncthreads();

  // ---- softmax over atoms + entropy (2 pairs: tid<128)
  if (tid < 128) {
    const int pp = tid >> 6, a = tid & 63;
    const int qw = ((q0 + pp) << 4) + w;
    const float relv = rel_s[(pp << 6) + a] + rb2[0];
    const float x = logf(fmaxf(cmass[(w << 6) + a], 1e-8f)) + relv;
    float m = x;
#pragma unroll
    for (int off = 1; off < 64; off <<= 1) m = fmaxf(m, __shfl_xor(m, off));
    const float pv = expf(x - m);
    float sv = pv;
#pragma unroll
    for (int off = 1; off < 64; off <<= 1) sv += __shfl_xor(sv, off);
    float mix = pv / fmaxf(sv, 1e-8f);
    float s2 = mix;
#pragma unroll
    for (int off = 1; off < 64; off <<= 1) s2 += __shfl_xor(s2, off);
    mix = mix / fmaxf(s2, 1e-8f);
    const float et = -mix * logf(fmaxf(mix, 1e-8f));
    float ent = et;
#pragma unroll
    for (int off = 1; off < 64; off <<= 1) ent += __shfl_xor(ent, off);
    out[(qw << 6) + a] = mix;                   // mixed[q][w][a]
    if (a == 0) out[65536 + qw] = ent;          // entropy[q][w]
  }
}

// ---------------------------------------------------------------------------
extern "C" void kernel_launch(void* const* d_in, const int* in_sizes, int n_in,
                              void* d_out, int out_size, void* d_ws, size_t ws_size,
                              hipStream_t stream) {
  (void)in_sizes; (void)n_in; (void)out_size; (void)ws_size;
  const float* q_atoms = (const float*)d_in[0];
  const float* q_mass  = (const float*)d_in[1];
  const float* c_atoms = (const float*)d_in[2];
  const float* c_mass  = (const float*)d_in[3];
  const float* c_sum   = (const float*)d_in[4];
  const float* e_ctx   = (const float*)d_in[5];
  const float* qg  = (const float*)d_in[6];  const float* qb  = (const float*)d_in[7];
  const float* qw1 = (const float*)d_in[8];  const float* qb1 = (const float*)d_in[9];
  const float* qw2 = (const float*)d_in[10]; const float* qb2 = (const float*)d_in[11];
  const float* ag  = (const float*)d_in[12]; const float* ab  = (const float*)d_in[13];
  const float* aw1 = (const float*)d_in[14]; const float* ab1 = (const float*)d_in[15];
  const float* aw2 = (const float*)d_in[16]; const float* ab2 = (const float*)d_in[17];
  const float* cg  = (const float*)d_in[18]; const float* cb  = (const float*)d_in[19];
  const float* cw1 = (const float*)d_in[20]; const float* cb1 = (const float*)d_in[21];
  const float* cw2 = (const float*)d_in[22]; const float* cb2 = (const float*)d_in[23];
  const float* rg  = (const float*)d_in[24]; const float* rb  = (const float*)d_in[25];
  const float* rw1 = (const float*)d_in[26]; const float* rb1 = (const float*)d_in[27];
  const float* rw2 = (const float*)d_in[28]; const float* rb2 = (const float*)d_in[29];

  float* ws = (float*)d_ws;
  float* out = (float*)d_out;

  hipMemsetAsync(ws + OFF_S1, 0, 1024 * sizeof(float), stream);  // S1+B1
  pre0_kernel<<<928, 512, 0, stream>>>(q_atoms, q_mass, c_atoms, c_sum, e_ctx,
                                       qg, qb, ag, ab, cg, cb, rw1, rg, rb,
                                       aw1, qw1, cw1, aw2, qw2, cw2, ws);
  gemm_kernel<1><<<140, 256, 0, stream>>>(ws, ab1, qb1, cb1, rg);
  gemm_kernel<2><<<140, 256, 0, stream>>>(ws, ab2, qb2, cb2, rg);
  gemm_kernel<3><<<136, 256, 0, stream>>>(ws, nullptr, nullptr, nullptr, rg);

  static const size_t MAIN_SMEM = 8192 + 65536;  // 73728 B
  hipFuncSetAttribute((const void*)main_kernel,
                      hipFuncAttributeMaxDynamicSharedMemorySize, (int)MAIN_SMEM);
  main_kernel<<<512, 512, MAIN_SMEM, stream>>>(
      ws + OFF_AHH, ws + OFF_QH, ws + OFF_CHH,
      (const ushort_t*)(ws + OFF_WT2), ws + OFF_YA, ws + OFF_YQ,
      ws + OFF_S1, ws + OFF_B1, rb1, rw2, rb2, c_mass, out);
}

// Round 13
// 162.807 us; speedup vs baseline: 1.8933x; 1.0494x over previous
//
#include <hip/hip_runtime.h>

// ---------------------------------------------------------------------------
// QueryConditionedTransportScorerV3 on MI355X (gfx950)
// Q=64 W=16 A=64 D=H=512.
//   fused@rw1 = Ya[w,a] + Yq[q] + [a*q ; |a-q|+c] @ (rg*rw1)[1024:2048] (MFMA)
//   h = rstd*(sum - mu*S1) + (rb1 + rb@rw1); gelu; @rw2; softmax+entropy fused
// Round 13: r12 + epilogue VALU diet — sigmoid-GELU (6 VALU vs 20) in the
//   main epilogue only (pre-path keeps exact erf), hoisted per-(r,cf) terms.
// ---------------------------------------------------------------------------

#define DEV static __device__ __forceinline__

typedef __attribute__((ext_vector_type(8))) __bf16 bf16x8;
typedef __attribute__((ext_vector_type(4))) float f32x4;
typedef unsigned short ushort_t;

DEV ushort_t f2bf(float f) {
  unsigned u = __builtin_bit_cast(unsigned, f);
  u = (u + 0x7fffu + ((u >> 16) & 1u)) >> 16;
  return (ushort_t)u;
}

// branch-free erf (Abramowitz-Stegun 7.1.26, |err| <= 1.5e-7) — pre-path only
DEV float gelu_fast(float x) {
  const float y = x * 0.70710678118654752f;
  const float z = fabsf(y);
  const float t = __fdividef(1.0f, 1.0f + 0.3275911f * z);
  float p = 1.061405429f;
  p = p * t - 1.453152027f;
  p = p * t + 1.421413741f;
  p = p * t - 0.284496736f;
  p = p * t + 0.254829592f;
  const float e = 1.0f - p * t * __expf(-z * z);
  const float erfv = copysignf(e, y);
  return 0.5f * x * (1.0f + erfv);
}

// cheap sigmoid-GELU for the main epilogue (err <= ~0.01 per element)
DEV float gelu_sig(float x) {
  return x * __frcp_rn(1.0f + __expf(-1.702f * x));
}

// ---- ws layout (float offsets) --------------------------------------------
#define OFF_XQB    0          // bf16 64x512    (aliased by QHS after P1)
#define OFF_XAB    16384      // bf16 1024x512  (aliased by AHHS after P1)
#define OFF_XCB    278528     // bf16 16x1024   (aliased by CHH f32 after P1)
#define OFF_HAB    286720     // bf16 1024x512
#define OFF_HQB    548864     // bf16 64x512
#define OFF_HCB    565248     // bf16 16x512
#define OFF_AHH    569344     // f32 1024x512
#define OFF_QH     1093632    // f32 64x512
#define OFF_S1     1126400    // f32 512
#define OFF_B1     1126912    // f32 512
#define OFF_WT2    1127424    // bf16 k-tiled hi rw1 (rg-scaled), 524288 el
#define OFF_RW1LOT 1389568    // bf16 [512n][512k] rw1[0:512]
#define OFF_RW1MIT 1520640    // bf16 [512n][512k] rw1[512:1024]
#define OFF_AW1T   1651712    // bf16 [512][512]   ┐
#define OFF_QW1T   1782784    // bf16 [512][512]   ├ dead after P1 -> YA
#define OFF_CW1T   1913856    // bf16 [512][1024]  ┘
#define OFF_AW2T   2176000    // bf16 [512][512]   ┐ dead after P2 -> YQ
#define OFF_QW2T   2307072    // bf16 [512][512]   ┘
#define OFF_CW2T   2438144    // bf16 [512][512]   (end: 2569216 fl)
#define OFF_YA     OFF_AW1T   // f32 1024x512
#define OFF_YQ     OFF_AW2T   // f32 64x512
#define OFF_CHH    OFF_XCB    // f32 16x512
#define OFF_AHHS   OFF_XAB    // bf16 1024x512 (ahh*rg_lo)
#define OFF_QHS    OFF_XQB    // bf16 64x512   (qh*rg_mid)

// WT2 k-tiled layout: element (n, k2) at (k2>>5)*16384 + n*32 + (k2&31).

// ======================== P0: wide prep kernel ==============================
DEV void transpose_tile(const float* __restrict__ src, int koff, int kt, int ct,
                        ushort_t* __restrict__ dst, int ldk, float* sh, int tid) {
  float (*t)[65] = (float(*)[65])sh;
  for (int idx = tid; idx < 4096; idx += 512) {
    const int r = idx >> 6, c = idx & 63;
    t[r][c] = src[(koff + kt + r) * 512 + ct + c];
  }
  __syncthreads();
  for (int idx = tid; idx < 4096; idx += 512) {
    const int c = idx >> 6, r = idx & 63;
    dst[(ct + c) * ldk + kt + r] = f2bf(t[r][c]);
  }
}

// roles: [0,128) WT2 | [128,192) rw1loT | [192,256) rw1midT | [256,320) aw1T
// [320,384) qw1T | [384,512) cw1T | [512,576) aw2T | [576,640) qw2T
// [640,704) cw2T | [704,720) S1/B1 | [720,784) q pool+LN | [784,912) a LN
// [912,928) c concat+LN
__global__ __launch_bounds__(512) void pre0_kernel(
    const float* __restrict__ qa, const float* __restrict__ qm,
    const float* __restrict__ ca, const float* __restrict__ csum,
    const float* __restrict__ ectx,
    const float* __restrict__ qg, const float* __restrict__ qb,
    const float* __restrict__ ag, const float* __restrict__ ab,
    const float* __restrict__ cg, const float* __restrict__ cb,
    const float* __restrict__ rw1, const float* __restrict__ rg,
    const float* __restrict__ rb,
    const float* __restrict__ aw1, const float* __restrict__ qw1,
    const float* __restrict__ cw1, const float* __restrict__ aw2,
    const float* __restrict__ qw2, const float* __restrict__ cw2,
    float* __restrict__ ws) {
  __shared__ float sh[4160];
  const int b = blockIdx.x, tid = threadIdx.x, l = tid & 63, wv = tid >> 6;

  if (b < 128) {
    ushort_t* WT = (ushort_t*)(ws + OFF_WT2);
    float (*t)[65] = (float(*)[65])sh;
    const int kt = (b >> 3) << 6;
    const int ct = (b & 7) << 6;
    for (int idx = tid; idx < 4096; idx += 512) {
      const int r = idx >> 6, c = idx & 63;
      t[r][c] = rg[1024 + kt + r] * rw1[(1024 + kt + r) * 512 + ct + c];
    }
    __syncthreads();
    for (int idx = tid; idx < 4096; idx += 512) {
      const int c = idx >> 6, r = idx & 63;
      const int n = ct + c, k2 = kt + r;
      WT[((k2 >> 5) << 14) + (n << 5) + (k2 & 31)] = f2bf(t[r][c]);
    }
  } else if (b < 192) {
    const int bb = b - 128;
    transpose_tile(rw1, 0, (bb >> 3) << 6, (bb & 7) << 6,
                   (ushort_t*)(ws + OFF_RW1LOT), 512, sh, tid);
  } else if (b < 256) {
    const int bb = b - 192;
    transpose_tile(rw1, 512, (bb >> 3) << 6, (bb & 7) << 6,
                   (ushort_t*)(ws + OFF_RW1MIT), 512, sh, tid);
  } else if (b < 320) {
    const int bb = b - 256;
    transpose_tile(aw1, 0, (bb >> 3) << 6, (bb & 7) << 6,
                   (ushort_t*)(ws + OFF_AW1T), 512, sh, tid);
  } else if (b < 384) {
    const int bb = b - 320;
    transpose_tile(qw1, 0, (bb >> 3) << 6, (bb & 7) << 6,
                   (ushort_t*)(ws + OFF_QW1T), 512, sh, tid);
  } else if (b < 512) {
    const int bb = b - 384;
    transpose_tile(cw1, 0, (bb >> 3) << 6, (bb & 7) << 6,
                   (ushort_t*)(ws + OFF_CW1T), 1024, sh, tid);
  } else if (b < 576) {
    const int bb = b - 512;
    transpose_tile(aw2, 0, (bb >> 3) << 6, (bb & 7) << 6,
                   (ushort_t*)(ws + OFF_AW2T), 512, sh, tid);
  } else if (b < 640) {
    const int bb = b - 576;
    transpose_tile(qw2, 0, (bb >> 3) << 6, (bb & 7) << 6,
                   (ushort_t*)(ws + OFF_QW2T), 512, sh, tid);
  } else if (b < 704) {
    const int bb = b - 640;
    transpose_tile(cw2, 0, (bb >> 3) << 6, (bb & 7) << 6,
                   (ushort_t*)(ws + OFF_CW2T), 512, sh, tid);
  } else if (b < 720) {
    const int kc = (b - 704) << 7;
    float s0 = 0.f, s1 = 0.f, b0 = 0.f, b1v = 0.f;
    for (int k = kc; k < kc + 128; k += 2) {
      const float wa = rw1[(k << 9) + tid];
      const float wb = rw1[((k + 1) << 9) + tid];
      s0 += rg[k] * wa; b0 += rb[k] * wa;
      s1 += rg[k + 1] * wb; b1v += rb[k + 1] * wb;
    }
    atomicAdd(ws + OFF_S1 + tid, s0 + s1);
    atomicAdd(ws + OFF_B1 + tid, b0 + b1v);
  } else if (b < 784) {
    const int q = b - 720;
    if (wv == 0) {
      float m = fmaxf(qm[(q << 6) + l], 0.f);
      sh[l] = m;
      float s = m;
#pragma unroll
      for (int off = 1; off < 64; off <<= 1) s += __shfl_xor(s, off);
      if (l == 0) sh[64] = 1.0f / fmaxf(s, 1e-8f);
    }
    __syncthreads();
    const float sinv = sh[64];
    const float* qaq = qa + (q << 15) + tid;
    float v0 = 0.f, v1 = 0.f, v2 = 0.f, v3 = 0.f;
#pragma unroll 4
    for (int a = 0; a < 64; a += 4) {
      v0 += sh[a] * qaq[a << 9];
      v1 += sh[a + 1] * qaq[(a + 1) << 9];
      v2 += sh[a + 2] * qaq[(a + 2) << 9];
      v3 += sh[a + 3] * qaq[(a + 3) << 9];
    }
    const float v = (v0 + v1 + v2 + v3) * sinv;
    float s = v, ss = v * v;
#pragma unroll
    for (int off = 1; off < 64; off <<= 1) {
      s += __shfl_xor(s, off); ss += __shfl_xor(ss, off);
    }
    if (l == 0) { sh[128 + wv] = s; sh[136 + wv] = ss; }
    __syncthreads();
    float st = 0.f, sst = 0.f;
#pragma unroll
    for (int i = 0; i < 8; ++i) { st += sh[128 + i]; sst += sh[136 + i]; }
    const float mu = st * (1.0f / 512.0f);
    const float rstd = rsqrtf(sst * (1.0f / 512.0f) - mu * mu + 1e-5f);
    ((ushort_t*)(ws + OFF_XQB))[(q << 9) + tid] =
        f2bf((v - mu) * rstd * qg[tid] + qb[tid]);
  } else if (b < 912) {
    const int row = ((b - 784) << 3) + wv;
    const float* crow = ca + (row << 9);
    float x[8];
    float s = 0.f, ss = 0.f;
#pragma unroll
    for (int i = 0; i < 8; ++i) {
      x[i] = crow[l + (i << 6)];
      s += x[i]; ss += x[i] * x[i];
    }
#pragma unroll
    for (int off = 1; off < 64; off <<= 1) {
      s += __shfl_xor(s, off); ss += __shfl_xor(ss, off);
    }
    const float mu = s * (1.0f / 512.0f);
    const float rstd = rsqrtf(ss * (1.0f / 512.0f) - mu * mu + 1e-5f);
    ushort_t* xab = (ushort_t*)(ws + OFF_XAB);
#pragma unroll
    for (int i = 0; i < 8; ++i) {
      const int k = l + (i << 6);
      xab[(row << 9) + k] = f2bf((x[i] - mu) * rstd * ag[k] + ab[k]);
    }
  } else {
    const int w = b - 912;
    const float v0 = csum[(w << 9) + tid];
    const float v1 = ectx[(w << 9) + tid];
    float s = v0 + v1, ss = v0 * v0 + v1 * v1;
#pragma unroll
    for (int off = 1; off < 64; off <<= 1) {
      s += __shfl_xor(s, off); ss += __shfl_xor(ss, off);
    }
    if (l == 0) { sh[wv] = s; sh[8 + wv] = ss; }
    __syncthreads();
    float st = 0.f, sst = 0.f;
#pragma unroll
    for (int i = 0; i < 8; ++i) { st += sh[i]; sst += sh[8 + i]; }
    const float mu = st * (1.0f / 1024.0f);
    const float rstd = rsqrtf(sst * (1.0f / 1024.0f) - mu * mu + 1e-5f);
    ushort_t* xcb = (ushort_t*)(ws + OFF_XCB);
    xcb[(w << 10) + tid] = f2bf((v0 - mu) * rstd * cg[tid] + cb[tid]);
    xcb[(w << 10) + 512 + tid] =
        f2bf((v1 - mu) * rstd * cg[512 + tid] + cb[512 + tid]);
  }
}

// ======================== MFMA GEMM phases (32x32 tiles/wave) ===============
template <int PHASE>
__global__ __launch_bounds__(256) void gemm_kernel(
    float* __restrict__ ws, const float* __restrict__ ba,
    const float* __restrict__ bq, const float* __restrict__ bc,
    const float* __restrict__ rg) {
  const int b = blockIdx.x, tid = threadIdx.x;
  const int l = tid & 63, wv = tid >> 6;

  const ushort_t* A; const ushort_t* BT;
  float* outF = nullptr; ushort_t* outB = nullptr; ushort_t* outS = nullptr;
  const float* bias = nullptr; const float* scl = nullptr;
  int M, K, t;

  if (PHASE == 1) {
    if (b < 128) {
      A = (const ushort_t*)(ws + OFF_XAB); BT = (const ushort_t*)(ws + OFF_AW1T);
      M = 1024; K = 512; outB = (ushort_t*)(ws + OFF_HAB); bias = ba;
      t = (b << 2) + wv;
    } else if (b < 136) {
      A = (const ushort_t*)(ws + OFF_XQB); BT = (const ushort_t*)(ws + OFF_QW1T);
      M = 64; K = 512; outB = (ushort_t*)(ws + OFF_HQB); bias = bq;
      t = ((b - 128) << 2) + wv;
    } else {
      A = (const ushort_t*)(ws + OFF_XCB); BT = (const ushort_t*)(ws + OFF_CW1T);
      M = 16; K = 1024; outB = (ushort_t*)(ws + OFF_HCB); bias = bc;
      t = ((b - 136) << 2) + wv;
    }
  } else if (PHASE == 2) {
    if (b < 128) {
      A = (const ushort_t*)(ws + OFF_HAB); BT = (const ushort_t*)(ws + OFF_AW2T);
      M = 1024; K = 512; outF = ws + OFF_AHH;
      outS = (ushort_t*)(ws + OFF_AHHS); bias = ba; scl = rg;
      t = (b << 2) + wv;
    } else if (b < 136) {
      A = (const ushort_t*)(ws + OFF_HQB); BT = (const ushort_t*)(ws + OFF_QW2T);
      M = 64; K = 512; outF = ws + OFF_QH;
      outS = (ushort_t*)(ws + OFF_QHS); bias = bq; scl = rg + 512;
      t = ((b - 128) << 2) + wv;
    } else {
      A = (const ushort_t*)(ws + OFF_HCB); BT = (const ushort_t*)(ws + OFF_CW2T);
      M = 16; K = 512; outF = ws + OFF_CHH; bias = bc;
      t = ((b - 136) << 2) + wv;
    }
  } else {
    if (b < 128) {
      A = (const ushort_t*)(ws + OFF_AHHS); BT = (const ushort_t*)(ws + OFF_RW1LOT);
      M = 1024; K = 512; outF = ws + OFF_YA;
      t = (b << 2) + wv;
    } else {
      A = (const ushort_t*)(ws + OFF_QHS); BT = (const ushort_t*)(ws + OFF_RW1MIT);
      M = 64; K = 512; outF = ws + OFF_YQ;
      t = ((b - 128) << 2) + wv;
    }
  }

  const int rt = t >> 4, ct = t & 15;
  const int r0 = rt << 5, c0 = ct << 5;
  const int kh = (l >> 4) << 3;
  const ushort_t* ap[2];
  const ushort_t* bp[2];
#pragma unroll
  for (int fr = 0; fr < 2; ++fr) {
    int r = r0 + (fr << 4) + (l & 15);
    if (r > M - 1) r = M - 1;          // row clamp for small-M tiles
    ap[fr] = A + r * K + kh;
  }
#pragma unroll
  for (int cf = 0; cf < 2; ++cf)
    bp[cf] = BT + (c0 + (cf << 4) + (l & 15)) * K + kh;

  f32x4 acc[2][2] = {};
  const int nst = K >> 5;
#pragma unroll 4
  for (int ks = 0; ks < nst; ++ks) {
    bf16x8 afr[2], bfr[2];
#pragma unroll
    for (int fr = 0; fr < 2; ++fr)
      afr[fr] = __builtin_bit_cast(bf16x8, *(const uint4*)(ap[fr] + (ks << 5)));
#pragma unroll
    for (int cf = 0; cf < 2; ++cf)
      bfr[cf] = __builtin_bit_cast(bf16x8, *(const uint4*)(bp[cf] + (ks << 5)));
#pragma unroll
    for (int fr = 0; fr < 2; ++fr)
#pragma unroll
      for (int cf = 0; cf < 2; ++cf)
        acc[fr][cf] = __builtin_amdgcn_mfma_f32_16x16x32_bf16(
            afr[fr], bfr[cf], acc[fr][cf], 0, 0, 0);
  }

  const int rsub = (l >> 4) << 2, cl = l & 15;
#pragma unroll
  for (int fr = 0; fr < 2; ++fr) {
#pragma unroll
    for (int cf = 0; cf < 2; ++cf) {
      const int col = c0 + (cf << 4) + cl;
#pragma unroll
      for (int j = 0; j < 4; ++j) {
        const int row = r0 + (fr << 4) + rsub + j;
        if (row < M) {
          float v = acc[fr][cf][j];
          if (PHASE == 1) {
            outB[(row << 9) + col] = f2bf(gelu_fast(v + bias[col]));
          } else if (PHASE == 2) {
            v += bias[col];
            outF[(row << 9) + col] = v;
            if (outS) outS[(row << 9) + col] = f2bf(v * scl[col]);
          } else {
            outF[(row << 9) + col] = v;
          }
        }
      }
    }
  }
}

// ---------------------------- main fused kernel -----------------------------
// 1 block per (q-pair, w). 512 threads = 8 waves; __launch_bounds__(512,2)
// -> 256-reg cap. Wave wv: cols [wv*64, wv*64+64), 64 rows, BOTH pairs:
// acc0[4][4] + acc1[4][4] = 128 AGPR. Rolling B prefetch; sigmoid-GELU
// epilogue (r13).
__global__ __launch_bounds__(512, 2) void main_kernel(
    const float* __restrict__ AH, const float* __restrict__ QH,
    const float* __restrict__ CH, const ushort_t* __restrict__ WT2,
    const float* __restrict__ Ya, const float* __restrict__ Yq,
    const float* __restrict__ S1, const float* __restrict__ B1,
    const float* __restrict__ rb1, const float* __restrict__ rw2,
    const float* __restrict__ rb2, const float* __restrict__ cmass,
    float* __restrict__ out) {
  extern __shared__ char smem_raw[];
  float* qs = (float*)smem_raw;          // 1024 (2 q rows)
  float* cs = qs + 1024;                 // 512
  float* s1_s = cs + 512;                // 128 ([p*64+r]) -> mu after loop
  float* s2_s = s1_s + 128;              // 128            -> rs after loop
  float* rel_s = s2_s + 128;             // 128
  float* misc = rel_s + 128;             // 4
  uint4* apv = (uint4*)(smem_raw + 8192);  // 2 buf x 2 pair x 16KB

  const int tid = threadIdx.x;           // 0..511
  const int l = tid & 63;
  const int wv = tid >> 6;               // 0..7
  const int w = blockIdx.x & 15;
  const int q0 = (blockIdx.x >> 4) << 1;

  qs[tid] = QH[(q0 << 9) + tid];
  qs[tid + 512] = QH[(q0 << 9) + 512 + tid];
  cs[tid] = CH[(w << 9) + tid];
  if (tid < 128) { s1_s[tid] = 0.f; s2_s[tid] = 0.f; rel_s[tid] = 0.f; }
  __syncthreads();

  const int p = wv >> 2;                 // build pair 0..1
  const int s = wv & 3;                  // build row-slot 0..3
  const int rloc = (s << 4) + (l & 15);
  const float* arow = AH + (((w << 6) + rloc) << 9);
  const float* qsrc = qs + (p << 9);
  const int kh = (l >> 4) << 3;          // 0,8,16,24
  float s1a = 0.f, s2a = 0.f;

  // build chunk C (k in [C*128,(C+1)*128)) into buffer B; 4-elem groups,
  // minimal live registers (one float4 triple at a time).
#define BUILD(C, B) do { \
    _Pragma("unroll") for (int ksl_ = 0; ksl_ < 4; ++ksl_) { \
      const int kg_ = ((C) << 7) + (ksl_ << 5) + kh; \
      const int ka_ = kg_ & 511; \
      union { __bf16 bv[8]; uint4 u4; } pk_; \
      _Pragma("unroll") for (int h_ = 0; h_ < 2; ++h_) { \
        const float4 a_ = *(const float4*)(arow + ka_ + (h_ << 2)); \
        const float4 qv_ = *(const float4*)(qsrc + ka_ + (h_ << 2)); \
        float v0_, v1_, v2_, v3_; \
        if ((C) < 4) { \
          v0_ = a_.x * qv_.x; v1_ = a_.y * qv_.y; \
          v2_ = a_.z * qv_.z; v3_ = a_.w * qv_.w; \
          s1a += (a_.x + a_.y + a_.z + a_.w) + (v0_ + v1_ + v2_ + v3_); \
          s2a += (a_.x * a_.x + a_.y * a_.y + a_.z * a_.z + a_.w * a_.w) + \
                 (v0_ * v0_ + v1_ * v1_ + v2_ * v2_ + v3_ * v3_); \
        } else { \
          const float4 c_ = *(const float4*)(cs + ka_ + (h_ << 2)); \
          v0_ = fabsf(a_.x - qv_.x) + c_.x; \
          v1_ = fabsf(a_.y - qv_.y) + c_.y; \
          v2_ = fabsf(a_.z - qv_.z) + c_.z; \
          v3_ = fabsf(a_.w - qv_.w) + c_.w; \
          s1a += v0_ + v1_ + v2_ + v3_; \
          s2a += v0_ * v0_ + v1_ * v1_ + v2_ * v2_ + v3_ * v3_; \
        } \
        pk_.bv[(h_ << 2) + 0] = (__bf16)v0_; \
        pk_.bv[(h_ << 2) + 1] = (__bf16)v1_; \
        pk_.bv[(h_ << 2) + 2] = (__bf16)v2_; \
        pk_.bv[(h_ << 2) + 3] = (__bf16)v3_; \
      } \
      apv[((B) << 11) + (p << 10) + (ksl_ << 8) + (s << 6) + l] = pk_.u4; \
    } } while (0)

  // ---- prologue: build chunk 0 into buf 0 + per-pair q-segment stats
  BUILD(0, 0);
  if ((wv & 3) == 0) {                   // wv==0 -> p=0, wv==4 -> p=1
    float sq = 0.f, sqq = 0.f;
#pragma unroll
    for (int it = 0; it < 8; ++it) {
      const float vq = qsrc[l + (it << 6)];
      sq += vq; sqq += vq * vq;
    }
#pragma unroll
    for (int off = 1; off < 64; off <<= 1) {
      sq += __shfl_xor(sq, off); sqq += __shfl_xor(sqq, off);
    }
    if (l == 0) { misc[(p << 1)] = sq; misc[(p << 1) + 1] = sqq; }
  }
  __syncthreads();

  // ---- chunk loop: BUILD(c+1), then MFMA(c) with rolling B prefetch -------
  f32x4 acc0[4][4] = {}, acc1[4][4] = {};
  const int ncb = (wv << 6) + (l & 15);  // wave col base (wave: 64 cols)
  const int boff = (ncb << 5) + kh;      // per-lane B offset within a slice
#pragma unroll
  for (int c = 0; c < 8; ++c) {
    if (c < 7) {
      BUILD(c + 1, (c + 1) & 1);
    } else {
      // fold per-thread stats into per-pair per-row LDS totals
      s1a += __shfl_xor(s1a, 16); s1a += __shfl_xor(s1a, 32);
      s2a += __shfl_xor(s2a, 16); s2a += __shfl_xor(s2a, 32);
      if ((l >> 4) == 0) {
        atomicAdd(&s1_s[(p << 6) + rloc], s1a);
        atomicAdd(&s2_s[(p << 6) + rloc], s2a);
      }
    }
    const uint4* cbuf = apv + ((c & 1) << 11);
    const ushort_t* wb = WT2 + ((c << 2) << 14) + boff;   // chunk B base
    // preload B for ksl = 0
    uint4 bn0 = *(const uint4*)(wb);
    uint4 bn1 = *(const uint4*)(wb + (16 << 5));
    uint4 bn2 = *(const uint4*)(wb + (32 << 5));
    uint4 bn3 = *(const uint4*)(wb + (48 << 5));
#pragma unroll
    for (int ksl = 0; ksl < 4; ++ksl) {
      const bf16x8 bf0 = __builtin_bit_cast(bf16x8, bn0);
      const bf16x8 bf1 = __builtin_bit_cast(bf16x8, bn1);
      const bf16x8 bf2 = __builtin_bit_cast(bf16x8, bn2);
      const bf16x8 bf3 = __builtin_bit_cast(bf16x8, bn3);
      if (ksl < 3) {                     // prefetch B for ksl+1
        const ushort_t* wn = wb + ((ksl + 1) << 14);
        bn0 = *(const uint4*)(wn);
        bn1 = *(const uint4*)(wn + (16 << 5));
        bn2 = *(const uint4*)(wn + (32 << 5));
        bn3 = *(const uint4*)(wn + (48 << 5));
      }
      bf16x8 afr;
      __builtin_amdgcn_s_setprio(1);
      // pair 0
#pragma unroll
      for (int fr = 0; fr < 4; ++fr) {
        afr = __builtin_bit_cast(bf16x8, cbuf[(ksl << 8) + (fr << 6) + l]);
        acc0[fr][0] = __builtin_amdgcn_mfma_f32_16x16x32_bf16(afr, bf0, acc0[fr][0], 0, 0, 0);
        acc0[fr][1] = __builtin_amdgcn_mfma_f32_16x16x32_bf16(afr, bf1, acc0[fr][1], 0, 0, 0);
        acc0[fr][2] = __builtin_amdgcn_mfma_f32_16x16x32_bf16(afr, bf2, acc0[fr][2], 0, 0, 0);
        acc0[fr][3] = __builtin_amdgcn_mfma_f32_16x16x32_bf16(afr, bf3, acc0[fr][3], 0, 0, 0);
      }
      // pair 1 (reuse afr register)
#pragma unroll
      for (int fr = 0; fr < 4; ++fr) {
        afr = __builtin_bit_cast(bf16x8, cbuf[(1 << 10) + (ksl << 8) + (fr << 6) + l]);
        acc1[fr][0] = __builtin_amdgcn_mfma_f32_16x16x32_bf16(afr, bf0, acc1[fr][0], 0, 0, 0);
        acc1[fr][1] = __builtin_amdgcn_mfma_f32_16x16x32_bf16(afr, bf1, acc1[fr][1], 0, 0, 0);
        acc1[fr][2] = __builtin_amdgcn_mfma_f32_16x16x32_bf16(afr, bf2, acc1[fr][2], 0, 0, 0);
        acc1[fr][3] = __builtin_amdgcn_mfma_f32_16x16x32_bf16(afr, bf3, acc1[fr][3], 0, 0, 0);
      }
      __builtin_amdgcn_s_setprio(0);
    }
    __syncthreads();
  }
#undef BUILD

  // ---- finalize LN stats: 128 (pair,row) mu/rs computed once --------------
  if (tid < 128) {
    const int pp = tid >> 6;
    const float s1r = s1_s[tid] + misc[pp << 1];
    const float s2r = s2_s[tid] + misc[(pp << 1) + 1];
    const float mu = s1r * (1.0f / 2048.0f);
    const float rs = rsqrtf(s2r * (1.0f / 2048.0f) - mu * mu + 1e-5f);
    s1_s[tid] = mu;
    s2_s[tid] = rs;
  }
  __syncthreads();

  // ---- epilogue: LN-fold + sigmoid-gelu + dot(rw2) -> relevance (2 pairs) --
  {
    float yqv0[4], yqv1[4], s1c[4], b1c[4], w2c[4];
#pragma unroll
    for (int cf = 0; cf < 4; ++cf) {
      const int n = ncb + (cf << 4);
      yqv0[cf] = Yq[(q0 << 9) + n];
      yqv1[cf] = Yq[((q0 + 1) << 9) + n];
      s1c[cf] = S1[n];
      b1c[cf] = B1[n] + rb1[n];
      w2c[cf] = rw2[n];
    }
    const float* yab = Ya + (w << 15) + ncb;
    const int rsub = (l >> 4) << 2;
#pragma unroll
    for (int fr = 0; fr < 4; ++fr) {
#pragma unroll
      for (int j = 0; j < 4; ++j) {
        const int r = (fr << 4) + rsub + j;
        const float mu0 = s1_s[r], rs0 = s2_s[r];
        const float mu1 = s1_s[64 + r], rs1 = s2_s[64 + r];
        float rp0 = 0.f, rp1 = 0.f;
#pragma unroll
        for (int cf = 0; cf < 4; ++cf) {
          const float ya = yab[(r << 9) + (cf << 4)];
          const float c0v = ya + yqv0[cf] - mu0 * s1c[cf];
          const float c1v = ya + yqv1[cf] - mu1 * s1c[cf];
          rp0 += gelu_sig(fmaf(rs0, acc0[fr][cf][j] + c0v, b1c[cf])) * w2c[cf];
          rp1 += gelu_sig(fmaf(rs1, acc1[fr][cf][j] + c1v, b1c[cf])) * w2c[cf];
        }
        rp0 += __shfl_xor(rp0, 1); rp0 += __shfl_xor(rp0, 2);
        rp0 += __shfl_xor(rp0, 4); rp0 += __shfl_xor(rp0, 8);
        rp1 += __shfl_xor(rp1, 1); rp1 += __shfl_xor(rp1, 2);
        rp1 += __shfl_xor(rp1, 4); rp1 += __shfl_xor(rp1, 8);
        if ((l & 15) == 0) {
          atomicAdd(&rel_s[r], rp0);
          atomicAdd(&rel_s[64 + r], rp1);
        }
      }
    }
  }
  __syncthreads();

  // ---- softmax over atoms + entropy (2 pairs: tid<128)
  if (tid < 128) {
    const int pp = tid >> 6, a = tid & 63;
    const int qw = ((q0 + pp) << 4) + w;
    const float relv = rel_s[(pp << 6) + a] + rb2[0];
    const float x = logf(fmaxf(cmass[(w << 6) + a], 1e-8f)) + relv;
    float m = x;
#pragma unroll
    for (int off = 1; off < 64; off <<= 1) m = fmaxf(m, __shfl_xor(m, off));
    const float pv = expf(x - m);
    float sv = pv;
#pragma unroll
    for (int off = 1; off < 64; off <<= 1) sv += __shfl_xor(sv, off);
    float mix = pv / fmaxf(sv, 1e-8f);
    float s2 = mix;
#pragma unroll
    for (int off = 1; off < 64; off <<= 1) s2 += __shfl_xor(s2, off);
    mix = mix / fmaxf(s2, 1e-8f);
    const float et = -mix * logf(fmaxf(mix, 1e-8f));
    float ent = et;
#pragma unroll
    for (int off = 1; off < 64; off <<= 1) ent += __shfl_xor(ent, off);
    out[(qw << 6) + a] = mix;                   // mixed[q][w][a]
    if (a == 0) out[65536 + qw] = ent;          // entropy[q][w]
  }
}

// ---------------------------------------------------------------------------
extern "C" void kernel_launch(void* const* d_in, const int* in_sizes, int n_in,
                              void* d_out, int out_size, void* d_ws, size_t ws_size,
                              hipStream_t stream) {
  (void)in_sizes; (void)n_in; (void)out_size; (void)ws_size;
  const float* q_atoms = (const float*)d_in[0];
  const float* q_mass  = (const float*)d_in[1];
  const float* c_atoms = (const float*)d_in[2];
  const float* c_mass  = (const float*)d_in[3];
  const float* c_sum   = (const float*)d_in[4];
  const float* e_ctx   = (const float*)d_in[5];
  const float* qg  = (const float*)d_in[6];  const float* qb  = (const float*)d_in[7];
  const float* qw1 = (const float*)d_in[8];  const float* qb1 = (const float*)d_in[9];
  const float* qw2 = (const float*)d_in[10]; const float* qb2 = (const float*)d_in[11];
  const float* ag  = (const float*)d_in[12]; const float* ab  = (const float*)d_in[13];
  const float* aw1 = (const float*)d_in[14]; const float* ab1 = (const float*)d_in[15];
  const float* aw2 = (const float*)d_in[16]; const float* ab2 = (const float*)d_in[17];
  const float* cg  = (const float*)d_in[18]; const float* cb  = (const float*)d_in[19];
  const float* cw1 = (const float*)d_in[20]; const float* cb1 = (const float*)d_in[21];
  const float* cw2 = (const float*)d_in[22]; const float* cb2 = (const float*)d_in[23];
  const float* rg  = (const float*)d_in[24]; const float* rb  = (const float*)d_in[25];
  const float* rw1 = (const float*)d_in[26]; const float* rb1 = (const float*)d_in[27];
  const float* rw2 = (const float*)d_in[28]; const float* rb2 = (const float*)d_in[29];

  float* ws = (float*)d_ws;
  float* out = (float*)d_out;

  hipMemsetAsync(ws + OFF_S1, 0, 1024 * sizeof(float), stream);  // S1+B1
  pre0_kernel<<<928, 512, 0, stream>>>(q_atoms, q_mass, c_atoms, c_sum, e_ctx,
                                       qg, qb, ag, ab, cg, cb, rw1, rg, rb,
                                       aw1, qw1, cw1, aw2, qw2, cw2, ws);
  gemm_kernel<1><<<140, 256, 0, stream>>>(ws, ab1, qb1, cb1, rg);
  gemm_kernel<2><<<140, 256, 0, stream>>>(ws, ab2, qb2, cb2, rg);
  gemm_kernel<3><<<136, 256, 0, stream>>>(ws, nullptr, nullptr, nullptr, rg);

  static const size_t MAIN_SMEM = 8192 + 65536;  // 73728 B
  hipFuncSetAttribute((const void*)main_kernel,
                      hipFuncAttributeMaxDynamicSharedMemorySize, (int)MAIN_SMEM);
  main_kernel<<<512, 512, MAIN_SMEM, stream>>>(
      ws + OFF_AHH, ws + OFF_QH, ws + OFF_CHH,
      (const ushort_t*)(ws + OFF_WT2), ws + OFF_YA, ws + OFF_YQ,
      ws + OFF_S1, ws + OFF_B1, rb1, rw2, rb2, c_mass, out);
}

// Round 14
// 149.028 us; speedup vs baseline: 2.0684x; 1.0925x over previous
//
#include <hip/hip_runtime.h>

// ---------------------------------------------------------------------------
// QueryConditionedTransportScorerV3 on MI355X (gfx950)
// Q=64 W=16 A=64 D=H=512.
//   fused@rw1 = Ya[w,a] + Yq[q] + [a*q ; |a-q|+c] @ (rg*rw1)[1024:2048] (MFMA)
//   h = rstd*(sum - mu*S1) + (rb1 + rb@rw1); gelu; @rw2; softmax+entropy fused
// Round 14: A-rows LDS-resident in main (bf16, XOR-swizzled 64KB tile staged
//   once) -> chunk loop has ZERO global loads except prefetched B. P2 emits
//   unscaled bf16 ahh for main. Epilogue sigmoid-GELU (r13).
// ---------------------------------------------------------------------------

#define DEV static __device__ __forceinline__

typedef __attribute__((ext_vector_type(8))) __bf16 bf16x8;
typedef __attribute__((ext_vector_type(4))) float f32x4;
typedef unsigned short ushort_t;

DEV ushort_t f2bf(float f) {
  unsigned u = __builtin_bit_cast(unsigned, f);
  u = (u + 0x7fffu + ((u >> 16) & 1u)) >> 16;
  return (ushort_t)u;
}

// branch-free erf (Abramowitz-Stegun 7.1.26, |err| <= 1.5e-7) — pre-path only
DEV float gelu_fast(float x) {
  const float y = x * 0.70710678118654752f;
  const float z = fabsf(y);
  const float t = __fdividef(1.0f, 1.0f + 0.3275911f * z);
  float p = 1.061405429f;
  p = p * t - 1.453152027f;
  p = p * t + 1.421413741f;
  p = p * t - 0.284496736f;
  p = p * t + 0.254829592f;
  const float e = 1.0f - p * t * __expf(-z * z);
  const float erfv = copysignf(e, y);
  return 0.5f * x * (1.0f + erfv);
}

// cheap sigmoid-GELU for the main epilogue (err <= ~0.01 per element)
DEV float gelu_sig(float x) {
  return x * __frcp_rn(1.0f + __expf(-1.702f * x));
}

// ---- ws layout (float offsets) --------------------------------------------
#define OFF_XQB    0          // bf16 64x512    (aliased by QHS after P1)
#define OFF_XAB    16384      // bf16 1024x512  (aliased by AHHS after P1)
#define OFF_XCB    278528     // bf16 16x1024   (aliased by CHH f32 after P1)
#define OFF_HAB    286720     // bf16 1024x512
#define OFF_HQB    548864     // bf16 64x512
#define OFF_HCB    565248     // bf16 16x512
#define OFF_AHB    569344     // bf16 1024x512 (UNSCALED ahh, for main)
#define OFF_QH     1093632    // f32 64x512
#define OFF_S1     1126400    // f32 512
#define OFF_B1     1126912    // f32 512
#define OFF_WT2    1127424    // bf16 k-tiled hi rw1 (rg-scaled), 524288 el
#define OFF_RW1LOT 1389568    // bf16 [512n][512k] rw1[0:512]
#define OFF_RW1MIT 1520640    // bf16 [512n][512k] rw1[512:1024]
#define OFF_AW1T   1651712    // bf16 [512][512]   ┐
#define OFF_QW1T   1782784    // bf16 [512][512]   ├ dead after P1 -> YA
#define OFF_CW1T   1913856    // bf16 [512][1024]  ┘
#define OFF_AW2T   2176000    // bf16 [512][512]   ┐ dead after P2 -> YQ
#define OFF_QW2T   2307072    // bf16 [512][512]   ┘
#define OFF_CW2T   2438144    // bf16 [512][512]   (end: 2569216 fl)
#define OFF_YA     OFF_AW1T   // f32 1024x512
#define OFF_YQ     OFF_AW2T   // f32 64x512
#define OFF_CHH    OFF_XCB    // f32 16x512
#define OFF_AHHS   OFF_XAB    // bf16 1024x512 (ahh*rg_lo)
#define OFF_QHS    OFF_XQB    // bf16 64x512   (qh*rg_mid)

// WT2 k-tiled layout: element (n, k2) at (k2>>5)*16384 + n*32 + (k2&31).

// ======================== P0: wide prep kernel ==============================
DEV void transpose_tile(const float* __restrict__ src, int koff, int kt, int ct,
                        ushort_t* __restrict__ dst, int ldk, float* sh, int tid) {
  float (*t)[65] = (float(*)[65])sh;
  for (int idx = tid; idx < 4096; idx += 512) {
    const int r = idx >> 6, c = idx & 63;
    t[r][c] = src[(koff + kt + r) * 512 + ct + c];
  }
  __syncthreads();
  for (int idx = tid; idx < 4096; idx += 512) {
    const int c = idx >> 6, r = idx & 63;
    dst[(ct + c) * ldk + kt + r] = f2bf(t[r][c]);
  }
}

// roles: [0,128) WT2 | [128,192) rw1loT | [192,256) rw1midT | [256,320) aw1T
// [320,384) qw1T | [384,512) cw1T | [512,576) aw2T | [576,640) qw2T
// [640,704) cw2T | [704,720) S1/B1 | [720,784) q pool+LN | [784,912) a LN
// [912,928) c concat+LN
__global__ __launch_bounds__(512) void pre0_kernel(
    const float* __restrict__ qa, const float* __restrict__ qm,
    const float* __restrict__ ca, const float* __restrict__ csum,
    const float* __restrict__ ectx,
    const float* __restrict__ qg, const float* __restrict__ qb,
    const float* __restrict__ ag, const float* __restrict__ ab,
    const float* __restrict__ cg, const float* __restrict__ cb,
    const float* __restrict__ rw1, const float* __restrict__ rg,
    const float* __restrict__ rb,
    const float* __restrict__ aw1, const float* __restrict__ qw1,
    const float* __restrict__ cw1, const float* __restrict__ aw2,
    const float* __restrict__ qw2, const float* __restrict__ cw2,
    float* __restrict__ ws) {
  __shared__ float sh[4160];
  const int b = blockIdx.x, tid = threadIdx.x, l = tid & 63, wv = tid >> 6;

  if (b < 128) {
    ushort_t* WT = (ushort_t*)(ws + OFF_WT2);
    float (*t)[65] = (float(*)[65])sh;
    const int kt = (b >> 3) << 6;
    const int ct = (b & 7) << 6;
    for (int idx = tid; idx < 4096; idx += 512) {
      const int r = idx >> 6, c = idx & 63;
      t[r][c] = rg[1024 + kt + r] * rw1[(1024 + kt + r) * 512 + ct + c];
    }
    __syncthreads();
    for (int idx = tid; idx < 4096; idx += 512) {
      const int c = idx >> 6, r = idx & 63;
      const int n = ct + c, k2 = kt + r;
      WT[((k2 >> 5) << 14) + (n << 5) + (k2 & 31)] = f2bf(t[r][c]);
    }
  } else if (b < 192) {
    const int bb = b - 128;
    transpose_tile(rw1, 0, (bb >> 3) << 6, (bb & 7) << 6,
                   (ushort_t*)(ws + OFF_RW1LOT), 512, sh, tid);
  } else if (b < 256) {
    const int bb = b - 192;
    transpose_tile(rw1, 512, (bb >> 3) << 6, (bb & 7) << 6,
                   (ushort_t*)(ws + OFF_RW1MIT), 512, sh, tid);
  } else if (b < 320) {
    const int bb = b - 256;
    transpose_tile(aw1, 0, (bb >> 3) << 6, (bb & 7) << 6,
                   (ushort_t*)(ws + OFF_AW1T), 512, sh, tid);
  } else if (b < 384) {
    const int bb = b - 320;
    transpose_tile(qw1, 0, (bb >> 3) << 6, (bb & 7) << 6,
                   (ushort_t*)(ws + OFF_QW1T), 512, sh, tid);
  } else if (b < 512) {
    const int bb = b - 384;
    transpose_tile(cw1, 0, (bb >> 3) << 6, (bb & 7) << 6,
                   (ushort_t*)(ws + OFF_CW1T), 1024, sh, tid);
  } else if (b < 576) {
    const int bb = b - 512;
    transpose_tile(aw2, 0, (bb >> 3) << 6, (bb & 7) << 6,
                   (ushort_t*)(ws + OFF_AW2T), 512, sh, tid);
  } else if (b < 640) {
    const int bb = b - 576;
    transpose_tile(qw2, 0, (bb >> 3) << 6, (bb & 7) << 6,
                   (ushort_t*)(ws + OFF_QW2T), 512, sh, tid);
  } else if (b < 704) {
    const int bb = b - 640;
    transpose_tile(cw2, 0, (bb >> 3) << 6, (bb & 7) << 6,
                   (ushort_t*)(ws + OFF_CW2T), 512, sh, tid);
  } else if (b < 720) {
    const int kc = (b - 704) << 7;
    float s0 = 0.f, s1 = 0.f, b0 = 0.f, b1v = 0.f;
    for (int k = kc; k < kc + 128; k += 2) {
      const float wa = rw1[(k << 9) + tid];
      const float wb = rw1[((k + 1) << 9) + tid];
      s0 += rg[k] * wa; b0 += rb[k] * wa;
      s1 += rg[k + 1] * wb; b1v += rb[k + 1] * wb;
    }
    atomicAdd(ws + OFF_S1 + tid, s0 + s1);
    atomicAdd(ws + OFF_B1 + tid, b0 + b1v);
  } else if (b < 784) {
    const int q = b - 720;
    if (wv == 0) {
      float m = fmaxf(qm[(q << 6) + l], 0.f);
      sh[l] = m;
      float s = m;
#pragma unroll
      for (int off = 1; off < 64; off <<= 1) s += __shfl_xor(s, off);
      if (l == 0) sh[64] = 1.0f / fmaxf(s, 1e-8f);
    }
    __syncthreads();
    const float sinv = sh[64];
    const float* qaq = qa + (q << 15) + tid;
    float v0 = 0.f, v1 = 0.f, v2 = 0.f, v3 = 0.f;
#pragma unroll 4
    for (int a = 0; a < 64; a += 4) {
      v0 += sh[a] * qaq[a << 9];
      v1 += sh[a + 1] * qaq[(a + 1) << 9];
      v2 += sh[a + 2] * qaq[(a + 2) << 9];
      v3 += sh[a + 3] * qaq[(a + 3) << 9];
    }
    const float v = (v0 + v1 + v2 + v3) * sinv;
    float s = v, ss = v * v;
#pragma unroll
    for (int off = 1; off < 64; off <<= 1) {
      s += __shfl_xor(s, off); ss += __shfl_xor(ss, off);
    }
    if (l == 0) { sh[128 + wv] = s; sh[136 + wv] = ss; }
    __syncthreads();
    float st = 0.f, sst = 0.f;
#pragma unroll
    for (int i = 0; i < 8; ++i) { st += sh[128 + i]; sst += sh[136 + i]; }
    const float mu = st * (1.0f / 512.0f);
    const float rstd = rsqrtf(sst * (1.0f / 512.0f) - mu * mu + 1e-5f);
    ((ushort_t*)(ws + OFF_XQB))[(q << 9) + tid] =
        f2bf((v - mu) * rstd * qg[tid] + qb[tid]);
  } else if (b < 912) {
    const int row = ((b - 784) << 3) + wv;
    const float* crow = ca + (row << 9);
    float x[8];
    float s = 0.f, ss = 0.f;
#pragma unroll
    for (int i = 0; i < 8; ++i) {
      x[i] = crow[l + (i << 6)];
      s += x[i]; ss += x[i] * x[i];
    }
#pragma unroll
    for (int off = 1; off < 64; off <<= 1) {
      s += __shfl_xor(s, off); ss += __shfl_xor(ss, off);
    }
    const float mu = s * (1.0f / 512.0f);
    const float rstd = rsqrtf(ss * (1.0f / 512.0f) - mu * mu + 1e-5f);
    ushort_t* xab = (ushort_t*)(ws + OFF_XAB);
#pragma unroll
    for (int i = 0; i < 8; ++i) {
      const int k = l + (i << 6);
      xab[(row << 9) + k] = f2bf((x[i] - mu) * rstd * ag[k] + ab[k]);
    }
  } else {
    const int w = b - 912;
    const float v0 = csum[(w << 9) + tid];
    const float v1 = ectx[(w << 9) + tid];
    float s = v0 + v1, ss = v0 * v0 + v1 * v1;
#pragma unroll
    for (int off = 1; off < 64; off <<= 1) {
      s += __shfl_xor(s, off); ss += __shfl_xor(ss, off);
    }
    if (l == 0) { sh[wv] = s; sh[8 + wv] = ss; }
    __syncthreads();
    float st = 0.f, sst = 0.f;
#pragma unroll
    for (int i = 0; i < 8; ++i) { st += sh[i]; sst += sh[8 + i]; }
    const float mu = st * (1.0f / 1024.0f);
    const float rstd = rsqrtf(sst * (1.0f / 1024.0f) - mu * mu + 1e-5f);
    ushort_t* xcb = (ushort_t*)(ws + OFF_XCB);
    xcb[(w << 10) + tid] = f2bf((v0 - mu) * rstd * cg[tid] + cb[tid]);
    xcb[(w << 10) + 512 + tid] =
        f2bf((v1 - mu) * rstd * cg[512 + tid] + cb[512 + tid]);
  }
}

// ======================== MFMA GEMM phases (32x32 tiles/wave) ===============
template <int PHASE>
__global__ __launch_bounds__(256) void gemm_kernel(
    float* __restrict__ ws, const float* __restrict__ ba,
    const float* __restrict__ bq, const float* __restrict__ bc,
    const float* __restrict__ rg) {
  const int b = blockIdx.x, tid = threadIdx.x;
  const int l = tid & 63, wv = tid >> 6;

  const ushort_t* A; const ushort_t* BT;
  float* outF = nullptr; ushort_t* outB = nullptr; ushort_t* outS = nullptr;
  ushort_t* outU = nullptr;
  const float* bias = nullptr; const float* scl = nullptr;
  int M, K, t;

  if (PHASE == 1) {
    if (b < 128) {
      A = (const ushort_t*)(ws + OFF_XAB); BT = (const ushort_t*)(ws + OFF_AW1T);
      M = 1024; K = 512; outB = (ushort_t*)(ws + OFF_HAB); bias = ba;
      t = (b << 2) + wv;
    } else if (b < 136) {
      A = (const ushort_t*)(ws + OFF_XQB); BT = (const ushort_t*)(ws + OFF_QW1T);
      M = 64; K = 512; outB = (ushort_t*)(ws + OFF_HQB); bias = bq;
      t = ((b - 128) << 2) + wv;
    } else {
      A = (const ushort_t*)(ws + OFF_XCB); BT = (const ushort_t*)(ws + OFF_CW1T);
      M = 16; K = 1024; outB = (ushort_t*)(ws + OFF_HCB); bias = bc;
      t = ((b - 136) << 2) + wv;
    }
  } else if (PHASE == 2) {
    if (b < 128) {
      A = (const ushort_t*)(ws + OFF_HAB); BT = (const ushort_t*)(ws + OFF_AW2T);
      M = 1024; K = 512; outU = (ushort_t*)(ws + OFF_AHB);
      outS = (ushort_t*)(ws + OFF_AHHS); bias = ba; scl = rg;
      t = (b << 2) + wv;
    } else if (b < 136) {
      A = (const ushort_t*)(ws + OFF_HQB); BT = (const ushort_t*)(ws + OFF_QW2T);
      M = 64; K = 512; outF = ws + OFF_QH;
      outS = (ushort_t*)(ws + OFF_QHS); bias = bq; scl = rg + 512;
      t = ((b - 128) << 2) + wv;
    } else {
      A = (const ushort_t*)(ws + OFF_HCB); BT = (const ushort_t*)(ws + OFF_CW2T);
      M = 16; K = 512; outF = ws + OFF_CHH; bias = bc;
      t = ((b - 136) << 2) + wv;
    }
  } else {
    if (b < 128) {
      A = (const ushort_t*)(ws + OFF_AHHS); BT = (const ushort_t*)(ws + OFF_RW1LOT);
      M = 1024; K = 512; outF = ws + OFF_YA;
      t = (b << 2) + wv;
    } else {
      A = (const ushort_t*)(ws + OFF_QHS); BT = (const ushort_t*)(ws + OFF_RW1MIT);
      M = 64; K = 512; outF = ws + OFF_YQ;
      t = ((b - 128) << 2) + wv;
    }
  }

  const int rt = t >> 4, ct = t & 15;
  const int r0 = rt << 5, c0 = ct << 5;
  const int kh = (l >> 4) << 3;
  const ushort_t* ap[2];
  const ushort_t* bp[2];
#pragma unroll
  for (int fr = 0; fr < 2; ++fr) {
    int r = r0 + (fr << 4) + (l & 15);
    if (r > M - 1) r = M - 1;          // row clamp for small-M tiles
    ap[fr] = A + r * K + kh;
  }
#pragma unroll
  for (int cf = 0; cf < 2; ++cf)
    bp[cf] = BT + (c0 + (cf << 4) + (l & 15)) * K + kh;

  f32x4 acc[2][2] = {};
  const int nst = K >> 5;
#pragma unroll 4
  for (int ks = 0; ks < nst; ++ks) {
    bf16x8 afr[2], bfr[2];
#pragma unroll
    for (int fr = 0; fr < 2; ++fr)
      afr[fr] = __builtin_bit_cast(bf16x8, *(const uint4*)(ap[fr] + (ks << 5)));
#pragma unroll
    for (int cf = 0; cf < 2; ++cf)
      bfr[cf] = __builtin_bit_cast(bf16x8, *(const uint4*)(bp[cf] + (ks << 5)));
#pragma unroll
    for (int fr = 0; fr < 2; ++fr)
#pragma unroll
      for (int cf = 0; cf < 2; ++cf)
        acc[fr][cf] = __builtin_amdgcn_mfma_f32_16x16x32_bf16(
            afr[fr], bfr[cf], acc[fr][cf], 0, 0, 0);
  }

  const int rsub = (l >> 4) << 2, cl = l & 15;
#pragma unroll
  for (int fr = 0; fr < 2; ++fr) {
#pragma unroll
    for (int cf = 0; cf < 2; ++cf) {
      const int col = c0 + (cf << 4) + cl;
#pragma unroll
      for (int j = 0; j < 4; ++j) {
        const int row = r0 + (fr << 4) + rsub + j;
        if (row < M) {
          float v = acc[fr][cf][j];
          if (PHASE == 1) {
            outB[(row << 9) + col] = f2bf(gelu_fast(v + bias[col]));
          } else if (PHASE == 2) {
            v += bias[col];
            if (outU) outU[(row << 9) + col] = f2bf(v);
            if (outF) outF[(row << 9) + col] = v;
            if (outS) outS[(row << 9) + col] = f2bf(v * scl[col]);
          } else {
            outF[(row << 9) + col] = v;
          }
        }
      }
    }
  }
}

// ---------------------------- main fused kernel -----------------------------
// 1 block per (q-pair, w). 512 threads = 8 waves; __launch_bounds__(512,2).
// A-rows staged ONCE into 64KB XOR-swizzled bf16 LDS tile; chunk loop has no
// global loads except rolling-prefetched B. acc0[4][4]+acc1[4][4] = 128 AGPR.
__global__ __launch_bounds__(512, 2) void main_kernel(
    const ushort_t* __restrict__ AHB, const float* __restrict__ QH,
    const float* __restrict__ CH, const ushort_t* __restrict__ WT2,
    const float* __restrict__ Ya, const float* __restrict__ Yq,
    const float* __restrict__ S1, const float* __restrict__ B1,
    const float* __restrict__ rb1, const float* __restrict__ rw2,
    const float* __restrict__ rb2, const float* __restrict__ cmass,
    float* __restrict__ out) {
  extern __shared__ char smem_raw[];
  float* qs = (float*)smem_raw;          // 1024 (2 q rows)
  float* cs = qs + 1024;                 // 512
  float* s1_s = cs + 512;                // 128 ([p*64+r]) -> mu after loop
  float* s2_s = s1_s + 128;              // 128            -> rs after loop
  float* rel_s = s2_s + 128;             // 128
  float* misc = rel_s + 128;             // 4 (pad to 8192 B)
  uint4* ab4 = (uint4*)(smem_raw + 8192);     // 64KB: A rows, XOR-swizzled
  uint4* apv = (uint4*)(smem_raw + 8192 + 65536);  // 64KB pair bufs

  const int tid = threadIdx.x;           // 0..511
  const int l = tid & 63;
  const int wv = tid >> 6;               // 0..7
  const int w = blockIdx.x & 15;
  const int q0 = (blockIdx.x >> 4) << 1;

  // ---- stage: A rows (64x512 bf16, swizzled), q rows, c row ---------------
  {
    const uint4* src = (const uint4*)(AHB + ((w << 6) << 9));
#pragma unroll
    for (int i = 0; i < 16; ++i) {
      const int u = tid + (i << 9);
      const int row = u >> 7, c16 = u & 127;
      ab4[(row << 7) + (c16 ^ (row & 7))] = src[u];
    }
  }
  qs[tid] = QH[(q0 << 9) + tid];
  qs[tid + 512] = QH[(q0 << 9) + 512 + tid];
  cs[tid] = CH[(w << 9) + tid];
  if (tid < 128) { s1_s[tid] = 0.f; s2_s[tid] = 0.f; rel_s[tid] = 0.f; }
  __syncthreads();

  const int p = wv >> 2;                 // build pair 0..1
  const int s = wv & 3;                  // build row-slot 0..3
  const int rloc = (s << 4) + (l & 15);
  const float* qsrc = qs + (p << 9);
  const int kh = (l >> 4) << 3;          // 0,8,16,24
  const int ar_base = rloc << 7;         // uint4 row base in ab4
  const int rsw = rloc & 7;              // swizzle key
  float s1a = 0.f, s2a = 0.f;

  // build chunk C (k in [C*128,(C+1)*128)) into buffer B from LDS-A
#define BUILD(C, B) do { \
    _Pragma("unroll") for (int ksl_ = 0; ksl_ < 4; ++ksl_) { \
      const int kg_ = ((C) << 7) + (ksl_ << 5) + kh; \
      const int ka_ = kg_ & 511; \
      const bf16x8 av8_ = __builtin_bit_cast(bf16x8, \
          ab4[ar_base + ((ka_ >> 3) ^ rsw)]); \
      union { __bf16 bv[8]; uint4 u4; } pk_; \
      _Pragma("unroll") for (int h_ = 0; h_ < 2; ++h_) { \
        const float4 qv_ = *(const float4*)(qsrc + ka_ + (h_ << 2)); \
        const float a0_ = (float)av8_[(h_ << 2) + 0]; \
        const float a1_ = (float)av8_[(h_ << 2) + 1]; \
        const float a2_ = (float)av8_[(h_ << 2) + 2]; \
        const float a3_ = (float)av8_[(h_ << 2) + 3]; \
        float v0_, v1_, v2_, v3_; \
        if ((C) < 4) { \
          v0_ = a0_ * qv_.x; v1_ = a1_ * qv_.y; \
          v2_ = a2_ * qv_.z; v3_ = a3_ * qv_.w; \
          s1a += (a0_ + a1_ + a2_ + a3_) + (v0_ + v1_ + v2_ + v3_); \
          s2a += (a0_ * a0_ + a1_ * a1_ + a2_ * a2_ + a3_ * a3_) + \
                 (v0_ * v0_ + v1_ * v1_ + v2_ * v2_ + v3_ * v3_); \
        } else { \
          const float4 c_ = *(const float4*)(cs + ka_ + (h_ << 2)); \
          v0_ = fabsf(a0_ - qv_.x) + c_.x; \
          v1_ = fabsf(a1_ - qv_.y) + c_.y; \
          v2_ = fabsf(a2_ - qv_.z) + c_.z; \
          v3_ = fabsf(a3_ - qv_.w) + c_.w; \
          s1a += v0_ + v1_ + v2_ + v3_; \
          s2a += v0_ * v0_ + v1_ * v1_ + v2_ * v2_ + v3_ * v3_; \
        } \
        pk_.bv[(h_ << 2) + 0] = (__bf16)v0_; \
        pk_.bv[(h_ << 2) + 1] = (__bf16)v1_; \
        pk_.bv[(h_ << 2) + 2] = (__bf16)v2_; \
        pk_.bv[(h_ << 2) + 3] = (__bf16)v3_; \
      } \
      apv[((B) << 11) + (p << 10) + (ksl_ << 8) + (s << 6) + l] = pk_.u4; \
    } } while (0)

  // ---- prologue: build chunk 0 into buf 0 + per-pair q-segment stats
  BUILD(0, 0);
  if ((wv & 3) == 0) {                   // wv==0 -> p=0, wv==4 -> p=1
    float sq = 0.f, sqq = 0.f;
#pragma unroll
    for (int it = 0; it < 8; ++it) {
      const float vq = qsrc[l + (it << 6)];
      sq += vq; sqq += vq * vq;
    }
#pragma unroll
    for (int off = 1; off < 64; off <<= 1) {
      sq += __shfl_xor(sq, off); sqq += __shfl_xor(sqq, off);
    }
    if (l == 0) { misc[(p << 1)] = sq; misc[(p << 1) + 1] = sqq; }
  }
  __syncthreads();

  // ---- chunk loop: BUILD(c+1), then MFMA(c) with rolling B prefetch -------
  f32x4 acc0[4][4] = {}, acc1[4][4] = {};
  const int ncb = (wv << 6) + (l & 15);  // wave col base (wave: 64 cols)
  const int boff = (ncb << 5) + kh;      // per-lane B offset within a slice
#pragma unroll
  for (int c = 0; c < 8; ++c) {
    if (c < 7) {
      BUILD(c + 1, (c + 1) & 1);
    } else {
      // fold per-thread stats into per-pair per-row LDS totals
      s1a += __shfl_xor(s1a, 16); s1a += __shfl_xor(s1a, 32);
      s2a += __shfl_xor(s2a, 16); s2a += __shfl_xor(s2a, 32);
      if ((l >> 4) == 0) {
        atomicAdd(&s1_s[(p << 6) + rloc], s1a);
        atomicAdd(&s2_s[(p << 6) + rloc], s2a);
      }
    }
    const uint4* cbuf = apv + ((c & 1) << 11);
    const ushort_t* wb = WT2 + ((c << 2) << 14) + boff;   // chunk B base
    // preload B for ksl = 0
    uint4 bn0 = *(const uint4*)(wb);
    uint4 bn1 = *(const uint4*)(wb + (16 << 5));
    uint4 bn2 = *(const uint4*)(wb + (32 << 5));
    uint4 bn3 = *(const uint4*)(wb + (48 << 5));
#pragma unroll
    for (int ksl = 0; ksl < 4; ++ksl) {
      const bf16x8 bf0 = __builtin_bit_cast(bf16x8, bn0);
      const bf16x8 bf1 = __builtin_bit_cast(bf16x8, bn1);
      const bf16x8 bf2 = __builtin_bit_cast(bf16x8, bn2);
      const bf16x8 bf3 = __builtin_bit_cast(bf16x8, bn3);
      if (ksl < 3) {                     // prefetch B for ksl+1
        const ushort_t* wn = wb + ((ksl + 1) << 14);
        bn0 = *(const uint4*)(wn);
        bn1 = *(const uint4*)(wn + (16 << 5));
        bn2 = *(const uint4*)(wn + (32 << 5));
        bn3 = *(const uint4*)(wn + (48 << 5));
      }
      bf16x8 afr;
      __builtin_amdgcn_s_setprio(1);
      // pair 0
#pragma unroll
      for (int fr = 0; fr < 4; ++fr) {
        afr = __builtin_bit_cast(bf16x8, cbuf[(ksl << 8) + (fr << 6) + l]);
        acc0[fr][0] = __builtin_amdgcn_mfma_f32_16x16x32_bf16(afr, bf0, acc0[fr][0], 0, 0, 0);
        acc0[fr][1] = __builtin_amdgcn_mfma_f32_16x16x32_bf16(afr, bf1, acc0[fr][1], 0, 0, 0);
        acc0[fr][2] = __builtin_amdgcn_mfma_f32_16x16x32_bf16(afr, bf2, acc0[fr][2], 0, 0, 0);
        acc0[fr][3] = __builtin_amdgcn_mfma_f32_16x16x32_bf16(afr, bf3, acc0[fr][3], 0, 0, 0);
      }
      // pair 1 (reuse afr register)
#pragma unroll
      for (int fr = 0; fr < 4; ++fr) {
        afr = __builtin_bit_cast(bf16x8, cbuf[(1 << 10) + (ksl << 8) + (fr << 6) + l]);
        acc1[fr][0] = __builtin_amdgcn_mfma_f32_16x16x32_bf16(afr, bf0, acc1[fr][0], 0, 0, 0);
        acc1[fr][1] = __builtin_amdgcn_mfma_f32_16x16x32_bf16(afr, bf1, acc1[fr][1], 0, 0, 0);
        acc1[fr][2] = __builtin_amdgcn_mfma_f32_16x16x32_bf16(afr, bf2, acc1[fr][2], 0, 0, 0);
        acc1[fr][3] = __builtin_amdgcn_mfma_f32_16x16x32_bf16(afr, bf3, acc1[fr][3], 0, 0, 0);
      }
      __builtin_amdgcn_s_setprio(0);
    }
    __syncthreads();
  }
#undef BUILD

  // ---- finalize LN stats: 128 (pair,row) mu/rs computed once --------------
  if (tid < 128) {
    const int pp = tid >> 6;
    const float s1r = s1_s[tid] + misc[pp << 1];
    const float s2r = s2_s[tid] + misc[(pp << 1) + 1];
    const float mu = s1r * (1.0f / 2048.0f);
    const float rs = rsqrtf(s2r * (1.0f / 2048.0f) - mu * mu + 1e-5f);
    s1_s[tid] = mu;
    s2_s[tid] = rs;
  }
  __syncthreads();

  // ---- epilogue: LN-fold + sigmoid-gelu + dot(rw2) -> relevance (2 pairs) --
  {
    float yqv0[4], yqv1[4], s1c[4], b1c[4], w2c[4];
#pragma unroll
    for (int cf = 0; cf < 4; ++cf) {
      const int n = ncb + (cf << 4);
      yqv0[cf] = Yq[(q0 << 9) + n];
      yqv1[cf] = Yq[((q0 + 1) << 9) + n];
      s1c[cf] = S1[n];
      b1c[cf] = B1[n] + rb1[n];
      w2c[cf] = rw2[n];
    }
    const float* yab = Ya + (w << 15) + ncb;
    const int rsub = (l >> 4) << 2;
#pragma unroll
    for (int fr = 0; fr < 4; ++fr) {
#pragma unroll
      for (int j = 0; j < 4; ++j) {
        const int r = (fr << 4) + rsub + j;
        const float mu0 = s1_s[r], rs0 = s2_s[r];
        const float mu1 = s1_s[64 + r], rs1 = s2_s[64 + r];
        float rp0 = 0.f, rp1 = 0.f;
#pragma unroll
        for (int cf = 0; cf < 4; ++cf) {
          const float ya = yab[(r << 9) + (cf << 4)];
          const float c0v = ya + yqv0[cf] - mu0 * s1c[cf];
          const float c1v = ya + yqv1[cf] - mu1 * s1c[cf];
          rp0 += gelu_sig(fmaf(rs0, acc0[fr][cf][j] + c0v, b1c[cf])) * w2c[cf];
          rp1 += gelu_sig(fmaf(rs1, acc1[fr][cf][j] + c1v, b1c[cf])) * w2c[cf];
        }
        rp0 += __shfl_xor(rp0, 1); rp0 += __shfl_xor(rp0, 2);
        rp0 += __shfl_xor(rp0, 4); rp0 += __shfl_xor(rp0, 8);
        rp1 += __shfl_xor(rp1, 1); rp1 += __shfl_xor(rp1, 2);
        rp1 += __shfl_xor(rp1, 4); rp1 += __shfl_xor(rp1, 8);
        if ((l & 15) == 0) {
          atomicAdd(&rel_s[r], rp0);
          atomicAdd(&rel_s[64 + r], rp1);
        }
      }
    }
  }
  __syncthreads();

  // ---- softmax over atoms + entropy (2 pairs: tid<128)
  if (tid < 128) {
    const int pp = tid >> 6, a = tid & 63;
    const int qw = ((q0 + pp) << 4) + w;
    const float relv = rel_s[(pp << 6) + a] + rb2[0];
    const float x = logf(fmaxf(cmass[(w << 6) + a], 1e-8f)) + relv;
    float m = x;
#pragma unroll
    for (int off = 1; off < 64; off <<= 1) m = fmaxf(m, __shfl_xor(m, off));
    const float pv = expf(x - m);
    float sv = pv;
#pragma unroll
    for (int off = 1; off < 64; off <<= 1) sv += __shfl_xor(sv, off);
    float mix = pv / fmaxf(sv, 1e-8f);
    float s2 = mix;
#pragma unroll
    for (int off = 1; off < 64; off <<= 1) s2 += __shfl_xor(s2, off);
    mix = mix / fmaxf(s2, 1e-8f);
    const float et = -mix * logf(fmaxf(mix, 1e-8f));
    float ent = et;
#pragma unroll
    for (int off = 1; off < 64; off <<= 1) ent += __shfl_xor(ent, off);
    out[(qw << 6) + a] = mix;                   // mixed[q][w][a]
    if (a == 0) out[65536 + qw] = ent;          // entropy[q][w]
  }
}

// ---------------------------------------------------------------------------
extern "C" void kernel_launch(void* const* d_in, const int* in_sizes, int n_in,
                              void* d_out, int out_size, void* d_ws, size_t ws_size,
                              hipStream_t stream) {
  (void)in_sizes; (void)n_in; (void)out_size; (void)ws_size;
  const float* q_atoms = (const float*)d_in[0];
  const float* q_mass  = (const float*)d_in[1];
  const float* c_atoms = (const float*)d_in[2];
  const float* c_mass  = (const float*)d_in[3];
  const float* c_sum   = (const float*)d_in[4];
  const float* e_ctx   = (const float*)d_in[5];
  const float* qg  = (const float*)d_in[6];  const float* qb  = (const float*)d_in[7];
  const float* qw1 = (const float*)d_in[8];  const float* qb1 = (const float*)d_in[9];
  const float* qw2 = (const float*)d_in[10]; const float* qb2 = (const float*)d_in[11];
  const float* ag  = (const float*)d_in[12]; const float* ab  = (const float*)d_in[13];
  const float* aw1 = (const float*)d_in[14]; const float* ab1 = (const float*)d_in[15];
  const float* aw2 = (const float*)d_in[16]; const float* ab2 = (const float*)d_in[17];
  const float* cg  = (const float*)d_in[18]; const float* cb  = (const float*)d_in[19];
  const float* cw1 = (const float*)d_in[20]; const float* cb1 = (const float*)d_in[21];
  const float* cw2 = (const float*)d_in[22]; const float* cb2 = (const float*)d_in[23];
  const float* rg  = (const float*)d_in[24]; const float* rb  = (const float*)d_in[25];
  const float* rw1 = (const float*)d_in[26]; const float* rb1 = (const float*)d_in[27];
  const float* rw2 = (const float*)d_in[28]; const float* rb2 = (const float*)d_in[29];

  float* ws = (float*)d_ws;
  float* out = (float*)d_out;

  hipMemsetAsync(ws + OFF_S1, 0, 1024 * sizeof(float), stream);  // S1+B1
  pre0_kernel<<<928, 512, 0, stream>>>(q_atoms, q_mass, c_atoms, c_sum, e_ctx,
                                       qg, qb, ag, ab, cg, cb, rw1, rg, rb,
                                       aw1, qw1, cw1, aw2, qw2, cw2, ws);
  gemm_kernel<1><<<140, 256, 0, stream>>>(ws, ab1, qb1, cb1, rg);
  gemm_kernel<2><<<140, 256, 0, stream>>>(ws, ab2, qb2, cb2, rg);
  gemm_kernel<3><<<136, 256, 0, stream>>>(ws, nullptr, nullptr, nullptr, rg);

  static const size_t MAIN_SMEM = 8192 + 65536 + 65536;  // 139264 B
  hipFuncSetAttribute((const void*)main_kernel,
                      hipFuncAttributeMaxDynamicSharedMemorySize, (int)MAIN_SMEM);
  main_kernel<<<512, 512, MAIN_SMEM, stream>>>(
      (const ushort_t*)(ws + OFF_AHB), ws + OFF_QH, ws + OFF_CHH,
      (const ushort_t*)(ws + OFF_WT2), ws + OFF_YA, ws + OFF_YQ,
      ws + OFF_S1, ws + OFF_B1, rb1, rw2, rb2, c_mass, out);
}